// Round 1
// baseline (2032.610 us; speedup 1.0000x reference)
//
#include <hip/hip_runtime.h>
#include <hip/hip_bf16.h>
#include <math.h>

#define NL    4
#define H     64
#define CV    16
#define NRBF  16
#define HEADS 8
#define DH    8
#define KK    32
#define DIN   176
#define NB    2
#define NN    2048
#define F1W   (CV*3)   // 48

// ---------------------------------------------------------------- center
__global__ __launch_bounds__(256) void k_center(const float* __restrict__ coord,
                                                float* __restrict__ coordC) {
  __shared__ float rx[256], ry[256], rz[256];
  int b = blockIdx.x;
  const float* cb = coord + b*NN*3;
  float sx = 0.f, sy = 0.f, sz = 0.f;
  for (int i = threadIdx.x; i < NN; i += 256) {
    sx += cb[i*3+0]; sy += cb[i*3+1]; sz += cb[i*3+2];
  }
  rx[threadIdx.x] = sx; ry[threadIdx.x] = sy; rz[threadIdx.x] = sz;
  __syncthreads();
  for (int s = 128; s > 0; s >>= 1) {
    if (threadIdx.x < s) {
      rx[threadIdx.x] += rx[threadIdx.x+s];
      ry[threadIdx.x] += ry[threadIdx.x+s];
      rz[threadIdx.x] += rz[threadIdx.x+s];
    }
    __syncthreads();
  }
  float mx = rx[0]*(1.0f/NN), my = ry[0]*(1.0f/NN), mz = rz[0]*(1.0f/NN);
  float* ob = coordC + b*NN*3;
  for (int i = threadIdx.x; i < NN; i += 256) {
    ob[i*3+0] = cb[i*3+0] - mx;
    ob[i*3+1] = cb[i*3+1] - my;
    ob[i*3+2] = cb[i*3+2] - mz;
  }
}

// ---------------------------------------------------------------- knn + geometry
__global__ __launch_bounds__(256) void k_knn(const float* __restrict__ coordC,
                                             int* __restrict__ idx,
                                             float* __restrict__ dirn,
                                             float* __restrict__ rbf) {
  __shared__ float cc[NN*3];
  __shared__ float d2[NN];
  __shared__ float rv[256];
  __shared__ int   ri[256];
  __shared__ int   sel[KK];
  const int node = blockIdx.x;              // b*NN + i
  const int b = node >> 11;
  const int i = node & (NN-1);
  const int t = threadIdx.x;
  const float* cb = coordC + b*NN*3;
  for (int j = t; j < NN*3; j += 256) cc[j] = cb[j];
  __syncthreads();
  const float xi = cc[i*3+0], yi = cc[i*3+1], zi = cc[i*3+2];
  const float sqi = xi*xi + yi*yi + zi*zi;
  for (int j = t; j < NN; j += 256) {
    float xj = cc[j*3+0], yj = cc[j*3+1], zj = cc[j*3+2];
    float sqj = xj*xj + yj*yj + zj*zj;
    float dot = xi*xj + yi*yj + zi*zj;
    float v = sqi + sqj - 2.0f*dot;          // gram-trick, matches reference
    if (j == i) v += 1.0e9f;                 // exclude self-loop
    d2[j] = v;
  }
  __syncthreads();
  // 32 successive stable argmins (ties -> lowest index, matches lax.top_k)
  for (int s = 0; s < KK; ++s) {
    float bv = 3.0e38f; int bi = 0x7fffffff;
    for (int j = t; j < NN; j += 256) {
      float v = d2[j];
      if (v < bv) { bv = v; bi = j; }
    }
    rv[t] = bv; ri[t] = bi;
    __syncthreads();
    for (int st = 128; st > 0; st >>= 1) {
      if (t < st) {
        float ov = rv[t+st]; int oi = ri[t+st];
        if (ov < rv[t] || (ov == rv[t] && oi < ri[t])) { rv[t] = ov; ri[t] = oi; }
      }
      __syncthreads();
    }
    if (t == 0) { sel[s] = ri[0]; d2[ri[0]] = 3.0e38f; }
    __syncthreads();
  }
  // geometry for the 32 selected edges
  if (t < KK) {
    int j = sel[t];
    idx[node*KK + t] = j;
    float rxv = cc[j*3+0] - xi, ryv = cc[j*3+1] - yi, rzv = cc[j*3+2] - zi;
    float dd = sqrtf(rxv*rxv + ryv*ryv + rzv*rzv + 1e-8f);
    float inv = 1.0f/dd;
    float* dn = dirn + (node*KK + t)*3;
    dn[0] = rxv*inv; dn[1] = ryv*inv; dn[2] = rzv*inv;
    float* rb = rbf + (node*KK + t)*NRBF;
    const float inv2s2 = 1.0f/(2.0f*0.625f*0.625f);
    #pragma unroll
    for (int r = 0; r < NRBF; ++r) {
      float mu = (10.0f/15.0f)*(float)r;
      float dm = dd - mu;
      rb[r] = expf(-(dm*dm)*inv2s2);
    }
  }
}

// ---------------------------------------------------------------- f0 init
__global__ __launch_bounds__(256) void k_f0init(const int* __restrict__ seq,
                                                const int* __restrict__ tptr,
                                                const float* __restrict__ atab,
                                                const float* __restrict__ ttab,
                                                const float* __restrict__ Wp0,
                                                const float* __restrict__ bp0,
                                                float* __restrict__ f0) {
  int g = blockIdx.x*256 + threadIdx.x;     // node*H + o
  int node = g >> 6, o = g & (H-1);
  int s = seq[node];
  int tv = tptr[0];
  const float* ar = atab + s*32;
  const float* tr = ttab + tv*32;
  float acc = bp0[o];
  for (int i2 = 0; i2 < 32; ++i2) acc = fmaf(ar[i2], Wp0[i2*H + o], acc);
  for (int i2 = 0; i2 < 32; ++i2) acc = fmaf(tr[i2], Wp0[(32+i2)*H + o], acc);
  f0[g] = acc;
}

// ---------------------------------------------------------------- f1 init
__global__ __launch_bounds__(256) void k_f1init(const float* __restrict__ coordC,
                                                const float* __restrict__ Wp1,
                                                float* __restrict__ f1) {
  int g = blockIdx.x*256 + threadIdx.x;
  if (g >= NB*NN*F1W) return;
  int node = g / F1W;
  int r = g - node*F1W;
  int c = r / 3, d = r - c*3;
  f1[g] = coordC[node*3 + d] * Wp1[c];
}

// ---------------------------------------------------------------- fused layer
__global__ __launch_bounds__(256) void k_layer(
    const float* __restrict__ f0i, const float* __restrict__ f1i,
    float* __restrict__ f0o, float* __restrict__ f1o,
    const int* __restrict__ idx, const float* __restrict__ dirn,
    const float* __restrict__ rbf,
    const float* __restrict__ We1, const float* __restrict__ be1,
    const float* __restrict__ We2, const float* __restrict__ be2,
    const float* __restrict__ Wq,  const float* __restrict__ Wk,
    const float* __restrict__ Wv0, const float* __restrict__ Wv1,
    const float* __restrict__ Wg1, const float* __restrict__ Wo0,
    const float* __restrict__ bo0)
{
  __shared__ float sF0i[H];
  __shared__ float sF1i[F1W];
  __shared__ int   sIdx[KK];
  __shared__ float sF0s[KK][H+1];
  __shared__ float sF1s[KK][F1W+1];
  __shared__ float sDir[KK][3];
  __shared__ float sRbf[KK][NRBF+1];
  __shared__ float sE[KK][DIN+1];
  __shared__ float sHh[KK][H+1];
  __shared__ float sM[KK][H+1];
  __shared__ float sV0[KK][H+1];
  __shared__ float sQ[H];
  __shared__ float sLog[KK][HEADS+1];
  __shared__ float sAtt[KK][HEADS+1];
  __shared__ float sA[KK];
  __shared__ float sMv1[KK][CV+1];
  __shared__ float sMg1[KK][CV+1];
  __shared__ float sAgg[H];

  const int node = blockIdx.x;
  const int t = threadIdx.x;
  const int bbase = node & ~(NN-1);

  if (t < KK) sIdx[t] = idx[node*KK + t];
  if (t < H)  sF0i[t] = f0i[node*H + t];
  if (t >= H && t < H + F1W) sF1i[t-H] = f1i[node*F1W + (t-H)];
  for (int e = t; e < KK*3; e += 256) sDir[e/3][e%3] = dirn[node*KK*3 + e];
  for (int e = t; e < KK*NRBF; e += 256) sRbf[e>>4][e&15] = rbf[node*KK*NRBF + e];
  __syncthreads();

  // gather neighbor features
  for (int e = t; e < KK*H; e += 256) {
    int kk2 = e >> 6, c = e & (H-1);
    sF0s[kk2][c] = f0i[(bbase + sIdx[kk2])*H + c];
  }
  for (int e = t; e < KK*F1W; e += 256) {
    int kk2 = e / F1W, r = e - kk2*F1W;
    sF1s[kk2][r] = f1i[(bbase + sIdx[kk2])*F1W + r];
  }
  __syncthreads();

  // build edge features E[32][176] = [f0_dst | f0_src | rbf | dot_s | dot_d]
  {
    int kk2 = t & (KK-1), part = t >> 5;     // 8 parts x 22 cols
    float dx = sDir[kk2][0], dy = sDir[kk2][1], dz = sDir[kk2][2];
    for (int c = part*22; c < part*22 + 22; ++c) {
      float v;
      if (c < 64)       v = sF0i[c];
      else if (c < 128) v = sF0s[kk2][c-64];
      else if (c < 144) v = sRbf[kk2][c-128];
      else if (c < 160) { int ch = c-144; v = sF1s[kk2][ch*3]*dx + sF1s[kk2][ch*3+1]*dy + sF1s[kk2][ch*3+2]*dz; }
      else              { int ch = c-160; v = sF1i[ch*3]*dx + sF1i[ch*3+1]*dy + sF1i[ch*3+2]*dz; }
      sE[kk2][c] = v;
    }
  }
  // q = f0 @ Wq (dst node)
  if (t < H) {
    float acc = 0.f;
    for (int i2 = 0; i2 < H; ++i2) acc = fmaf(sF0i[i2], Wq[i2*H + t], acc);
    sQ[t] = acc;
  }
  __syncthreads();

  const int k  = t & (KK-1);
  const int og = t >> 5;                     // 8 output groups of 8

  // H1 = relu(E @ We1 + be1)
  {
    float acc[8];
    #pragma unroll
    for (int j = 0; j < 8; ++j) acc[j] = be1[og*8 + j];
    for (int i2 = 0; i2 < DIN; ++i2) {
      float ev = sE[k][i2];
      const float* wr = We1 + i2*H + og*8;
      #pragma unroll
      for (int j = 0; j < 8; ++j) acc[j] = fmaf(ev, wr[j], acc[j]);
    }
    #pragma unroll
    for (int j = 0; j < 8; ++j) sHh[k][og*8 + j] = fmaxf(acc[j], 0.f);
  }
  __syncthreads();

  // M = H1 @ We2 + be2
  {
    float acc[8];
    #pragma unroll
    for (int j = 0; j < 8; ++j) acc[j] = be2[og*8 + j];
    for (int i2 = 0; i2 < H; ++i2) {
      float hv = sHh[k][i2];
      const float* wr = We2 + i2*H + og*8;
      #pragma unroll
      for (int j = 0; j < 8; ++j) acc[j] = fmaf(hv, wr[j], acc[j]);
    }
    #pragma unroll
    for (int j = 0; j < 8; ++j) sM[k][og*8 + j] = acc[j];
  }
  __syncthreads();

  // logits[k][h] = <q_h, (M @ Wk)_kh> / sqrt(DH)
  {
    float acc[8];
    #pragma unroll
    for (int j = 0; j < 8; ++j) acc[j] = 0.f;
    for (int i2 = 0; i2 < H; ++i2) {
      float mv = sM[k][i2];
      const float* wr = Wk + i2*H + og*8;
      #pragma unroll
      for (int j = 0; j < 8; ++j) acc[j] = fmaf(mv, wr[j], acc[j]);
    }
    float lg = 0.f;
    #pragma unroll
    for (int j = 0; j < 8; ++j) lg = fmaf(sQ[og*8 + j], acc[j], lg);
    sLog[k][og] = lg * 0.35355339059327373f;
  }
  __syncthreads();

  // softmax over k, per head
  if (t < HEADS) {
    float mx = -3.0e38f;
    for (int kk2 = 0; kk2 < KK; ++kk2) mx = fmaxf(mx, sLog[kk2][t]);
    float sum = 0.f;
    for (int kk2 = 0; kk2 < KK; ++kk2) { float ev = expf(sLog[kk2][t] - mx); sAtt[kk2][t] = ev; sum += ev; }
    float inv = 1.0f/sum;
    for (int kk2 = 0; kk2 < KK; ++kk2) sAtt[kk2][t] *= inv;
  }
  __syncthreads();

  // V0 = M @ Wv0 ; mv1 = M @ Wv1 ; mg1 = M @ Wg1 ; a = mean_h attn
  {
    float acc[8];
    #pragma unroll
    for (int j = 0; j < 8; ++j) acc[j] = 0.f;
    float a0 = 0.f, a1 = 0.f, b0 = 0.f, b1 = 0.f;
    for (int i2 = 0; i2 < H; ++i2) {
      float mv = sM[k][i2];
      const float* wr = Wv0 + i2*H + og*8;
      #pragma unroll
      for (int j = 0; j < 8; ++j) acc[j] = fmaf(mv, wr[j], acc[j]);
      a0 = fmaf(mv, Wv1[i2*CV + og*2    ], a0);
      a1 = fmaf(mv, Wv1[i2*CV + og*2 + 1], a1);
      b0 = fmaf(mv, Wg1[i2*CV + og*2    ], b0);
      b1 = fmaf(mv, Wg1[i2*CV + og*2 + 1], b1);
    }
    #pragma unroll
    for (int j = 0; j < 8; ++j) sV0[k][og*8 + j] = acc[j];
    sMv1[k][og*2] = a0; sMv1[k][og*2+1] = a1;
    sMg1[k][og*2] = b0; sMg1[k][og*2+1] = b1;
  }
  if (t < KK) {
    float s = 0.f;
    for (int hh = 0; hh < HEADS; ++hh) s += sAtt[t][hh];
    sA[t] = s * (1.0f/HEADS);
  }
  __syncthreads();

  // agg0[o] = sum_k attn[k][h(o)] * V0[k][o]
  if (t < H) {
    int hh = t >> 3;
    float acc = 0.f;
    for (int kk2 = 0; kk2 < KK; ++kk2) acc = fmaf(sAtt[kk2][hh], sV0[kk2][t], acc);
    sAgg[t] = acc;
  }
  __syncthreads();

  // f0_out = f0 + agg0 @ Wo0 + bo0
  if (t < H) {
    float acc = sF0i[t] + bo0[t];
    for (int i2 = 0; i2 < H; ++i2) acc = fmaf(sAgg[i2], Wo0[i2*H + t], acc);
    f0o[node*H + t] = acc;
  }
  // f1_out[c][d] = f1[c][d] + sum_k a[k]*(dir[k][d]*mv1[k][c] + mg1[k][c]*f1s[k][c][d])
  if (t >= H && t < H + F1W) {
    int r = t - H;
    int c = r / 3, d = r - c*3;
    float acc = sF1i[r];
    for (int kk2 = 0; kk2 < KK; ++kk2) {
      float v1 = sDir[kk2][d]*sMv1[kk2][c] + sMg1[kk2][c]*sF1s[kk2][c*3 + d];
      acc = fmaf(sA[kk2], v1, acc);
    }
    f1o[node*F1W + r] = acc;
  }
}

// ---------------------------------------------------------------- output
__global__ __launch_bounds__(256) void k_out(const float* __restrict__ f1,
                                             const float* __restrict__ Wout1,
                                             float* __restrict__ out) {
  int g = blockIdx.x*256 + threadIdx.x;      // node*3 + d
  if (g >= NB*NN*3) return;
  int node = g / 3, d = g - node*3;
  float acc = 0.f;
  for (int c = 0; c < CV; ++c) acc = fmaf(f1[node*F1W + c*3 + d], Wout1[c], acc);
  out[g] = acc;
}

// ---------------------------------------------------------------- launch
extern "C" void kernel_launch(void* const* d_in, const int* in_sizes, int n_in,
                              void* d_out, int out_size, void* d_ws, size_t ws_size,
                              hipStream_t stream) {
  const int*   seq   = (const int*)  d_in[0];
  const float* coord = (const float*)d_in[1];
  const int*   tptr  = (const int*)  d_in[2];
  const float* atab  = (const float*)d_in[3];
  const float* ttab  = (const float*)d_in[4];
  const float* Wp0   = (const float*)d_in[5];
  const float* bp0   = (const float*)d_in[6];
  const float* Wp1   = (const float*)d_in[7];
  const float* We1   = (const float*)d_in[8];
  const float* be1   = (const float*)d_in[9];
  const float* We2   = (const float*)d_in[10];
  const float* be2   = (const float*)d_in[11];
  const float* Wq    = (const float*)d_in[12];
  const float* Wk    = (const float*)d_in[13];
  const float* Wv0   = (const float*)d_in[14];
  const float* Wv1   = (const float*)d_in[15];
  const float* Wg1   = (const float*)d_in[16];
  const float* Wo0   = (const float*)d_in[17];
  const float* bo0   = (const float*)d_in[18];
  const float* Wout1 = (const float*)d_in[19];
  float* out = (float*)d_out;

  float* ws = (float*)d_ws;
  float* coordC = ws;                                   // 12288
  int*   idx    = (int*)(ws + 12288);                   // 131072
  float* dirn   = ws + 12288 + 131072;                  // 393216
  float* rbfb   = dirn + (size_t)NB*NN*KK*3;            // 2097152
  float* f0A    = rbfb + (size_t)NB*NN*KK*NRBF;         // 262144
  float* f0B    = f0A + (size_t)NB*NN*H;
  float* f1A    = f0B + (size_t)NB*NN*H;                // 196608
  float* f1B    = f1A + (size_t)NB*NN*F1W;

  k_center<<<NB, 256, 0, stream>>>(coord, coordC);
  k_knn<<<NB*NN, 256, 0, stream>>>(coordC, idx, dirn, rbfb);
  k_f0init<<<NB*NN*H/256, 256, 0, stream>>>(seq, tptr, atab, ttab, Wp0, bp0, f0A);
  k_f1init<<<(NB*NN*F1W + 255)/256, 256, 0, stream>>>(coordC, Wp1, f1A);

  const float* f0in = f0A; float* f0out = f0B;
  const float* f1in = f1A; float* f1out = f1B;
  for (int l = 0; l < NL; ++l) {
    k_layer<<<NB*NN, 256, 0, stream>>>(
        f0in, f1in, f0out, f1out, idx, dirn, rbfb,
        We1 + (size_t)l*DIN*H, be1 + (size_t)l*H,
        We2 + (size_t)l*H*H,   be2 + (size_t)l*H,
        Wq  + (size_t)l*H*H,   Wk  + (size_t)l*H*H,
        Wv0 + (size_t)l*H*H,   Wv1 + (size_t)l*H*CV,
        Wg1 + (size_t)l*H*CV,  Wo0 + (size_t)l*H*H,
        bo0 + (size_t)l*H);
    const float* tf0 = f0in; f0in = f0out; f0out = (float*)tf0;
    const float* tf1 = f1in; f1in = f1out; f1out = (float*)tf1;
  }
  // after 4 layers, final f1 is back in f1A (== f1in)
  k_out<<<(NB*NN*3 + 255)/256, 256, 0, stream>>>(f1in, Wout1, out);
}

// Round 5
// 516.617 us; speedup vs baseline: 3.9345x; 3.9345x over previous
//
#include <hip/hip_runtime.h>
#include <hip/hip_bf16.h>
#include <math.h>

#define NL    4
#define H     64
#define CV    16
#define NRBF  16
#define HEADS 8
#define KK    32
#define DIN   176
#define NB    2
#define NN    2048
#define F1W   (CV*3)   // 48
#define NTILES 136     // 68 hi + 68 lo per layer

typedef __attribute__((ext_vector_type(8))) short short8v;
typedef __attribute__((ext_vector_type(4))) float floatx4;

__device__ __forceinline__ ushort f2bf(float f) {
  union { float f; unsigned u; } v; v.f = f;
  unsigned r = v.u + 0x7FFFu + ((v.u >> 16) & 1u);
  return (ushort)(r >> 16);
}
__device__ __forceinline__ float bf2f(ushort s) {
  union { unsigned u; float f; } v; v.u = ((unsigned)s) << 16;
  return v.f;
}
__device__ __forceinline__ void split_bf(float v, ushort& h, ushort& l) {
  h = f2bf(v);
  l = f2bf(v - bf2f(h));
}
__device__ __forceinline__ floatx4 mfma3(short8v ah, short8v al,
                                         short8v bh, short8v bl, floatx4 acc) {
  acc = __builtin_amdgcn_mfma_f32_16x16x32_bf16(ah, bh, acc, 0, 0, 0);
  acc = __builtin_amdgcn_mfma_f32_16x16x32_bf16(ah, bl, acc, 0, 0, 0);
  acc = __builtin_amdgcn_mfma_f32_16x16x32_bf16(al, bh, acc, 0, 0, 0);
  return acc;
}

// ---------------------------------------------------------------- center
__global__ __launch_bounds__(256) void k_center(const float* __restrict__ coord,
                                                float* __restrict__ coordC) {
  __shared__ float rx[256], ry[256], rz[256];
  int b = blockIdx.x;
  const float* cb = coord + b*NN*3;
  float sx = 0.f, sy = 0.f, sz = 0.f;
  for (int i = threadIdx.x; i < NN; i += 256) {
    sx += cb[i*3+0]; sy += cb[i*3+1]; sz += cb[i*3+2];
  }
  rx[threadIdx.x] = sx; ry[threadIdx.x] = sy; rz[threadIdx.x] = sz;
  __syncthreads();
  for (int s = 128; s > 0; s >>= 1) {
    if (threadIdx.x < s) {
      rx[threadIdx.x] += rx[threadIdx.x+s];
      ry[threadIdx.x] += ry[threadIdx.x+s];
      rz[threadIdx.x] += rz[threadIdx.x+s];
    }
    __syncthreads();
  }
  float mx = rx[0]*(1.0f/NN), my = ry[0]*(1.0f/NN), mz = rz[0]*(1.0f/NN);
  float* ob = coordC + b*NN*3;
  for (int i = threadIdx.x; i < NN; i += 256) {
    ob[i*3+0] = cb[i*3+0] - mx;
    ob[i*3+1] = cb[i*3+1] - my;
    ob[i*3+2] = cb[i*3+2] - mz;
  }
}

// ---------------------------------------------------------------- knn (wave per node)
__global__ __launch_bounds__(64) void k_knn(const float* __restrict__ coordC,
                                            int* __restrict__ idx,
                                            float* __restrict__ dirn,
                                            ushort* __restrict__ rbf16) {
  __shared__ float d2s[NN];
  const int node = blockIdx.x;
  const int b = node >> 11;
  const int i = node & (NN-1);
  const int l = threadIdx.x;
  const float* cb = coordC + b*NN*3;
  const float xi = cb[i*3+0], yi = cb[i*3+1], zi = cb[i*3+2];
  const float sqi = xi*xi + yi*yi + zi*zi;
  #pragma unroll 4
  for (int it = 0; it < NN/64; ++it) {
    int j = it*64 + l;
    float xj = cb[j*3+0], yj = cb[j*3+1], zj = cb[j*3+2];
    float sqj = xj*xj + yj*yj + zj*zj;
    float dot = xi*xj + yi*yj + zi*zj;
    float v = sqi + sqj - 2.0f*dot;
    if (j == i) v += 1.0e9f;
    d2s[j] = v;
  }
  __syncthreads();
  int myselidx = 0;
  for (int s = 0; s < KK; ++s) {
    float bv = 3.0e38f; int bi = 0x7fffffff;
    #pragma unroll 8
    for (int it = 0; it < NN/64; ++it) {
      int j = it*64 + l;
      float v = d2s[j];
      if (v < bv) { bv = v; bi = j; }
    }
    #pragma unroll
    for (int off = 1; off <= 32; off <<= 1) {
      float ov = __shfl_xor(bv, off, 64);
      int   oi = __shfl_xor(bi, off, 64);
      if (ov < bv || (ov == bv && oi < bi)) { bv = ov; bi = oi; }
    }
    if (l == s) myselidx = bi;
    if (l == 0) d2s[bi] = 3.0e38f;
    __syncthreads();
  }
  if (l < KK) {
    int j = myselidx;
    idx[node*KK + l] = j;
    float rxv = cb[j*3+0] - xi, ryv = cb[j*3+1] - yi, rzv = cb[j*3+2] - zi;
    float dd = sqrtf(rxv*rxv + ryv*ryv + rzv*rzv + 1e-8f);
    float inv = 1.0f/dd;
    float* dn = dirn + (node*KK + l)*3;
    dn[0] = rxv*inv; dn[1] = ryv*inv; dn[2] = rzv*inv;
    ushort* rb = rbf16 + (size_t)(node*KK + l)*NRBF;
    const float inv2s2 = 1.0f/(2.0f*0.625f*0.625f);
    #pragma unroll
    for (int r = 0; r < NRBF; ++r) {
      float mu = (10.0f/15.0f)*(float)r;
      float dm = dd - mu;
      rb[r] = f2bf(expf(-(dm*dm)*inv2s2));
    }
  }
}

// ---------------------------------------------------------------- f0 init
__global__ __launch_bounds__(256) void k_f0init(const int* __restrict__ seq,
                                                const int* __restrict__ tptr,
                                                const float* __restrict__ atab,
                                                const float* __restrict__ ttab,
                                                const float* __restrict__ Wp0,
                                                const float* __restrict__ bp0,
                                                float* __restrict__ f0) {
  int gidx = blockIdx.x*256 + threadIdx.x;
  int node = gidx >> 6, o = gidx & (H-1);
  int s = seq[node];
  int tv = tptr[0];
  const float* ar = atab + s*32;
  const float* tr = ttab + tv*32;
  float acc = bp0[o];
  for (int i2 = 0; i2 < 32; ++i2) acc = fmaf(ar[i2], Wp0[i2*H + o], acc);
  for (int i2 = 0; i2 < 32; ++i2) acc = fmaf(tr[i2], Wp0[(32+i2)*H + o], acc);
  f0[gidx] = acc;
}

// ---------------------------------------------------------------- f1 init
__global__ __launch_bounds__(256) void k_f1init(const float* __restrict__ coordC,
                                                const float* __restrict__ Wp1,
                                                float* __restrict__ f1) {
  int gidx = blockIdx.x*256 + threadIdx.x;
  if (gidx >= NB*NN*F1W) return;
  int node = gidx / F1W;
  int r = gidx - node*F1W;
  int c = r / 3, d = r - c*3;
  f1[gidx] = coordC[node*3 + d] * Wp1[c];
}

// ---------------------------------------------------------------- weight fragment prep
// per layer: hi tiles 0..67 [We1 24|We2 8|Wk 8|Wq 8|Wv0 8|Wvg 4|Wo0 8], lo tiles 68..135
// frag: wfrag[tile][lane][j] = part(W[k = kt*32 + (lane>>4)*8 + j][col = nt*16 + (lane&15)])
__global__ __launch_bounds__(256) void k_prep(
    const float* __restrict__ We1, const float* __restrict__ We2,
    const float* __restrict__ Wq,  const float* __restrict__ Wk,
    const float* __restrict__ Wv0, const float* __restrict__ Wv1,
    const float* __restrict__ Wg1, const float* __restrict__ Wo0,
    ushort* __restrict__ wfrag) {
  int gid = blockIdx.x*256 + threadIdx.x;
  if (gid >= NL*NTILES*64) return;
  int lane = gid & 63;
  int tile = gid >> 6;
  int l = tile / NTILES;
  int tt = tile - l*NTILES;
  int part = (tt >= 68) ? 1 : 0;
  int t = part ? (tt - 68) : tt;
  int kt, nt, K = H;
  const float* src = nullptr;
  int wvg = 0;
  if (t < 24)      { kt = t>>2;           nt = t&3; src = We1 + (size_t)l*DIN*H; K = DIN; }
  else if (t < 32) { int u=t-24; kt=u>>2; nt = u&3; src = We2 + (size_t)l*H*H; }
  else if (t < 40) { int u=t-32; kt=u>>2; nt = u&3; src = Wk  + (size_t)l*H*H; }
  else if (t < 48) { int u=t-40; kt=u>>2; nt = u&3; src = Wq  + (size_t)l*H*H; }
  else if (t < 56) { int u=t-48; kt=u>>2; nt = u&3; src = Wv0 + (size_t)l*H*H; }
  else if (t < 60) { int u=t-56; kt=u>>1; nt = u&1; wvg = 1; }
  else             { int u=t-60; kt=u>>2; nt = u&3; src = Wo0 + (size_t)l*H*H; }
  ushort out[8];
  #pragma unroll
  for (int j = 0; j < 8; ++j) {
    int k = kt*32 + (lane>>4)*8 + j;
    int col = nt*16 + (lane&15);
    float v = 0.f;
    if (k < K) {
      if (wvg) v = (col < CV) ? Wv1[(size_t)l*H*CV + k*CV + col]
                              : Wg1[(size_t)l*H*CV + k*CV + (col-CV)];
      else     v = src[(size_t)k*H + col];
    }
    ushort h, lo; split_bf(v, h, lo);
    out[j] = part ? lo : h;
  }
  *(short8v*)(wfrag + (size_t)tile*512 + lane*8) = *(const short8v*)out;
}

// ---------------------------------------------------------------- fused layer (wave per node, split-bf16 MFMA)
__global__ __launch_bounds__(64) void k_layer(
    const float* __restrict__ f0i, const float* __restrict__ f1i,
    float* __restrict__ f0o, float* __restrict__ f1o,
    const int* __restrict__ idx, const float* __restrict__ dirn,
    const ushort* __restrict__ rbf16,
    const ushort* __restrict__ wfl,      // this layer's NTILES*512 fragment block
    const float* __restrict__ be1, const float* __restrict__ be2,
    const float* __restrict__ bo0)
{
  // regionA/Alo: f0src -> H1 -> (A = fp32 Mvg [32][34])
  // regionB/Blo: [rbf|dotS|dotD|0] -> M
  __shared__ __align__(16) ushort regionA  [32*72];
  __shared__ __align__(16) ushort regionAlo[32*72];
  __shared__ __align__(16) ushort regionB  [32*72];
  __shared__ __align__(16) ushort regionBlo[32*72];
  __shared__ float sF1s[32*52];            // fp32 gathered source vectors
  __shared__ __align__(16) ushort sF0h[64], sF0l[64];
  __shared__ __align__(16) ushort sAggH[64], sAggL[64];
  __shared__ float sF1d[F1W];
  __shared__ float sDir[KK][4];
  __shared__ int   sIdx[KK];
  __shared__ float sLog[KK*9];
  __shared__ float sAtt[KK*9];
  __shared__ float sA[KK];

  const int lane = threadIdx.x;
  const int node = blockIdx.x;
  const int bbase = node & ~(NN-1);

  // ---------------- stage
  float f0reg = f0i[node*H + lane];
  { ushort h, l; split_bf(f0reg, h, l); sF0h[lane] = h; sF0l[lane] = l; }
  if (lane < KK)  sIdx[lane] = idx[node*KK + lane];
  if (lane < F1W) sF1d[lane] = f1i[node*F1W + lane];
  sDir[lane/3][lane%3] = dirn[node*(KK*3) + lane];
  if (lane < 32) {
    int e = 64 + lane;
    sDir[e/3][e%3] = dirn[node*(KK*3) + e];
  }
  __syncthreads();
  #pragma unroll 8
  for (int r = 0; r < KK; ++r) {
    float v = f0i[(bbase + sIdx[r])*H + lane];
    ushort h, l; split_bf(v, h, l);
    regionA[r*72 + lane] = h; regionAlo[r*72 + lane] = l;
  }
  #pragma unroll 8
  for (int r = 0; r < KK; ++r) {
    if (lane < F1W) sF1s[r*52 + lane] = f1i[(bbase + sIdx[r])*F1W + lane];
  }
  #pragma unroll
  for (int it = 0; it < 8; ++it) {
    int p = it*64 + lane;                 // k = p>>4, c = p&15
    regionB  [(p>>4)*72 + (p&15)] = rbf16[(size_t)node*(KK*NRBF) + p];
    regionBlo[(p>>4)*72 + (p&15)] = 0;
  }
  #pragma unroll
  for (int it = 0; it < 12; ++it) {       // zero cols 48..71
    int p = it*64 + lane;
    int k = p / 24, c = 48 + p % 24;
    regionB[k*72 + c] = 0; regionBlo[k*72 + c] = 0;
  }
  __syncthreads();
  // invariants: dotS (cols 16..31), dotD (cols 32..47), fp32 then split
  #pragma unroll
  for (int it = 0; it < 8; ++it) {
    int p = it*64 + lane; int k = p>>4, ch = p&15;
    float ds_ = 0.f, dd_ = 0.f;
    #pragma unroll
    for (int d = 0; d < 3; ++d) {
      float dr = sDir[k][d];
      ds_ += sF1s[k*52 + ch*3 + d] * dr;
      dd_ += sF1d[ch*3 + d] * dr;
    }
    ushort h, l;
    split_bf(ds_, h, l); regionB[k*72 + 16 + ch] = h; regionBlo[k*72 + 16 + ch] = l;
    split_bf(dd_, h, l); regionB[k*72 + 32 + ch] = h; regionBlo[k*72 + 32 + ch] = l;
  }
  __syncthreads();

  const int r0 = lane & 15, g = lane >> 4;
  const floatx4 fz = {0.f, 0.f, 0.f, 0.f};

  // ---------------- GEMM1: H1 = relu(E @ We1 + be1), K = 192 (6 ktiles)
  floatx4 c1[2][4];
  #pragma unroll
  for (int mt = 0; mt < 2; ++mt)
    #pragma unroll
    for (int nt = 0; nt < 4; ++nt) c1[mt][nt] = fz;
  #pragma unroll
  for (int kt = 0; kt < 6; ++kt) {
    short8v a0h, a0l, a1h, a1l;
    if (kt < 2) {
      a0h = *(const short8v*)&sF0h[kt*32 + g*8];
      a0l = *(const short8v*)&sF0l[kt*32 + g*8];
      a1h = a0h; a1l = a0l;
    } else if (kt < 4) {
      int off = (kt-2)*32 + g*8;
      a0h = *(const short8v*)&regionA  [r0*72 + off];
      a0l = *(const short8v*)&regionAlo[r0*72 + off];
      a1h = *(const short8v*)&regionA  [(r0+16)*72 + off];
      a1l = *(const short8v*)&regionAlo[(r0+16)*72 + off];
    } else {
      int off = ((kt == 4) ? 0 : 32) + g*8;
      a0h = *(const short8v*)&regionB  [r0*72 + off];
      a0l = *(const short8v*)&regionBlo[r0*72 + off];
      a1h = *(const short8v*)&regionB  [(r0+16)*72 + off];
      a1l = *(const short8v*)&regionBlo[(r0+16)*72 + off];
    }
    #pragma unroll
    for (int nt = 0; nt < 4; ++nt) {
      short8v bh = *(const short8v*)&wfl[(size_t)(kt*4 + nt)*512 + lane*8];
      short8v bl = *(const short8v*)&wfl[(size_t)(68 + kt*4 + nt)*512 + lane*8];
      c1[0][nt] = mfma3(a0h, a0l, bh, bl, c1[0][nt]);
      c1[1][nt] = mfma3(a1h, a1l, bh, bl, c1[1][nt]);
    }
  }
  __syncthreads();
  #pragma unroll
  for (int nt = 0; nt < 4; ++nt) {
    float be = be1[nt*16 + r0];
    #pragma unroll
    for (int mt = 0; mt < 2; ++mt)
      #pragma unroll
      for (int i = 0; i < 4; ++i) {
        float v = fmaxf(c1[mt][nt][i] + be, 0.f);
        ushort h, l; split_bf(v, h, l);
        regionA  [(mt*16 + g*4 + i)*72 + nt*16 + r0] = h;
        regionAlo[(mt*16 + g*4 + i)*72 + nt*16 + r0] = l;
      }
  }
  __syncthreads();

  // ---------------- GEMM2: M = H1 @ We2 + be2
  floatx4 c2[2][4];
  #pragma unroll
  for (int mt = 0; mt < 2; ++mt)
    #pragma unroll
    for (int nt = 0; nt < 4; ++nt) c2[mt][nt] = fz;
  #pragma unroll
  for (int kt = 0; kt < 2; ++kt) {
    int off = kt*32 + g*8;
    short8v a0h = *(const short8v*)&regionA  [r0*72 + off];
    short8v a0l = *(const short8v*)&regionAlo[r0*72 + off];
    short8v a1h = *(const short8v*)&regionA  [(r0+16)*72 + off];
    short8v a1l = *(const short8v*)&regionAlo[(r0+16)*72 + off];
    #pragma unroll
    for (int nt = 0; nt < 4; ++nt) {
      short8v bh = *(const short8v*)&wfl[(size_t)(24 + kt*4 + nt)*512 + lane*8];
      short8v bl = *(const short8v*)&wfl[(size_t)(92 + kt*4 + nt)*512 + lane*8];
      c2[0][nt] = mfma3(a0h, a0l, bh, bl, c2[0][nt]);
      c2[1][nt] = mfma3(a1h, a1l, bh, bl, c2[1][nt]);
    }
  }
  __syncthreads();
  #pragma unroll
  for (int nt = 0; nt < 4; ++nt) {
    float be = be2[nt*16 + r0];
    #pragma unroll
    for (int mt = 0; mt < 2; ++mt)
      #pragma unroll
      for (int i = 0; i < 4; ++i) {
        ushort h, l; split_bf(c2[mt][nt][i] + be, h, l);
        regionB  [(mt*16 + g*4 + i)*72 + nt*16 + r0] = h;
        regionBlo[(mt*16 + g*4 + i)*72 + nt*16 + r0] = l;
      }
  }
  __syncthreads();

  // ---------------- q = f0 @ Wq and kk = M @ Wk
  floatx4 cq[4];
  #pragma unroll
  for (int nt = 0; nt < 4; ++nt) cq[nt] = fz;
  #pragma unroll
  for (int kt = 0; kt < 2; ++kt) {
    short8v aqh = *(const short8v*)&sF0h[kt*32 + g*8];
    short8v aql = *(const short8v*)&sF0l[kt*32 + g*8];
    #pragma unroll
    for (int nt = 0; nt < 4; ++nt) {
      short8v bh = *(const short8v*)&wfl[(size_t)(40 + kt*4 + nt)*512 + lane*8];
      short8v bl = *(const short8v*)&wfl[(size_t)(108 + kt*4 + nt)*512 + lane*8];
      cq[nt] = mfma3(aqh, aql, bh, bl, cq[nt]);
    }
  }
  floatx4 ck[2][4];
  #pragma unroll
  for (int mt = 0; mt < 2; ++mt)
    #pragma unroll
    for (int nt = 0; nt < 4; ++nt) ck[mt][nt] = fz;
  #pragma unroll
  for (int kt = 0; kt < 2; ++kt) {
    int off = kt*32 + g*8;
    short8v a0h = *(const short8v*)&regionB  [r0*72 + off];
    short8v a0l = *(const short8v*)&regionBlo[r0*72 + off];
    short8v a1h = *(const short8v*)&regionB  [(r0+16)*72 + off];
    short8v a1l = *(const short8v*)&regionBlo[(r0+16)*72 + off];
    #pragma unroll
    for (int nt = 0; nt < 4; ++nt) {
      short8v bh = *(const short8v*)&wfl[(size_t)(32 + kt*4 + nt)*512 + lane*8];
      short8v bl = *(const short8v*)&wfl[(size_t)(100 + kt*4 + nt)*512 + lane*8];
      ck[0][nt] = mfma3(a0h, a0l, bh, bl, ck[0][nt]);
      ck[1][nt] = mfma3(a1h, a1l, bh, bl, ck[1][nt]);
    }
  }
  // logits: in-register head reduction
  #pragma unroll
  for (int mt = 0; mt < 2; ++mt)
    #pragma unroll
    for (int nt = 0; nt < 4; ++nt)
      #pragma unroll
      for (int i = 0; i < 4; ++i) {
        float v = ck[mt][nt][i] * cq[nt][0];
        v += __shfl_xor(v, 1, 64);
        v += __shfl_xor(v, 2, 64);
        v += __shfl_xor(v, 4, 64);
        if ((lane & 7) == 0)
          sLog[(mt*16 + g*4 + i)*9 + nt*2 + (r0 >> 3)] = v * 0.35355339059327373f;
      }
  __syncthreads();

  // ---------------- softmax over k per head; sA = mean over heads
  {
    int h = lane & 7, seg = lane >> 3;
    float l0[4];
    float mx = -3.0e38f;
    #pragma unroll
    for (int i = 0; i < 4; ++i) { l0[i] = sLog[(seg*4 + i)*9 + h]; mx = fmaxf(mx, l0[i]); }
    #pragma unroll
    for (int off = 8; off <= 32; off <<= 1) mx = fmaxf(mx, __shfl_xor(mx, off, 64));
    float e0[4], sum = 0.f;
    #pragma unroll
    for (int i = 0; i < 4; ++i) { e0[i] = expf(l0[i] - mx); sum += e0[i]; }
    #pragma unroll
    for (int off = 8; off <= 32; off <<= 1) sum += __shfl_xor(sum, off, 64);
    float inv = 1.0f / sum;
    #pragma unroll
    for (int i = 0; i < 4; ++i) {
      float a = e0[i] * inv;
      sAtt[(seg*4 + i)*9 + h] = a;
      float tt = a;
      tt += __shfl_xor(tt, 1, 64);
      tt += __shfl_xor(tt, 2, 64);
      tt += __shfl_xor(tt, 4, 64);
      if (h == 0) sA[seg*4 + i] = tt * 0.125f;
    }
  }
  __syncthreads();

  // ---------------- V0 = M @ Wv0, agg0 in-register
  floatx4 cv[2][4];
  #pragma unroll
  for (int mt = 0; mt < 2; ++mt)
    #pragma unroll
    for (int nt = 0; nt < 4; ++nt) cv[mt][nt] = fz;
  #pragma unroll
  for (int kt = 0; kt < 2; ++kt) {
    int off = kt*32 + g*8;
    short8v a0h = *(const short8v*)&regionB  [r0*72 + off];
    short8v a0l = *(const short8v*)&regionBlo[r0*72 + off];
    short8v a1h = *(const short8v*)&regionB  [(r0+16)*72 + off];
    short8v a1l = *(const short8v*)&regionBlo[(r0+16)*72 + off];
    #pragma unroll
    for (int nt = 0; nt < 4; ++nt) {
      short8v bh = *(const short8v*)&wfl[(size_t)(48 + kt*4 + nt)*512 + lane*8];
      short8v bl = *(const short8v*)&wfl[(size_t)(116 + kt*4 + nt)*512 + lane*8];
      cv[0][nt] = mfma3(a0h, a0l, bh, bl, cv[0][nt]);
      cv[1][nt] = mfma3(a1h, a1l, bh, bl, cv[1][nt]);
    }
  }
  {
    int hsub = r0 >> 3;
    #pragma unroll
    for (int nt = 0; nt < 4; ++nt) {
      float p = 0.f;
      #pragma unroll
      for (int mt = 0; mt < 2; ++mt)
        #pragma unroll
        for (int i = 0; i < 4; ++i)
          p += sAtt[(mt*16 + g*4 + i)*9 + nt*2 + hsub] * cv[mt][nt][i];
      p += __shfl_xor(p, 16, 64);
      p += __shfl_xor(p, 32, 64);
      if (g == 0) {
        ushort h, l; split_bf(p, h, l);
        sAggH[nt*16 + r0] = h; sAggL[nt*16 + r0] = l;
      }
    }
  }

  // ---------------- Mvg = M @ [Wv1|Wg1]
  floatx4 cvg[2][2];
  #pragma unroll
  for (int mt = 0; mt < 2; ++mt)
    #pragma unroll
    for (int nt = 0; nt < 2; ++nt) cvg[mt][nt] = fz;
  #pragma unroll
  for (int kt = 0; kt < 2; ++kt) {
    int off = kt*32 + g*8;
    short8v a0h = *(const short8v*)&regionB  [r0*72 + off];
    short8v a0l = *(const short8v*)&regionBlo[r0*72 + off];
    short8v a1h = *(const short8v*)&regionB  [(r0+16)*72 + off];
    short8v a1l = *(const short8v*)&regionBlo[(r0+16)*72 + off];
    #pragma unroll
    for (int nt = 0; nt < 2; ++nt) {
      short8v bh = *(const short8v*)&wfl[(size_t)(56 + kt*2 + nt)*512 + lane*8];
      short8v bl = *(const short8v*)&wfl[(size_t)(124 + kt*2 + nt)*512 + lane*8];
      cvg[0][nt] = mfma3(a0h, a0l, bh, bl, cvg[0][nt]);
      cvg[1][nt] = mfma3(a1h, a1l, bh, bl, cvg[1][nt]);
    }
  }
  __syncthreads();    // regionA fully dead -> reuse as fp32 Mvg [32][34]
  {
    float* sMvg = (float*)regionA;
    #pragma unroll
    for (int mt = 0; mt < 2; ++mt)
      #pragma unroll
      for (int nt = 0; nt < 2; ++nt)
        #pragma unroll
        for (int i = 0; i < 4; ++i)
          sMvg[(mt*16 + g*4 + i)*34 + nt*16 + r0] = cvg[mt][nt][i];
  }
  __syncthreads();

  // ---------------- f0 out: f0 + agg0 @ Wo0 + bo0
  floatx4 co[4];
  #pragma unroll
  for (int nt = 0; nt < 4; ++nt) co[nt] = fz;
  #pragma unroll
  for (int kt = 0; kt < 2; ++kt) {
    short8v aah = *(const short8v*)&sAggH[kt*32 + g*8];
    short8v aal = *(const short8v*)&sAggL[kt*32 + g*8];
    #pragma unroll
    for (int nt = 0; nt < 4; ++nt) {
      short8v bh = *(const short8v*)&wfl[(size_t)(60 + kt*4 + nt)*512 + lane*8];
      short8v bl = *(const short8v*)&wfl[(size_t)(128 + kt*4 + nt)*512 + lane*8];
      co[nt] = mfma3(aah, aal, bh, bl, co[nt]);
    }
  }
  {
    int ntl = lane >> 4;
    float v = (ntl == 0) ? co[0][0] : (ntl == 1) ? co[1][0] : (ntl == 2) ? co[2][0] : co[3][0];
    f0o[node*H + lane] = f0reg + v + bo0[lane];
  }

  // ---------------- f1 out (all fp32)
  if (lane < F1W) {
    const float* sMvg = (const float*)regionA;
    int ch = lane / 3, d = lane - ch*3;
    float acc = sF1d[lane];
    #pragma unroll 8
    for (int k = 0; k < KK; ++k) {
      float a   = sA[k];
      float mv1 = sMvg[k*34 + ch];
      float mg1 = sMvg[k*34 + 16 + ch];
      float f1s = sF1s[k*52 + lane];
      acc += a * (sDir[k][d]*mv1 + mg1*f1s);
    }
    f1o[node*F1W + lane] = acc;
  }
}

// ---------------------------------------------------------------- output
__global__ __launch_bounds__(256) void k_out(const float* __restrict__ f1,
                                             const float* __restrict__ Wout1,
                                             float* __restrict__ out) {
  int gidx = blockIdx.x*256 + threadIdx.x;
  if (gidx >= NB*NN*3) return;
  int node = gidx / 3, d = gidx - node*3;
  float acc = 0.f;
  for (int c = 0; c < CV; ++c) acc = fmaf(f1[node*F1W + c*3 + d], Wout1[c], acc);
  out[gidx] = acc;
}

// ---------------------------------------------------------------- launch
extern "C" void kernel_launch(void* const* d_in, const int* in_sizes, int n_in,
                              void* d_out, int out_size, void* d_ws, size_t ws_size,
                              hipStream_t stream) {
  const int*   seq   = (const int*)  d_in[0];
  const float* coord = (const float*)d_in[1];
  const int*   tptr  = (const int*)  d_in[2];
  const float* atab  = (const float*)d_in[3];
  const float* ttab  = (const float*)d_in[4];
  const float* Wp0   = (const float*)d_in[5];
  const float* bp0   = (const float*)d_in[6];
  const float* Wp1   = (const float*)d_in[7];
  const float* We1   = (const float*)d_in[8];
  const float* be1   = (const float*)d_in[9];
  const float* We2   = (const float*)d_in[10];
  const float* be2   = (const float*)d_in[11];
  const float* Wq    = (const float*)d_in[12];
  const float* Wk    = (const float*)d_in[13];
  const float* Wv0   = (const float*)d_in[14];
  const float* Wv1   = (const float*)d_in[15];
  const float* Wg1   = (const float*)d_in[16];
  const float* Wo0   = (const float*)d_in[17];
  const float* bo0   = (const float*)d_in[18];
  const float* Wout1 = (const float*)d_in[19];
  float* out = (float*)d_out;

  float* ws = (float*)d_ws;
  float*  coordC = ws;                                    // 12288
  int*    idxb   = (int*)(ws + 12288);                    // 131072
  float*  dirn   = ws + 12288 + 131072;                   // 393216
  float*  f0A    = dirn + (size_t)NB*NN*KK*3;             // 262144
  float*  f0B    = f0A + (size_t)NB*NN*H;                 // 262144
  float*  f1A    = f0B + (size_t)NB*NN*H;                 // 196608
  float*  f1B    = f1A + (size_t)NB*NN*F1W;               // 196608
  ushort* rbf16  = (ushort*)(f1B + (size_t)NB*NN*F1W);    // 2097152 ushorts
  ushort* wfrag  = rbf16 + (size_t)NB*NN*KK*NRBF;         // NL*136*512 ushorts

  k_center<<<NB, 256, 0, stream>>>(coord, coordC);
  k_knn<<<NB*NN, 64, 0, stream>>>(coordC, idxb, dirn, rbf16);
  k_f0init<<<NB*NN*H/256, 256, 0, stream>>>(seq, tptr, atab, ttab, Wp0, bp0, f0A);
  k_f1init<<<(NB*NN*F1W + 255)/256, 256, 0, stream>>>(coordC, Wp1, f1A);
  k_prep<<<(NL*NTILES*64 + 255)/256, 256, 0, stream>>>(We1, We2, Wq, Wk, Wv0, Wv1, Wg1, Wo0, wfrag);

  const float* f0in = f0A; float* f0out = f0B;
  const float* f1in = f1A; float* f1out = f1B;
  for (int l = 0; l < NL; ++l) {
    k_layer<<<NB*NN, 64, 0, stream>>>(
        f0in, f1in, f0out, f1out, idxb, dirn, rbf16,
        wfrag + (size_t)l*NTILES*512,
        be1 + (size_t)l*H, be2 + (size_t)l*H, bo0 + (size_t)l*H);
    const float* tf0 = f0in; f0in = f0out; f0out = (float*)tf0;
    const float* tf1 = f1in; f1in = f1out; f1out = (float*)tf1;
  }
  k_out<<<(NB*NN*3 + 255)/256, 256, 0, stream>>>(f1in, Wout1, out);
}

// Round 6
// 429.139 us; speedup vs baseline: 4.7365x; 1.2038x over previous
//
#include <hip/hip_runtime.h>
#include <hip/hip_bf16.h>
#include <math.h>

#define NL    4
#define H     64
#define CV    16
#define NRBF  16
#define HEADS 8
#define KK    32
#define DIN   176
#define NB    2
#define NN    2048
#define F1W   (CV*3)   // 48
#define NTILES 136     // 68 hi + 68 lo per layer

typedef __attribute__((ext_vector_type(8))) short short8v;
typedef __attribute__((ext_vector_type(4))) float floatx4;

__device__ __forceinline__ ushort f2bf(float f) {
  union { float f; unsigned u; } v; v.f = f;
  unsigned r = v.u + 0x7FFFu + ((v.u >> 16) & 1u);
  return (ushort)(r >> 16);
}
__device__ __forceinline__ float bf2f(ushort s) {
  union { unsigned u; float f; } v; v.u = ((unsigned)s) << 16;
  return v.f;
}
__device__ __forceinline__ void split_bf(float v, ushort& h, ushort& l) {
  h = f2bf(v);
  l = f2bf(v - bf2f(h));
}
__device__ __forceinline__ floatx4 mfma3(short8v ah, short8v al,
                                         short8v bh, short8v bl, floatx4 acc) {
  acc = __builtin_amdgcn_mfma_f32_16x16x32_bf16(ah, bh, acc, 0, 0, 0);
  acc = __builtin_amdgcn_mfma_f32_16x16x32_bf16(ah, bl, acc, 0, 0, 0);
  acc = __builtin_amdgcn_mfma_f32_16x16x32_bf16(al, bh, acc, 0, 0, 0);
  return acc;
}

// ---------------------------------------------------------------- center
__global__ __launch_bounds__(256) void k_center(const float* __restrict__ coord,
                                                float* __restrict__ coordC) {
  __shared__ float rx[256], ry[256], rz[256];
  int b = blockIdx.x;
  const float* cb = coord + b*NN*3;
  float sx = 0.f, sy = 0.f, sz = 0.f;
  for (int i = threadIdx.x; i < NN; i += 256) {
    sx += cb[i*3+0]; sy += cb[i*3+1]; sz += cb[i*3+2];
  }
  rx[threadIdx.x] = sx; ry[threadIdx.x] = sy; rz[threadIdx.x] = sz;
  __syncthreads();
  for (int s = 128; s > 0; s >>= 1) {
    if (threadIdx.x < s) {
      rx[threadIdx.x] += rx[threadIdx.x+s];
      ry[threadIdx.x] += ry[threadIdx.x+s];
      rz[threadIdx.x] += rz[threadIdx.x+s];
    }
    __syncthreads();
  }
  float mx = rx[0]*(1.0f/NN), my = ry[0]*(1.0f/NN), mz = rz[0]*(1.0f/NN);
  float* ob = coordC + b*NN*3;
  for (int i = threadIdx.x; i < NN; i += 256) {
    ob[i*3+0] = cb[i*3+0] - mx;
    ob[i*3+1] = cb[i*3+1] - my;
    ob[i*3+2] = cb[i*3+2] - mz;
  }
}

// ---------------------------------------------------------------- knn (wave per node)
__global__ __launch_bounds__(64) void k_knn(const float* __restrict__ coordC,
                                            int* __restrict__ idx,
                                            float* __restrict__ dirn,
                                            ushort* __restrict__ rbf16) {
  __shared__ float d2s[NN];
  const int node = blockIdx.x;
  const int b = node >> 11;
  const int i = node & (NN-1);
  const int l = threadIdx.x;
  const float* cb = coordC + b*NN*3;
  const float xi = cb[i*3+0], yi = cb[i*3+1], zi = cb[i*3+2];
  const float sqi = xi*xi + yi*yi + zi*zi;
  #pragma unroll 4
  for (int it = 0; it < NN/64; ++it) {
    int j = it*64 + l;
    float xj = cb[j*3+0], yj = cb[j*3+1], zj = cb[j*3+2];
    float sqj = xj*xj + yj*yj + zj*zj;
    float dot = xi*xj + yi*yj + zi*zj;
    float v = sqi + sqj - 2.0f*dot;
    if (j == i) v += 1.0e9f;
    d2s[j] = v;
  }
  __syncthreads();
  int myselidx = 0;
  for (int s = 0; s < KK; ++s) {
    float bv = 3.0e38f; int bi = 0x7fffffff;
    #pragma unroll 8
    for (int it = 0; it < NN/64; ++it) {
      int j = it*64 + l;
      float v = d2s[j];
      if (v < bv) { bv = v; bi = j; }
    }
    #pragma unroll
    for (int off = 1; off <= 32; off <<= 1) {
      float ov = __shfl_xor(bv, off, 64);
      int   oi = __shfl_xor(bi, off, 64);
      if (ov < bv || (ov == bv && oi < bi)) { bv = ov; bi = oi; }
    }
    if (l == s) myselidx = bi;
    if (l == 0) d2s[bi] = 3.0e38f;
    __syncthreads();
  }
  if (l < KK) {
    int j = myselidx;
    idx[node*KK + l] = j;
    float rxv = cb[j*3+0] - xi, ryv = cb[j*3+1] - yi, rzv = cb[j*3+2] - zi;
    float dd = sqrtf(rxv*rxv + ryv*ryv + rzv*rzv + 1e-8f);
    float inv = 1.0f/dd;
    float* dn = dirn + (node*KK + l)*3;
    dn[0] = rxv*inv; dn[1] = ryv*inv; dn[2] = rzv*inv;
    ushort* rb = rbf16 + (size_t)(node*KK + l)*NRBF;
    const float inv2s2 = 1.0f/(2.0f*0.625f*0.625f);
    #pragma unroll
    for (int r = 0; r < NRBF; ++r) {
      float mu = (10.0f/15.0f)*(float)r;
      float dm = dd - mu;
      rb[r] = f2bf(expf(-(dm*dm)*inv2s2));
    }
  }
}

// ---------------------------------------------------------------- f0 init
__global__ __launch_bounds__(256) void k_f0init(const int* __restrict__ seq,
                                                const int* __restrict__ tptr,
                                                const float* __restrict__ atab,
                                                const float* __restrict__ ttab,
                                                const float* __restrict__ Wp0,
                                                const float* __restrict__ bp0,
                                                float* __restrict__ f0) {
  int gidx = blockIdx.x*256 + threadIdx.x;
  int node = gidx >> 6, o = gidx & (H-1);
  int s = seq[node];
  int tv = tptr[0];
  const float* ar = atab + s*32;
  const float* tr = ttab + tv*32;
  float acc = bp0[o];
  for (int i2 = 0; i2 < 32; ++i2) acc = fmaf(ar[i2], Wp0[i2*H + o], acc);
  for (int i2 = 0; i2 < 32; ++i2) acc = fmaf(tr[i2], Wp0[(32+i2)*H + o], acc);
  f0[gidx] = acc;
}

// ---------------------------------------------------------------- f1 init
__global__ __launch_bounds__(256) void k_f1init(const float* __restrict__ coordC,
                                                const float* __restrict__ Wp1,
                                                float* __restrict__ f1) {
  int gidx = blockIdx.x*256 + threadIdx.x;
  if (gidx >= NB*NN*F1W) return;
  int node = gidx / F1W;
  int r = gidx - node*F1W;
  int c = r / 3, d = r - c*3;
  f1[gidx] = coordC[node*3 + d] * Wp1[c];
}

// ---------------------------------------------------------------- weight fragment prep
__global__ __launch_bounds__(256) void k_prep(
    const float* __restrict__ We1, const float* __restrict__ We2,
    const float* __restrict__ Wq,  const float* __restrict__ Wk,
    const float* __restrict__ Wv0, const float* __restrict__ Wv1,
    const float* __restrict__ Wg1, const float* __restrict__ Wo0,
    ushort* __restrict__ wfrag) {
  int gid = blockIdx.x*256 + threadIdx.x;
  if (gid >= NL*NTILES*64) return;
  int lane = gid & 63;
  int tile = gid >> 6;
  int l = tile / NTILES;
  int tt = tile - l*NTILES;
  int part = (tt >= 68) ? 1 : 0;
  int t = part ? (tt - 68) : tt;
  int kt, nt, K = H;
  const float* src = nullptr;
  int wvg = 0;
  if (t < 24)      { kt = t>>2;           nt = t&3; src = We1 + (size_t)l*DIN*H; K = DIN; }
  else if (t < 32) { int u=t-24; kt=u>>2; nt = u&3; src = We2 + (size_t)l*H*H; }
  else if (t < 40) { int u=t-32; kt=u>>2; nt = u&3; src = Wk  + (size_t)l*H*H; }
  else if (t < 48) { int u=t-40; kt=u>>2; nt = u&3; src = Wq  + (size_t)l*H*H; }
  else if (t < 56) { int u=t-48; kt=u>>2; nt = u&3; src = Wv0 + (size_t)l*H*H; }
  else if (t < 60) { int u=t-56; kt=u>>1; nt = u&1; wvg = 1; }
  else             { int u=t-60; kt=u>>2; nt = u&3; src = Wo0 + (size_t)l*H*H; }
  ushort out[8];
  #pragma unroll
  for (int j = 0; j < 8; ++j) {
    int k = kt*32 + (lane>>4)*8 + j;
    int col = nt*16 + (lane&15);
    float v = 0.f;
    if (k < K) {
      if (wvg) v = (col < CV) ? Wv1[(size_t)l*H*CV + k*CV + col]
                              : Wg1[(size_t)l*H*CV + k*CV + (col-CV)];
      else     v = src[(size_t)k*H + col];
    }
    ushort h, lo; split_bf(v, h, lo);
    out[j] = part ? lo : h;
  }
  *(short8v*)(wfrag + (size_t)tile*512 + lane*8) = *(const short8v*)out;
}

// ---------------------------------------------------------------- fused layer
// 128 threads = 2 waves cooperating on ONE node; wave w owns output rows mt=w.
__global__ __launch_bounds__(128) void k_layer(
    const float* __restrict__ f0i, const float* __restrict__ f1i,
    float* __restrict__ f0o, float* __restrict__ f1o,
    const int* __restrict__ idx, const float* __restrict__ dirn,
    const ushort* __restrict__ rbf16,
    const ushort* __restrict__ wfl,
    const float* __restrict__ be1, const float* __restrict__ be2,
    const float* __restrict__ bo0)
{
  __shared__ __align__(16) ushort regionA  [32*72];   // f0src -> H1 -> fp32 Mvg[32][34]
  __shared__ __align__(16) ushort regionAlo[32*72];
  __shared__ __align__(16) ushort regionB  [32*72];   // [rbf|dotS|dotD|0] -> M
  __shared__ __align__(16) ushort regionBlo[32*72];
  __shared__ float sF1s[32*52];
  __shared__ __align__(16) ushort sF0h[64], sF0l[64];
  __shared__ __align__(16) ushort sAggH[64], sAggL[64];
  __shared__ float sF1d[F1W];
  __shared__ float sDir[KK][4];
  __shared__ int   sIdx[KK];
  __shared__ float sLog[KK*9];
  __shared__ float sAtt[KK*9];
  __shared__ float sA[KK];
  __shared__ float sQ[64];
  __shared__ float sAggP[2][64];

  const int t    = threadIdx.x;
  const int wid  = t >> 6;
  const int lane = t & 63;
  const int node = blockIdx.x;
  const int bbase = node & ~(NN-1);

  // ---------------- stage phase 0
  float f0reg = 0.f;
  if (wid == 0) {
    f0reg = f0i[node*H + lane];
    ushort h, l; split_bf(f0reg, h, l); sF0h[lane] = h; sF0l[lane] = l;
  } else {
    if (lane < KK)  sIdx[lane] = idx[node*KK + lane];
    if (lane < F1W) sF1d[lane] = f1i[node*F1W + lane];
  }
  if (t < 96) sDir[t/3][t%3] = dirn[node*(KK*3) + t];
  __syncthreads();

  // ---------------- gather (wave w: rows w*16..w*16+15)
  #pragma unroll 4
  for (int r = 0; r < 16; ++r) {
    int rr = wid*16 + r;
    float v = f0i[(bbase + sIdx[rr])*H + lane];
    ushort h, l; split_bf(v, h, l);
    regionA[rr*72 + lane] = h; regionAlo[rr*72 + lane] = l;
  }
  #pragma unroll 4
  for (int r = 0; r < 16; ++r) {
    int rr = wid*16 + r;
    if (lane < F1W) sF1s[rr*52 + lane] = f1i[(bbase + sIdx[rr])*F1W + lane];
  }
  #pragma unroll
  for (int it = 0; it < 4; ++it) {        // rbf: 512 elems
    int p = it*128 + t;
    regionB  [(p>>4)*72 + (p&15)] = rbf16[(size_t)node*(KK*NRBF) + p];
    regionBlo[(p>>4)*72 + (p&15)] = 0;
  }
  #pragma unroll
  for (int it = 0; it < 4; ++it) {        // zero cols 48..63
    int p = it*128 + t;
    int k = p >> 4, c = 48 + (p & 15);
    regionB[k*72 + c] = 0; regionBlo[k*72 + c] = 0;
  }
  __syncthreads();
  // dot invariants (512 elems over 128 threads)
  #pragma unroll
  for (int it = 0; it < 4; ++it) {
    int p = it*128 + t; int k = p>>4, ch = p&15;
    float ds_ = 0.f, dd_ = 0.f;
    #pragma unroll
    for (int d = 0; d < 3; ++d) {
      float dr = sDir[k][d];
      ds_ += sF1s[k*52 + ch*3 + d] * dr;
      dd_ += sF1d[ch*3 + d] * dr;
    }
    ushort h, l;
    split_bf(ds_, h, l); regionB[k*72 + 16 + ch] = h; regionBlo[k*72 + 16 + ch] = l;
    split_bf(dd_, h, l); regionB[k*72 + 32 + ch] = h; regionBlo[k*72 + 32 + ch] = l;
  }
  __syncthreads();

  const int r0 = lane & 15, g = lane >> 4;
  const int mrow = wid*16 + r0;           // this wave's A row
  const floatx4 fz = {0.f, 0.f, 0.f, 0.f};

  // ---------------- P1: GEMM1 H1 = relu(E @ We1 + be1) — rows mt=wid
  floatx4 c1[4];
  #pragma unroll
  for (int nt = 0; nt < 4; ++nt) c1[nt] = fz;
  #pragma unroll
  for (int kt = 0; kt < 6; ++kt) {
    short8v ah, al;
    if (kt < 2) {
      ah = *(const short8v*)&sF0h[kt*32 + g*8];
      al = *(const short8v*)&sF0l[kt*32 + g*8];
    } else if (kt < 4) {
      int off = (kt-2)*32 + g*8;
      ah = *(const short8v*)&regionA  [mrow*72 + off];
      al = *(const short8v*)&regionAlo[mrow*72 + off];
    } else {
      int off = ((kt == 4) ? 0 : 32) + g*8;
      ah = *(const short8v*)&regionB  [mrow*72 + off];
      al = *(const short8v*)&regionBlo[mrow*72 + off];
    }
    #pragma unroll
    for (int nt = 0; nt < 4; ++nt) {
      short8v bh = *(const short8v*)&wfl[(size_t)(kt*4 + nt)*512 + lane*8];
      short8v bl = *(const short8v*)&wfl[(size_t)(68 + kt*4 + nt)*512 + lane*8];
      c1[nt] = mfma3(ah, al, bh, bl, c1[nt]);
    }
  }
  __syncthreads();
  #pragma unroll
  for (int nt = 0; nt < 4; ++nt) {
    float be = be1[nt*16 + r0];
    #pragma unroll
    for (int i = 0; i < 4; ++i) {
      float v = fmaxf(c1[nt][i] + be, 0.f);
      ushort h, l; split_bf(v, h, l);
      regionA  [(wid*16 + g*4 + i)*72 + nt*16 + r0] = h;
      regionAlo[(wid*16 + g*4 + i)*72 + nt*16 + r0] = l;
    }
  }
  __syncthreads();

  // ---------------- P2: GEMM2 M = H1 @ We2 + be2 — rows mt=wid
  floatx4 c2[4];
  #pragma unroll
  for (int nt = 0; nt < 4; ++nt) c2[nt] = fz;
  #pragma unroll
  for (int kt = 0; kt < 2; ++kt) {
    int off = kt*32 + g*8;
    short8v ah = *(const short8v*)&regionA  [mrow*72 + off];
    short8v al = *(const short8v*)&regionAlo[mrow*72 + off];
    #pragma unroll
    for (int nt = 0; nt < 4; ++nt) {
      short8v bh = *(const short8v*)&wfl[(size_t)(24 + kt*4 + nt)*512 + lane*8];
      short8v bl = *(const short8v*)&wfl[(size_t)(92 + kt*4 + nt)*512 + lane*8];
      c2[nt] = mfma3(ah, al, bh, bl, c2[nt]);
    }
  }
  __syncthreads();
  #pragma unroll
  for (int nt = 0; nt < 4; ++nt) {
    float be = be2[nt*16 + r0];
    #pragma unroll
    for (int i = 0; i < 4; ++i) {
      ushort h, l; split_bf(c2[nt][i] + be, h, l);
      regionB  [(wid*16 + g*4 + i)*72 + nt*16 + r0] = h;
      regionBlo[(wid*16 + g*4 + i)*72 + nt*16 + r0] = l;
    }
  }
  __syncthreads();

  // ---------------- P3: wave0 q = f0@Wq -> sQ ; wave1 ck(mt=1)
  floatx4 ck[4];
  #pragma unroll
  for (int nt = 0; nt < 4; ++nt) ck[nt] = fz;
  if (wid == 0) {
    floatx4 cq[4];
    #pragma unroll
    for (int nt = 0; nt < 4; ++nt) cq[nt] = fz;
    #pragma unroll
    for (int kt = 0; kt < 2; ++kt) {
      short8v ah = *(const short8v*)&sF0h[kt*32 + g*8];
      short8v al = *(const short8v*)&sF0l[kt*32 + g*8];
      #pragma unroll
      for (int nt = 0; nt < 4; ++nt) {
        short8v bh = *(const short8v*)&wfl[(size_t)(40 + kt*4 + nt)*512 + lane*8];
        short8v bl = *(const short8v*)&wfl[(size_t)(108 + kt*4 + nt)*512 + lane*8];
        cq[nt] = mfma3(ah, al, bh, bl, cq[nt]);
      }
    }
    if (g == 0) {
      #pragma unroll
      for (int nt = 0; nt < 4; ++nt) sQ[nt*16 + r0] = cq[nt][0];
    }
  } else {
    #pragma unroll
    for (int kt = 0; kt < 2; ++kt) {
      int off = kt*32 + g*8;
      short8v ah = *(const short8v*)&regionB  [mrow*72 + off];
      short8v al = *(const short8v*)&regionBlo[mrow*72 + off];
      #pragma unroll
      for (int nt = 0; nt < 4; ++nt) {
        short8v bh = *(const short8v*)&wfl[(size_t)(32 + kt*4 + nt)*512 + lane*8];
        short8v bl = *(const short8v*)&wfl[(size_t)(100 + kt*4 + nt)*512 + lane*8];
        ck[nt] = mfma3(ah, al, bh, bl, ck[nt]);
      }
    }
  }
  __syncthreads();

  // ---------------- P4: wave0 ck(mt=0); both: logits for own rows; wave1: V0(mt=1)
  floatx4 cv[4];
  #pragma unroll
  for (int nt = 0; nt < 4; ++nt) cv[nt] = fz;
  if (wid == 0) {
    #pragma unroll
    for (int kt = 0; kt < 2; ++kt) {
      int off = kt*32 + g*8;
      short8v ah = *(const short8v*)&regionB  [mrow*72 + off];
      short8v al = *(const short8v*)&regionBlo[mrow*72 + off];
      #pragma unroll
      for (int nt = 0; nt < 4; ++nt) {
        short8v bh = *(const short8v*)&wfl[(size_t)(32 + kt*4 + nt)*512 + lane*8];
        short8v bl = *(const short8v*)&wfl[(size_t)(100 + kt*4 + nt)*512 + lane*8];
        ck[nt] = mfma3(ah, al, bh, bl, ck[nt]);
      }
    }
  } else {
    #pragma unroll
    for (int kt = 0; kt < 2; ++kt) {
      int off = kt*32 + g*8;
      short8v ah = *(const short8v*)&regionB  [mrow*72 + off];
      short8v al = *(const short8v*)&regionBlo[mrow*72 + off];
      #pragma unroll
      for (int nt = 0; nt < 4; ++nt) {
        short8v bh = *(const short8v*)&wfl[(size_t)(48 + kt*4 + nt)*512 + lane*8];
        short8v bl = *(const short8v*)&wfl[(size_t)(116 + kt*4 + nt)*512 + lane*8];
        cv[nt] = mfma3(ah, al, bh, bl, cv[nt]);
      }
    }
  }
  {
    float qv[4];
    #pragma unroll
    for (int nt = 0; nt < 4; ++nt) qv[nt] = sQ[nt*16 + r0];
    #pragma unroll
    for (int nt = 0; nt < 4; ++nt)
      #pragma unroll
      for (int i = 0; i < 4; ++i) {
        float v = ck[nt][i] * qv[nt];
        v += __shfl_xor(v, 1, 64);
        v += __shfl_xor(v, 2, 64);
        v += __shfl_xor(v, 4, 64);
        if ((lane & 7) == 0)
          sLog[(wid*16 + g*4 + i)*9 + nt*2 + (r0 >> 3)] = v * 0.35355339059327373f;
      }
  }
  __syncthreads();

  // ---------------- P5: wave1 softmax ; wave0 V0(mt=0) + Mvg(mt=0)
  floatx4 cvg[2];
  cvg[0] = fz; cvg[1] = fz;
  if (wid == 1) {
    int h = lane & 7, seg = lane >> 3;
    float l0[4];
    float mx = -3.0e38f;
    #pragma unroll
    for (int i = 0; i < 4; ++i) { l0[i] = sLog[(seg*4 + i)*9 + h]; mx = fmaxf(mx, l0[i]); }
    #pragma unroll
    for (int off = 8; off <= 32; off <<= 1) mx = fmaxf(mx, __shfl_xor(mx, off, 64));
    float e0[4], sum = 0.f;
    #pragma unroll
    for (int i = 0; i < 4; ++i) { e0[i] = expf(l0[i] - mx); sum += e0[i]; }
    #pragma unroll
    for (int off = 8; off <= 32; off <<= 1) sum += __shfl_xor(sum, off, 64);
    float inv = 1.0f / sum;
    #pragma unroll
    for (int i = 0; i < 4; ++i) {
      float a = e0[i] * inv;
      sAtt[(seg*4 + i)*9 + h] = a;
      float tt = a;
      tt += __shfl_xor(tt, 1, 64);
      tt += __shfl_xor(tt, 2, 64);
      tt += __shfl_xor(tt, 4, 64);
      if (h == 0) sA[seg*4 + i] = tt * 0.125f;
    }
  } else {
    #pragma unroll
    for (int kt = 0; kt < 2; ++kt) {
      int off = kt*32 + g*8;
      short8v ah = *(const short8v*)&regionB  [mrow*72 + off];
      short8v al = *(const short8v*)&regionBlo[mrow*72 + off];
      #pragma unroll
      for (int nt = 0; nt < 4; ++nt) {
        short8v bh = *(const short8v*)&wfl[(size_t)(48 + kt*4 + nt)*512 + lane*8];
        short8v bl = *(const short8v*)&wfl[(size_t)(116 + kt*4 + nt)*512 + lane*8];
        cv[nt] = mfma3(ah, al, bh, bl, cv[nt]);
      }
      #pragma unroll
      for (int nt = 0; nt < 2; ++nt) {
        short8v bh = *(const short8v*)&wfl[(size_t)(56 + kt*2 + nt)*512 + lane*8];
        short8v bl = *(const short8v*)&wfl[(size_t)(124 + kt*2 + nt)*512 + lane*8];
        cvg[nt] = mfma3(ah, al, bh, bl, cvg[nt]);
      }
    }
    // Mvg rows mt=0 into fp32 sMvg (aliased regionA; H1 dead after P2)
    float* sMvg = (float*)regionA;
    #pragma unroll
    for (int nt = 0; nt < 2; ++nt)
      #pragma unroll
      for (int i = 0; i < 4; ++i)
        sMvg[(g*4 + i)*34 + nt*16 + r0] = cvg[nt][i];
  }
  __syncthreads();

  // ---------------- P6: both waves: partial agg; wave1 also Mvg(mt=1)
  {
    int hsub = r0 >> 3;
    #pragma unroll
    for (int nt = 0; nt < 4; ++nt) {
      float p = 0.f;
      #pragma unroll
      for (int i = 0; i < 4; ++i)
        p += sAtt[(wid*16 + g*4 + i)*9 + nt*2 + hsub] * cv[nt][i];
      p += __shfl_xor(p, 16, 64);
      p += __shfl_xor(p, 32, 64);
      if (g == 0) sAggP[wid][nt*16 + r0] = p;
    }
  }
  if (wid == 1) {
    cvg[0] = fz; cvg[1] = fz;
    #pragma unroll
    for (int kt = 0; kt < 2; ++kt) {
      int off = kt*32 + g*8;
      short8v ah = *(const short8v*)&regionB  [mrow*72 + off];
      short8v al = *(const short8v*)&regionBlo[mrow*72 + off];
      #pragma unroll
      for (int nt = 0; nt < 2; ++nt) {
        short8v bh = *(const short8v*)&wfl[(size_t)(56 + kt*2 + nt)*512 + lane*8];
        short8v bl = *(const short8v*)&wfl[(size_t)(124 + kt*2 + nt)*512 + lane*8];
        cvg[nt] = mfma3(ah, al, bh, bl, cvg[nt]);
      }
    }
    float* sMvg = (float*)regionA;
    #pragma unroll
    for (int nt = 0; nt < 2; ++nt)
      #pragma unroll
      for (int i = 0; i < 4; ++i)
        sMvg[(16 + g*4 + i)*34 + nt*16 + r0] = cvg[nt][i];
  }
  __syncthreads();

  // ---------------- P7: wave0 f0 out (agg combine + Wo0) ; wave1 f1 out
  if (wid == 0) {
    {
      float p = sAggP[0][lane] + sAggP[1][lane];
      ushort h, l; split_bf(p, h, l);
      sAggH[lane] = h; sAggL[lane] = l;
    }
    floatx4 co[4];
    #pragma unroll
    for (int nt = 0; nt < 4; ++nt) co[nt] = fz;
    #pragma unroll
    for (int kt = 0; kt < 2; ++kt) {
      short8v ah = *(const short8v*)&sAggH[kt*32 + g*8];
      short8v al = *(const short8v*)&sAggL[kt*32 + g*8];
      #pragma unroll
      for (int nt = 0; nt < 4; ++nt) {
        short8v bh = *(const short8v*)&wfl[(size_t)(60 + kt*4 + nt)*512 + lane*8];
        short8v bl = *(const short8v*)&wfl[(size_t)(128 + kt*4 + nt)*512 + lane*8];
        co[nt] = mfma3(ah, al, bh, bl, co[nt]);
      }
    }
    float v = (g == 0) ? co[0][0] : (g == 1) ? co[1][0] : (g == 2) ? co[2][0] : co[3][0];
    f0o[node*H + lane] = f0reg + v + bo0[lane];
  } else if (lane < F1W) {
    const float* sMvg = (const float*)regionA;
    int ch = lane / 3, d = lane - ch*3;
    float acc = sF1d[lane];
    #pragma unroll 8
    for (int k = 0; k < KK; ++k) {
      float a   = sA[k];
      float mv1 = sMvg[k*34 + ch];
      float mg1 = sMvg[k*34 + 16 + ch];
      float f1s = sF1s[k*52 + lane];
      acc += a * (sDir[k][d]*mv1 + mg1*f1s);
    }
    f1o[node*F1W + lane] = acc;
  }
}

// ---------------------------------------------------------------- output
__global__ __launch_bounds__(256) void k_out(const float* __restrict__ f1,
                                             const float* __restrict__ Wout1,
                                             float* __restrict__ out) {
  int gidx = blockIdx.x*256 + threadIdx.x;
  if (gidx >= NB*NN*3) return;
  int node = gidx / 3, d = gidx - node*3;
  float acc = 0.f;
  for (int c = 0; c < CV; ++c) acc = fmaf(f1[node*F1W + c*3 + d], Wout1[c], acc);
  out[gidx] = acc;
}

// ---------------------------------------------------------------- launch
extern "C" void kernel_launch(void* const* d_in, const int* in_sizes, int n_in,
                              void* d_out, int out_size, void* d_ws, size_t ws_size,
                              hipStream_t stream) {
  const int*   seq   = (const int*)  d_in[0];
  const float* coord = (const float*)d_in[1];
  const int*   tptr  = (const int*)  d_in[2];
  const float* atab  = (const float*)d_in[3];
  const float* ttab  = (const float*)d_in[4];
  const float* Wp0   = (const float*)d_in[5];
  const float* bp0   = (const float*)d_in[6];
  const float* Wp1   = (const float*)d_in[7];
  const float* We1   = (const float*)d_in[8];
  const float* be1   = (const float*)d_in[9];
  const float* We2   = (const float*)d_in[10];
  const float* be2   = (const float*)d_in[11];
  const float* Wq    = (const float*)d_in[12];
  const float* Wk    = (const float*)d_in[13];
  const float* Wv0   = (const float*)d_in[14];
  const float* Wv1   = (const float*)d_in[15];
  const float* Wg1   = (const float*)d_in[16];
  const float* Wo0   = (const float*)d_in[17];
  const float* bo0   = (const float*)d_in[18];
  const float* Wout1 = (const float*)d_in[19];
  float* out = (float*)d_out;

  float* ws = (float*)d_ws;
  float*  coordC = ws;
  int*    idxb   = (int*)(ws + 12288);
  float*  dirn   = ws + 12288 + 131072;
  float*  f0A    = dirn + (size_t)NB*NN*KK*3;
  float*  f0B    = f0A + (size_t)NB*NN*H;
  float*  f1A    = f0B + (size_t)NB*NN*H;
  float*  f1B    = f1A + (size_t)NB*NN*F1W;
  ushort* rbf16  = (ushort*)(f1B + (size_t)NB*NN*F1W);
  ushort* wfrag  = rbf16 + (size_t)NB*NN*KK*NRBF;

  k_center<<<NB, 256, 0, stream>>>(coord, coordC);
  k_knn<<<NB*NN, 64, 0, stream>>>(coordC, idxb, dirn, rbf16);
  k_f0init<<<NB*NN*H/256, 256, 0, stream>>>(seq, tptr, atab, ttab, Wp0, bp0, f0A);
  k_f1init<<<(NB*NN*F1W + 255)/256, 256, 0, stream>>>(coordC, Wp1, f1A);
  k_prep<<<(NL*NTILES*64 + 255)/256, 256, 0, stream>>>(We1, We2, Wq, Wk, Wv0, Wv1, Wg1, Wo0, wfrag);

  const float* f0in = f0A; float* f0out = f0B;
  const float* f1in = f1A; float* f1out = f1B;
  for (int l = 0; l < NL; ++l) {
    k_layer<<<NB*NN, 128, 0, stream>>>(
        f0in, f1in, f0out, f1out, idxb, dirn, rbf16,
        wfrag + (size_t)l*NTILES*512,
        be1 + (size_t)l*H, be2 + (size_t)l*H, bo0 + (size_t)l*H);
    const float* tf0 = f0in; f0in = f0out; f0out = (float*)tf0;
    const float* tf1 = f1in; f1in = f1out; f1out = (float*)tf1;
  }
  k_out<<<(NB*NN*3 + 255)/256, 256, 0, stream>>>(f1in, Wout1, out);
}

// Round 7
// 390.963 us; speedup vs baseline: 5.1990x; 1.0976x over previous
//
#include <hip/hip_runtime.h>
#include <hip/hip_bf16.h>
#include <math.h>

#define NL    4
#define H     64
#define CV    16
#define NRBF  16
#define HEADS 8
#define KK    32
#define DIN   176
#define NB    2
#define NN    2048
#define F1W   (CV*3)   // 48
#define NTILES 136     // 68 hi + 68 lo per layer

typedef __attribute__((ext_vector_type(8))) short short8v;
typedef __attribute__((ext_vector_type(4))) float floatx4;

__device__ __forceinline__ ushort f2bf(float f) {
  union { float f; unsigned u; } v; v.f = f;
  unsigned r = v.u + 0x7FFFu + ((v.u >> 16) & 1u);
  return (ushort)(r >> 16);
}
__device__ __forceinline__ float bf2f(ushort s) {
  union { unsigned u; float f; } v; v.u = ((unsigned)s) << 16;
  return v.f;
}
__device__ __forceinline__ void split_bf(float v, ushort& h, ushort& l) {
  h = f2bf(v);
  l = f2bf(v - bf2f(h));
}
__device__ __forceinline__ floatx4 mfma3(short8v ah, short8v al,
                                         short8v bh, short8v bl, floatx4 acc) {
  acc = __builtin_amdgcn_mfma_f32_16x16x32_bf16(ah, bh, acc, 0, 0, 0);
  acc = __builtin_amdgcn_mfma_f32_16x16x32_bf16(ah, bl, acc, 0, 0, 0);
  acc = __builtin_amdgcn_mfma_f32_16x16x32_bf16(al, bh, acc, 0, 0, 0);
  return acc;
}

// ---------------------------------------------------------------- center
__global__ __launch_bounds__(256) void k_center(const float* __restrict__ coord,
                                                float* __restrict__ coordC) {
  __shared__ float rx[256], ry[256], rz[256];
  int b = blockIdx.x;
  const float* cb = coord + b*NN*3;
  float sx = 0.f, sy = 0.f, sz = 0.f;
  for (int i = threadIdx.x; i < NN; i += 256) {
    sx += cb[i*3+0]; sy += cb[i*3+1]; sz += cb[i*3+2];
  }
  rx[threadIdx.x] = sx; ry[threadIdx.x] = sy; rz[threadIdx.x] = sz;
  __syncthreads();
  for (int s = 128; s > 0; s >>= 1) {
    if (threadIdx.x < s) {
      rx[threadIdx.x] += rx[threadIdx.x+s];
      ry[threadIdx.x] += ry[threadIdx.x+s];
      rz[threadIdx.x] += rz[threadIdx.x+s];
    }
    __syncthreads();
  }
  float mx = rx[0]*(1.0f/NN), my = ry[0]*(1.0f/NN), mz = rz[0]*(1.0f/NN);
  float* ob = coordC + b*NN*3;
  for (int i = threadIdx.x; i < NN; i += 256) {
    ob[i*3+0] = cb[i*3+0] - mx;
    ob[i*3+1] = cb[i*3+1] - my;
    ob[i*3+2] = cb[i*3+2] - mz;
  }
}

// ---------------------------------------------------------------- knn
// d2 kept in 32 registers per lane (d2[it*64+l] owned by lane l); selected
// neighbors tracked by a 32-bit mask per lane. No LDS, no barriers.
__global__ __launch_bounds__(64) void k_knn(const float* __restrict__ coordC,
                                            int* __restrict__ idx,
                                            float* __restrict__ dirn,
                                            ushort* __restrict__ rbf16) {
  const int node = blockIdx.x;
  const int b = node >> 11;
  const int i = node & (NN-1);
  const int l = threadIdx.x;
  const float* cb = coordC + b*NN*3;
  const float xi = cb[i*3+0], yi = cb[i*3+1], zi = cb[i*3+2];
  const float sqi = xi*xi + yi*yi + zi*zi;
  float d2r[32];
  #pragma unroll
  for (int it = 0; it < 32; ++it) {
    int j = it*64 + l;
    float xj = cb[j*3+0], yj = cb[j*3+1], zj = cb[j*3+2];
    float sqj = xj*xj + yj*yj + zj*zj;
    float dot = xi*xj + yi*yj + zi*zj;
    float v = sqi + sqj - 2.0f*dot;            // gram-trick, matches reference
    if (j == i) v += 1.0e9f;
    d2r[it] = v;
  }
  unsigned mask = 0;
  int myselidx = 0;
  for (int s = 0; s < KK; ++s) {
    float bv = 3.0e38f; int bi = 0x7fffffff;
    #pragma unroll
    for (int it = 0; it < 32; ++it) {
      float v = ((mask >> it) & 1u) ? 3.0e38f : d2r[it];
      int j = it*64 + l;
      if (v < bv) { bv = v; bi = j; }
    }
    #pragma unroll
    for (int off = 1; off <= 32; off <<= 1) {
      float ov = __shfl_xor(bv, off, 64);
      int   oi = __shfl_xor(bi, off, 64);
      if (ov < bv || (ov == bv && oi < bi)) { bv = ov; bi = oi; }
    }
    if (l == s) myselidx = bi;
    if ((bi & 63) == l) mask |= 1u << (bi >> 6);
  }
  if (l < KK) {
    int j = myselidx;
    idx[node*KK + l] = j;
    float rxv = cb[j*3+0] - xi, ryv = cb[j*3+1] - yi, rzv = cb[j*3+2] - zi;
    float dd = sqrtf(rxv*rxv + ryv*ryv + rzv*rzv + 1e-8f);
    float inv = 1.0f/dd;
    float* dn = dirn + (node*KK + l)*3;
    dn[0] = rxv*inv; dn[1] = ryv*inv; dn[2] = rzv*inv;
    ushort* rb = rbf16 + (size_t)(node*KK + l)*NRBF;
    const float inv2s2 = 1.0f/(2.0f*0.625f*0.625f);
    #pragma unroll
    for (int r = 0; r < NRBF; ++r) {
      float mu = (10.0f/15.0f)*(float)r;
      float dm = dd - mu;
      rb[r] = f2bf(expf(-(dm*dm)*inv2s2));
    }
  }
}

// ---------------------------------------------------------------- f0 init
__global__ __launch_bounds__(256) void k_f0init(const int* __restrict__ seq,
                                                const int* __restrict__ tptr,
                                                const float* __restrict__ atab,
                                                const float* __restrict__ ttab,
                                                const float* __restrict__ Wp0,
                                                const float* __restrict__ bp0,
                                                float* __restrict__ f0) {
  int gidx = blockIdx.x*256 + threadIdx.x;
  int node = gidx >> 6, o = gidx & (H-1);
  int s = seq[node];
  int tv = tptr[0];
  const float* ar = atab + s*32;
  const float* tr = ttab + tv*32;
  float acc = bp0[o];
  for (int i2 = 0; i2 < 32; ++i2) acc = fmaf(ar[i2], Wp0[i2*H + o], acc);
  for (int i2 = 0; i2 < 32; ++i2) acc = fmaf(tr[i2], Wp0[(32+i2)*H + o], acc);
  f0[gidx] = acc;
}

// ---------------------------------------------------------------- f1 init
__global__ __launch_bounds__(256) void k_f1init(const float* __restrict__ coordC,
                                                const float* __restrict__ Wp1,
                                                float* __restrict__ f1) {
  int gidx = blockIdx.x*256 + threadIdx.x;
  if (gidx >= NB*NN*F1W) return;
  int node = gidx / F1W;
  int r = gidx - node*F1W;
  int c = r / 3, d = r - c*3;
  f1[gidx] = coordC[node*3 + d] * Wp1[c];
}

// ---------------------------------------------------------------- weight fragment prep
__global__ __launch_bounds__(256) void k_prep(
    const float* __restrict__ We1, const float* __restrict__ We2,
    const float* __restrict__ Wq,  const float* __restrict__ Wk,
    const float* __restrict__ Wv0, const float* __restrict__ Wv1,
    const float* __restrict__ Wg1, const float* __restrict__ Wo0,
    ushort* __restrict__ wfrag) {
  int gid = blockIdx.x*256 + threadIdx.x;
  if (gid >= NL*NTILES*64) return;
  int lane = gid & 63;
  int tile = gid >> 6;
  int l = tile / NTILES;
  int tt = tile - l*NTILES;
  int part = (tt >= 68) ? 1 : 0;
  int t = part ? (tt - 68) : tt;
  int kt, nt, K = H;
  const float* src = nullptr;
  int wvg = 0;
  if (t < 24)      { kt = t>>2;           nt = t&3; src = We1 + (size_t)l*DIN*H; K = DIN; }
  else if (t < 32) { int u=t-24; kt=u>>2; nt = u&3; src = We2 + (size_t)l*H*H; }
  else if (t < 40) { int u=t-32; kt=u>>2; nt = u&3; src = Wk  + (size_t)l*H*H; }
  else if (t < 48) { int u=t-40; kt=u>>2; nt = u&3; src = Wq  + (size_t)l*H*H; }
  else if (t < 56) { int u=t-48; kt=u>>2; nt = u&3; src = Wv0 + (size_t)l*H*H; }
  else if (t < 60) { int u=t-56; kt=u>>1; nt = u&1; wvg = 1; }
  else             { int u=t-60; kt=u>>2; nt = u&3; src = Wo0 + (size_t)l*H*H; }
  ushort out[8];
  #pragma unroll
  for (int j = 0; j < 8; ++j) {
    int k = kt*32 + (lane>>4)*8 + j;
    int col = nt*16 + (lane&15);
    float v = 0.f;
    if (k < K) {
      if (wvg) v = (col < CV) ? Wv1[(size_t)l*H*CV + k*CV + col]
                              : Wg1[(size_t)l*H*CV + k*CV + (col-CV)];
      else     v = src[(size_t)k*H + col];
    }
    ushort h, lo; split_bf(v, h, lo);
    out[j] = part ? lo : h;
  }
  *(short8v*)(wfrag + (size_t)tile*512 + lane*8) = *(const short8v*)out;
}

// ---------------------------------------------------------------- fused layer
// 128 threads = 2 waves on ONE node; wave w owns edge rows w*16..w*16+15.
// Only 5 barriers: B1 (broadcast staging), P3->P4 (sQ), P4->P5 (logits),
// P5->P6 (softmax), P6->P7 (sMvg/sAggP).
__global__ __launch_bounds__(128) void k_layer(
    const float* __restrict__ f0i, const float* __restrict__ f1i,
    float* __restrict__ f0o, float* __restrict__ f1o,
    const int* __restrict__ idx, const float* __restrict__ dirn,
    const ushort* __restrict__ rbf16,
    const ushort* __restrict__ wfl,
    const float* __restrict__ be1, const float* __restrict__ be2,
    const float* __restrict__ bo0)
{
  __shared__ __align__(16) ushort regionA  [32*72];   // f0src -> H1 -> fp32 Mvg[32][34]
  __shared__ __align__(16) ushort regionAlo[32*72];
  __shared__ __align__(16) ushort regionB  [32*72];   // [rbf|dotS|dotD|0] -> M
  __shared__ __align__(16) ushort regionBlo[32*72];
  __shared__ __align__(16) ushort sF0h[64], sF0l[64];
  __shared__ __align__(16) ushort sAggH[64], sAggL[64];
  __shared__ float sF1d[F1W];
  __shared__ float sDir[KK][4];
  __shared__ int   sIdx[KK];
  __shared__ float sAtt[KK*9];       // logits then softmax, in place
  __shared__ float sA[KK];
  __shared__ float sQ[64];
  __shared__ float sAggP[2][64];

  const int t    = threadIdx.x;
  const int wid  = t >> 6;
  const int lane = t & 63;
  const int node = blockIdx.x;
  const int bbase = node & ~(NN-1);
  const int r0 = lane & 15, g = lane >> 4;
  const int mrow = wid*16 + r0;
  const floatx4 fz = {0.f, 0.f, 0.f, 0.f};

  // ---- prefetch GEMM1 kt=0 B-frags (global, no deps on anything)
  short8v cbh[4], cbl[4];
  #pragma unroll
  for (int nt = 0; nt < 4; ++nt) {
    cbh[nt] = *(const short8v*)&wfl[(size_t)(nt)*512 + lane*8];
    cbl[nt] = *(const short8v*)&wfl[(size_t)(68 + nt)*512 + lane*8];
  }

  // ---- phase 0: broadcast staging
  float f0reg = 0.f;
  if (wid == 0) {
    f0reg = f0i[node*H + lane];
    ushort h, l; split_bf(f0reg, h, l); sF0h[lane] = h; sF0l[lane] = l;
  } else {
    if (lane < KK)  sIdx[lane] = idx[node*KK + lane];
    if (lane < F1W) sF1d[lane] = f1i[node*F1W + lane];
  }
  if (t < 96) sDir[t/3][t%3] = dirn[node*(KK*3) + t];
  __syncthreads();                                   // B1

  // ---- staging, own rows only (no barrier before P1)
  #pragma unroll 4
  for (int r = 0; r < 16; ++r) {
    int rr = wid*16 + r;
    float v = f0i[(bbase + sIdx[rr])*H + lane];
    ushort h, l; split_bf(v, h, l);
    regionA[rr*72 + lane] = h; regionAlo[rr*72 + lane] = l;
  }
  #pragma unroll
  for (int it = 0; it < 4; ++it) {       // rbf cols 0..15 + zero cols 48..63
    int q = it*64 + lane;
    int k = wid*16 + (q >> 4), c = q & 15;
    regionB  [k*72 + c] = rbf16[(size_t)node*(KK*NRBF) + k*NRBF + c];
    regionBlo[k*72 + c] = 0;
    regionB  [k*72 + 48 + c] = 0;
    regionBlo[k*72 + 48 + c] = 0;
  }
  #pragma unroll
  for (int it = 0; it < 4; ++it) {       // dotS cols 16..31, dotD cols 32..47
    int q = it*64 + lane;
    int k = wid*16 + (q >> 4), ch = q & 15;
    const float* fs = f1i + (size_t)(bbase + sIdx[k])*F1W + ch*3;
    float ds_ = 0.f, dd_ = 0.f;
    #pragma unroll
    for (int d = 0; d < 3; ++d) {
      float dr = sDir[k][d];
      ds_ += fs[d] * dr;
      dd_ += sF1d[ch*3 + d] * dr;
    }
    ushort h, l;
    split_bf(ds_, h, l); regionB[k*72 + 16 + ch] = h; regionBlo[k*72 + 16 + ch] = l;
    split_bf(dd_, h, l); regionB[k*72 + 32 + ch] = h; regionBlo[k*72 + 32 + ch] = l;
  }

  // ---------------- P1: H1 = relu(E @ We1 + be1), K=192, B double-buffered
  floatx4 c1[4];
  #pragma unroll
  for (int nt = 0; nt < 4; ++nt) c1[nt] = fz;
  #pragma unroll
  for (int kt = 0; kt < 6; ++kt) {
    short8v nbh[4], nbl[4];
    if (kt < 5) {
      #pragma unroll
      for (int nt = 0; nt < 4; ++nt) {
        nbh[nt] = *(const short8v*)&wfl[(size_t)((kt+1)*4 + nt)*512 + lane*8];
        nbl[nt] = *(const short8v*)&wfl[(size_t)(68 + (kt+1)*4 + nt)*512 + lane*8];
      }
    }
    short8v ah, al;
    if (kt < 2) {
      ah = *(const short8v*)&sF0h[kt*32 + g*8];
      al = *(const short8v*)&sF0l[kt*32 + g*8];
    } else if (kt < 4) {
      int off = (kt-2)*32 + g*8;
      ah = *(const short8v*)&regionA  [mrow*72 + off];
      al = *(const short8v*)&regionAlo[mrow*72 + off];
    } else {
      int off = ((kt == 4) ? 0 : 32) + g*8;
      ah = *(const short8v*)&regionB  [mrow*72 + off];
      al = *(const short8v*)&regionBlo[mrow*72 + off];
    }
    #pragma unroll
    for (int nt = 0; nt < 4; ++nt) c1[nt] = mfma3(ah, al, cbh[nt], cbl[nt], c1[nt]);
    if (kt < 5) {
      #pragma unroll
      for (int nt = 0; nt < 4; ++nt) { cbh[nt] = nbh[nt]; cbl[nt] = nbl[nt]; }
    }
  }
  // issue P2 B loads now (in flight over H1 epilogue)
  short8v b2h[8], b2l[8];
  #pragma unroll
  for (int i2 = 0; i2 < 8; ++i2) {
    b2h[i2] = *(const short8v*)&wfl[(size_t)(24 + i2)*512 + lane*8];
    b2l[i2] = *(const short8v*)&wfl[(size_t)(92 + i2)*512 + lane*8];
  }
  // H1 epilogue (own rows; no barrier)
  #pragma unroll
  for (int nt = 0; nt < 4; ++nt) {
    float be = be1[nt*16 + r0];
    #pragma unroll
    for (int i = 0; i < 4; ++i) {
      float v = fmaxf(c1[nt][i] + be, 0.f);
      ushort h, l; split_bf(v, h, l);
      regionA  [(wid*16 + g*4 + i)*72 + nt*16 + r0] = h;
      regionAlo[(wid*16 + g*4 + i)*72 + nt*16 + r0] = l;
    }
  }

  // ---------------- P2: M = H1 @ We2 + be2 (own rows; no barrier)
  floatx4 c2[4];
  #pragma unroll
  for (int nt = 0; nt < 4; ++nt) c2[nt] = fz;
  #pragma unroll
  for (int kt = 0; kt < 2; ++kt) {
    int off = kt*32 + g*8;
    short8v ah = *(const short8v*)&regionA  [mrow*72 + off];
    short8v al = *(const short8v*)&regionAlo[mrow*72 + off];
    #pragma unroll
    for (int nt = 0; nt < 4; ++nt)
      c2[nt] = mfma3(ah, al, b2h[kt*4 + nt], b2l[kt*4 + nt], c2[nt]);
  }
  #pragma unroll
  for (int nt = 0; nt < 4; ++nt) {
    float be = be2[nt*16 + r0];
    #pragma unroll
    for (int i = 0; i < 4; ++i) {
      ushort h, l; split_bf(c2[nt][i] + be, h, l);
      regionB  [(wid*16 + g*4 + i)*72 + nt*16 + r0] = h;
      regionBlo[(wid*16 + g*4 + i)*72 + nt*16 + r0] = l;
    }
  }

  // ---------------- P3: wave0 q = f0@Wq -> sQ ; wave1 ck(mt=1)
  floatx4 ck[4];
  #pragma unroll
  for (int nt = 0; nt < 4; ++nt) ck[nt] = fz;
  if (wid == 0) {
    floatx4 cq[4];
    #pragma unroll
    for (int nt = 0; nt < 4; ++nt) cq[nt] = fz;
    #pragma unroll
    for (int kt = 0; kt < 2; ++kt) {
      short8v ah = *(const short8v*)&sF0h[kt*32 + g*8];
      short8v al = *(const short8v*)&sF0l[kt*32 + g*8];
      #pragma unroll
      for (int nt = 0; nt < 4; ++nt) {
        short8v bh = *(const short8v*)&wfl[(size_t)(40 + kt*4 + nt)*512 + lane*8];
        short8v bl = *(const short8v*)&wfl[(size_t)(108 + kt*4 + nt)*512 + lane*8];
        cq[nt] = mfma3(ah, al, bh, bl, cq[nt]);
      }
    }
    if (g == 0) {
      #pragma unroll
      for (int nt = 0; nt < 4; ++nt) sQ[nt*16 + r0] = cq[nt][0];
    }
  } else {
    #pragma unroll
    for (int kt = 0; kt < 2; ++kt) {
      int off = kt*32 + g*8;
      short8v ah = *(const short8v*)&regionB  [mrow*72 + off];
      short8v al = *(const short8v*)&regionBlo[mrow*72 + off];
      #pragma unroll
      for (int nt = 0; nt < 4; ++nt) {
        short8v bh = *(const short8v*)&wfl[(size_t)(32 + kt*4 + nt)*512 + lane*8];
        short8v bl = *(const short8v*)&wfl[(size_t)(100 + kt*4 + nt)*512 + lane*8];
        ck[nt] = mfma3(ah, al, bh, bl, ck[nt]);
      }
    }
  }
  __syncthreads();                                   // B2 (sQ)

  // ---------------- P4: wave0 ck(mt=0) | wave1 V0(mt=1); both write logits
  floatx4 cv[4];
  #pragma unroll
  for (int nt = 0; nt < 4; ++nt) cv[nt] = fz;
  if (wid == 0) {
    #pragma unroll
    for (int kt = 0; kt < 2; ++kt) {
      int off = kt*32 + g*8;
      short8v ah = *(const short8v*)&regionB  [mrow*72 + off];
      short8v al = *(const short8v*)&regionBlo[mrow*72 + off];
      #pragma unroll
      for (int nt = 0; nt < 4; ++nt) {
        short8v bh = *(const short8v*)&wfl[(size_t)(32 + kt*4 + nt)*512 + lane*8];
        short8v bl = *(const short8v*)&wfl[(size_t)(100 + kt*4 + nt)*512 + lane*8];
        ck[nt] = mfma3(ah, al, bh, bl, ck[nt]);
      }
    }
  } else {
    #pragma unroll
    for (int kt = 0; kt < 2; ++kt) {
      int off = kt*32 + g*8;
      short8v ah = *(const short8v*)&regionB  [mrow*72 + off];
      short8v al = *(const short8v*)&regionBlo[mrow*72 + off];
      #pragma unroll
      for (int nt = 0; nt < 4; ++nt) {
        short8v bh = *(const short8v*)&wfl[(size_t)(48 + kt*4 + nt)*512 + lane*8];
        short8v bl = *(const short8v*)&wfl[(size_t)(116 + kt*4 + nt)*512 + lane*8];
        cv[nt] = mfma3(ah, al, bh, bl, cv[nt]);
      }
    }
  }
  {
    float qv[4];
    #pragma unroll
    for (int nt = 0; nt < 4; ++nt) qv[nt] = sQ[nt*16 + r0];
    #pragma unroll
    for (int nt = 0; nt < 4; ++nt)
      #pragma unroll
      for (int i = 0; i < 4; ++i) {
        float v = ck[nt][i] * qv[nt];
        v += __shfl_xor(v, 1, 64);
        v += __shfl_xor(v, 2, 64);
        v += __shfl_xor(v, 4, 64);
        if ((lane & 7) == 0)
          sAtt[(wid*16 + g*4 + i)*9 + nt*2 + (r0 >> 3)] = v * 0.35355339059327373f;
      }
  }
  __syncthreads();                                   // B3 (logits)

  // ---------------- P5: wave1 softmax (in place) | wave0 V0(mt0)+Mvg(mt0)
  floatx4 cvg[2];
  cvg[0] = fz; cvg[1] = fz;
  if (wid == 1) {
    int h = lane & 7, seg = lane >> 3;
    float l0[4];
    float mx = -3.0e38f;
    #pragma unroll
    for (int i = 0; i < 4; ++i) { l0[i] = sAtt[(seg*4 + i)*9 + h]; mx = fmaxf(mx, l0[i]); }
    #pragma unroll
    for (int off = 8; off <= 32; off <<= 1) mx = fmaxf(mx, __shfl_xor(mx, off, 64));
    float e0[4], sum = 0.f;
    #pragma unroll
    for (int i = 0; i < 4; ++i) { e0[i] = expf(l0[i] - mx); sum += e0[i]; }
    #pragma unroll
    for (int off = 8; off <= 32; off <<= 1) sum += __shfl_xor(sum, off, 64);
    float inv = 1.0f / sum;
    #pragma unroll
    for (int i = 0; i < 4; ++i) {
      float a = e0[i] * inv;
      sAtt[(seg*4 + i)*9 + h] = a;
      float tt = a;
      tt += __shfl_xor(tt, 1, 64);
      tt += __shfl_xor(tt, 2, 64);
      tt += __shfl_xor(tt, 4, 64);
      if (h == 0) sA[seg*4 + i] = tt * 0.125f;
    }
  } else {
    #pragma unroll
    for (int kt = 0; kt < 2; ++kt) {
      int off = kt*32 + g*8;
      short8v ah = *(const short8v*)&regionB  [mrow*72 + off];
      short8v al = *(const short8v*)&regionBlo[mrow*72 + off];
      #pragma unroll
      for (int nt = 0; nt < 4; ++nt) {
        short8v bh = *(const short8v*)&wfl[(size_t)(48 + kt*4 + nt)*512 + lane*8];
        short8v bl = *(const short8v*)&wfl[(size_t)(116 + kt*4 + nt)*512 + lane*8];
        cv[nt] = mfma3(ah, al, bh, bl, cv[nt]);
      }
      #pragma unroll
      for (int nt = 0; nt < 2; ++nt) {
        short8v bh = *(const short8v*)&wfl[(size_t)(56 + kt*2 + nt)*512 + lane*8];
        short8v bl = *(const short8v*)&wfl[(size_t)(124 + kt*2 + nt)*512 + lane*8];
        cvg[nt] = mfma3(ah, al, bh, bl, cvg[nt]);
      }
    }
    float* sMvg = (float*)regionA;     // rows 0..15 (bytes disjoint from wave1 use)
    #pragma unroll
    for (int nt = 0; nt < 2; ++nt)
      #pragma unroll
      for (int i = 0; i < 4; ++i)
        sMvg[(g*4 + i)*34 + nt*16 + r0] = cvg[nt][i];
  }
  __syncthreads();                                   // B4 (softmax)

  // ---------------- P6: both agg-partial; wave1 Mvg(mt1); wave0 prefetch Wo0
  short8v b7h[8], b7l[8];
  if (wid == 0) {
    #pragma unroll
    for (int i2 = 0; i2 < 8; ++i2) {
      b7h[i2] = *(const short8v*)&wfl[(size_t)(60 + i2)*512 + lane*8];
      b7l[i2] = *(const short8v*)&wfl[(size_t)(128 + i2)*512 + lane*8];
    }
  }
  {
    int hsub = r0 >> 3;
    #pragma unroll
    for (int nt = 0; nt < 4; ++nt) {
      float p = 0.f;
      #pragma unroll
      for (int i = 0; i < 4; ++i)
        p += sAtt[(wid*16 + g*4 + i)*9 + nt*2 + hsub] * cv[nt][i];
      p += __shfl_xor(p, 16, 64);
      p += __shfl_xor(p, 32, 64);
      if (g == 0) sAggP[wid][nt*16 + r0] = p;
    }
  }
  if (wid == 1) {
    cvg[0] = fz; cvg[1] = fz;
    #pragma unroll
    for (int kt = 0; kt < 2; ++kt) {
      int off = kt*32 + g*8;
      short8v ah = *(const short8v*)&regionB  [mrow*72 + off];
      short8v al = *(const short8v*)&regionBlo[mrow*72 + off];
      #pragma unroll
      for (int nt = 0; nt < 2; ++nt) {
        short8v bh = *(const short8v*)&wfl[(size_t)(56 + kt*2 + nt)*512 + lane*8];
        short8v bl = *(const short8v*)&wfl[(size_t)(124 + kt*2 + nt)*512 + lane*8];
        cvg[nt] = mfma3(ah, al, bh, bl, cvg[nt]);
      }
    }
    float* sMvg = (float*)regionA;
    #pragma unroll
    for (int nt = 0; nt < 2; ++nt)
      #pragma unroll
      for (int i = 0; i < 4; ++i)
        sMvg[(16 + g*4 + i)*34 + nt*16 + r0] = cvg[nt][i];
  }
  __syncthreads();                                   // B5 (sMvg/sAggP)

  // ---------------- P7: wave0 f0 out | wave1 f1 out
  if (wid == 0) {
    {
      float p = sAggP[0][lane] + sAggP[1][lane];
      ushort h, l; split_bf(p, h, l);
      sAggH[lane] = h; sAggL[lane] = l;
    }
    floatx4 co[4];
    #pragma unroll
    for (int nt = 0; nt < 4; ++nt) co[nt] = fz;
    #pragma unroll
    for (int kt = 0; kt < 2; ++kt) {
      short8v ah = *(const short8v*)&sAggH[kt*32 + g*8];
      short8v al = *(const short8v*)&sAggL[kt*32 + g*8];
      #pragma unroll
      for (int nt = 0; nt < 4; ++nt)
        co[nt] = mfma3(ah, al, b7h[kt*4 + nt], b7l[kt*4 + nt], co[nt]);
    }
    float v = (g == 0) ? co[0][0] : (g == 1) ? co[1][0] : (g == 2) ? co[2][0] : co[3][0];
    f0o[node*H + lane] = f0reg + v + bo0[lane];
  } else if (lane < F1W) {
    const float* sMvg = (const float*)regionA;
    int ch = lane / 3, d = lane - ch*3;
    float acc = sF1d[lane];
    #pragma unroll 8
    for (int k = 0; k < KK; ++k) {
      float f1s = f1i[(size_t)(bbase + sIdx[k])*F1W + lane];
      float a   = sA[k];
      float mv1 = sMvg[k*34 + ch];
      float mg1 = sMvg[k*34 + 16 + ch];
      acc += a * (sDir[k][d]*mv1 + mg1*f1s);
    }
    f1o[node*F1W + lane] = acc;
  }
}

// ---------------------------------------------------------------- output
__global__ __launch_bounds__(256) void k_out(const float* __restrict__ f1,
                                             const float* __restrict__ Wout1,
                                             float* __restrict__ out) {
  int gidx = blockIdx.x*256 + threadIdx.x;
  if (gidx >= NB*NN*3) return;
  int node = gidx / 3, d = gidx - node*3;
  float acc = 0.f;
  for (int c = 0; c < CV; ++c) acc = fmaf(f1[node*F1W + c*3 + d], Wout1[c], acc);
  out[gidx] = acc;
}

// ---------------------------------------------------------------- launch
extern "C" void kernel_launch(void* const* d_in, const int* in_sizes, int n_in,
                              void* d_out, int out_size, void* d_ws, size_t ws_size,
                              hipStream_t stream) {
  const int*   seq   = (const int*)  d_in[0];
  const float* coord = (const float*)d_in[1];
  const int*   tptr  = (const int*)  d_in[2];
  const float* atab  = (const float*)d_in[3];
  const float* ttab  = (const float*)d_in[4];
  const float* Wp0   = (const float*)d_in[5];
  const float* bp0   = (const float*)d_in[6];
  const float* Wp1   = (const float*)d_in[7];
  const float* We1   = (const float*)d_in[8];
  const float* be1   = (const float*)d_in[9];
  const float* We2   = (const float*)d_in[10];
  const float* be2   = (const float*)d_in[11];
  const float* Wq    = (const float*)d_in[12];
  const float* Wk    = (const float*)d_in[13];
  const float* Wv0   = (const float*)d_in[14];
  const float* Wv1   = (const float*)d_in[15];
  const float* Wg1   = (const float*)d_in[16];
  const float* Wo0   = (const float*)d_in[17];
  const float* bo0   = (const float*)d_in[18];
  const float* Wout1 = (const float*)d_in[19];
  float* out = (float*)d_out;

  float* ws = (float*)d_ws;
  float*  coordC = ws;
  int*    idxb   = (int*)(ws + 12288);
  float*  dirn   = ws + 12288 + 131072;
  float*  f0A    = dirn + (size_t)NB*NN*KK*3;
  float*  f0B    = f0A + (size_t)NB*NN*H;
  float*  f1A    = f0B + (size_t)NB*NN*H;
  float*  f1B    = f1A + (size_t)NB*NN*F1W;
  ushort* rbf16  = (ushort*)(f1B + (size_t)NB*NN*F1W);
  ushort* wfrag  = rbf16 + (size_t)NB*NN*KK*NRBF;

  k_center<<<NB, 256, 0, stream>>>(coord, coordC);
  k_knn<<<NB*NN, 64, 0, stream>>>(coordC, idxb, dirn, rbf16);
  k_f0init<<<NB*NN*H/256, 256, 0, stream>>>(seq, tptr, atab, ttab, Wp0, bp0, f0A);
  k_f1init<<<(NB*NN*F1W + 255)/256, 256, 0, stream>>>(coordC, Wp1, f1A);
  k_prep<<<(NL*NTILES*64 + 255)/256, 256, 0, stream>>>(We1, We2, Wq, Wk, Wv0, Wv1, Wg1, Wo0, wfrag);

  const float* f0in = f0A; float* f0out = f0B;
  const float* f1in = f1A; float* f1out = f1B;
  for (int l = 0; l < NL; ++l) {
    k_layer<<<NB*NN, 128, 0, stream>>>(
        f0in, f1in, f0out, f1out, idxb, dirn, rbf16,
        wfrag + (size_t)l*NTILES*512,
        be1 + (size_t)l*H, be2 + (size_t)l*H, bo0 + (size_t)l*H);
    const float* tf0 = f0in; f0in = f0out; f0out = (float*)tf0;
    const float* tf1 = f1in; f1in = f1out; f1out = (float*)tf1;
  }
  k_out<<<(NB*NN*3 + 255)/256, 256, 0, stream>>>(f1in, Wout1, out);
}

// Round 8
// 368.939 us; speedup vs baseline: 5.5093x; 1.0597x over previous
//
#include <hip/hip_runtime.h>
#include <hip/hip_bf16.h>
#include <math.h>

#define NL    4
#define H     64
#define CV    16
#define NRBF  16
#define HEADS 8
#define KK    32
#define DIN   176
#define NB    2
#define NN    2048
#define F1W   (CV*3)   // 48
#define NTILES 136     // 68 hi + 68 lo per layer

typedef __attribute__((ext_vector_type(8))) short short8v;
typedef __attribute__((ext_vector_type(4))) float floatx4;

__device__ __forceinline__ ushort f2bf(float f) {
  union { float f; unsigned u; } v; v.f = f;
  unsigned r = v.u + 0x7FFFu + ((v.u >> 16) & 1u);
  return (ushort)(r >> 16);
}
__device__ __forceinline__ float bf2f(ushort s) {
  union { unsigned u; float f; } v; v.u = ((unsigned)s) << 16;
  return v.f;
}
__device__ __forceinline__ void split_bf(float v, ushort& h, ushort& l) {
  h = f2bf(v);
  l = f2bf(v - bf2f(h));
}
__device__ __forceinline__ floatx4 mfma3(short8v ah, short8v al,
                                         short8v bh, short8v bl, floatx4 acc) {
  acc = __builtin_amdgcn_mfma_f32_16x16x32_bf16(ah, bh, acc, 0, 0, 0);
  acc = __builtin_amdgcn_mfma_f32_16x16x32_bf16(ah, bl, acc, 0, 0, 0);
  acc = __builtin_amdgcn_mfma_f32_16x16x32_bf16(al, bh, acc, 0, 0, 0);
  return acc;
}

// ---------------------------------------------------------------- center
__global__ __launch_bounds__(256) void k_center(const float* __restrict__ coord,
                                                float* __restrict__ coordC) {
  __shared__ float rx[256], ry[256], rz[256];
  int b = blockIdx.x;
  const float* cb = coord + b*NN*3;
  float sx = 0.f, sy = 0.f, sz = 0.f;
  for (int i = threadIdx.x; i < NN; i += 256) {
    sx += cb[i*3+0]; sy += cb[i*3+1]; sz += cb[i*3+2];
  }
  rx[threadIdx.x] = sx; ry[threadIdx.x] = sy; rz[threadIdx.x] = sz;
  __syncthreads();
  for (int s = 128; s > 0; s >>= 1) {
    if (threadIdx.x < s) {
      rx[threadIdx.x] += rx[threadIdx.x+s];
      ry[threadIdx.x] += ry[threadIdx.x+s];
      rz[threadIdx.x] += rz[threadIdx.x+s];
    }
    __syncthreads();
  }
  float mx = rx[0]*(1.0f/NN), my = ry[0]*(1.0f/NN), mz = rz[0]*(1.0f/NN);
  float* ob = coordC + b*NN*3;
  for (int i = threadIdx.x; i < NN; i += 256) {
    ob[i*3+0] = cb[i*3+0] - mx;
    ob[i*3+1] = cb[i*3+1] - my;
    ob[i*3+2] = cb[i*3+2] - mz;
  }
}

// ---------------------------------------------------------------- knn
// Exact top-32 by (d2, idx): per-lane bitonic sort of 32 packed u64 keys
// (ordinal(d2)<<16 | j), sorted lists in LDS, 32 tournament rounds of
// butterfly-min over lane heads. Extraction order identical to successive
// stable argmin (ascending (d2,idx)).
__global__ __launch_bounds__(64) void k_knn(const float* __restrict__ coordC,
                                            int* __restrict__ idx,
                                            float* __restrict__ dirn,
                                            ushort* __restrict__ rbf16) {
  __shared__ unsigned long long heap[64*33];
  const int node = blockIdx.x;
  const int b = node >> 11;
  const int i = node & (NN-1);
  const int l = threadIdx.x;
  const float* cb = coordC + b*NN*3;
  const float xi = cb[i*3+0], yi = cb[i*3+1], zi = cb[i*3+2];
  const float sqi = xi*xi + yi*yi + zi*zi;
  unsigned long long key[32];
  #pragma unroll
  for (int it = 0; it < 32; ++it) {
    int j = it*64 + l;
    float xj = cb[j*3+0], yj = cb[j*3+1], zj = cb[j*3+2];
    float sqj = xj*xj + yj*yj + zj*zj;
    float dot = xi*xj + yi*yj + zi*zj;
    float v = sqi + sqj - 2.0f*dot;            // gram-trick, matches reference
    if (j == i) v += 1.0e9f;
    unsigned u = __float_as_uint(v);
    u ^= (u >> 31) ? 0xFFFFFFFFu : 0x80000000u;  // total order = float order
    key[it] = (((unsigned long long)u) << 16) | (unsigned)j;
  }
  // in-register bitonic sort, ascending
  #pragma unroll
  for (int k2 = 2; k2 <= 32; k2 <<= 1) {
    #pragma unroll
    for (int jj = k2 >> 1; jj > 0; jj >>= 1) {
      #pragma unroll
      for (int ii = 0; ii < 32; ++ii) {
        int ixj = ii ^ jj;
        if (ixj > ii) {
          bool up = ((ii & k2) == 0);
          unsigned long long a = key[ii], c = key[ixj];
          bool sw = (a > c) == up;
          unsigned long long lo = sw ? c : a;
          unsigned long long hi = sw ? a : c;
          key[ii] = lo; key[ixj] = hi;
        }
      }
    }
  }
  // sorted list -> LDS (own row only; single wave, no barrier needed)
  unsigned long long* row = heap + l*33;
  #pragma unroll
  for (int it = 0; it < 32; ++it) row[it] = key[it];
  row[32] = 0xFFFFFFFFFFFFFFFFULL;
  // 32 tournament rounds
  int ptr = 0;
  unsigned long long head = key[0];
  int myselidx = 0;
  for (int s = 0; s < KK; ++s) {
    unsigned long long w = head;
    #pragma unroll
    for (int off = 1; off <= 32; off <<= 1) {
      unsigned long long o = __shfl_xor(w, off, 64);
      w = (o < w) ? o : w;
    }
    int wj = (int)(w & 0xFFFFull);
    if (l == s) myselidx = wj;
    if ((wj & 63) == l) { ++ptr; head = row[ptr]; }
  }
  // geometry for the 32 selected edges
  if (l < KK) {
    int j = myselidx;
    idx[node*KK + l] = j;
    float rxv = cb[j*3+0] - xi, ryv = cb[j*3+1] - yi, rzv = cb[j*3+2] - zi;
    float dd = sqrtf(rxv*rxv + ryv*ryv + rzv*rzv + 1e-8f);
    float inv = 1.0f/dd;
    float* dn = dirn + (node*KK + l)*3;
    dn[0] = rxv*inv; dn[1] = ryv*inv; dn[2] = rzv*inv;
    ushort* rb = rbf16 + (size_t)(node*KK + l)*NRBF;
    const float inv2s2 = 1.0f/(2.0f*0.625f*0.625f);
    #pragma unroll
    for (int r = 0; r < NRBF; ++r) {
      float mu = (10.0f/15.0f)*(float)r;
      float dm = dd - mu;
      rb[r] = f2bf(expf(-(dm*dm)*inv2s2));
    }
  }
}

// ---------------------------------------------------------------- f0 init
__global__ __launch_bounds__(256) void k_f0init(const int* __restrict__ seq,
                                                const int* __restrict__ tptr,
                                                const float* __restrict__ atab,
                                                const float* __restrict__ ttab,
                                                const float* __restrict__ Wp0,
                                                const float* __restrict__ bp0,
                                                float* __restrict__ f0) {
  int gidx = blockIdx.x*256 + threadIdx.x;
  int node = gidx >> 6, o = gidx & (H-1);
  int s = seq[node];
  int tv = tptr[0];
  const float* ar = atab + s*32;
  const float* tr = ttab + tv*32;
  float acc = bp0[o];
  for (int i2 = 0; i2 < 32; ++i2) acc = fmaf(ar[i2], Wp0[i2*H + o], acc);
  for (int i2 = 0; i2 < 32; ++i2) acc = fmaf(tr[i2], Wp0[(32+i2)*H + o], acc);
  f0[gidx] = acc;
}

// ---------------------------------------------------------------- f1 init
__global__ __launch_bounds__(256) void k_f1init(const float* __restrict__ coordC,
                                                const float* __restrict__ Wp1,
                                                float* __restrict__ f1) {
  int gidx = blockIdx.x*256 + threadIdx.x;
  if (gidx >= NB*NN*F1W) return;
  int node = gidx / F1W;
  int r = gidx - node*F1W;
  int c = r / 3, d = r - c*3;
  f1[gidx] = coordC[node*3 + d] * Wp1[c];
}

// ---------------------------------------------------------------- weight fragment prep
__global__ __launch_bounds__(256) void k_prep(
    const float* __restrict__ We1, const float* __restrict__ We2,
    const float* __restrict__ Wq,  const float* __restrict__ Wk,
    const float* __restrict__ Wv0, const float* __restrict__ Wv1,
    const float* __restrict__ Wg1, const float* __restrict__ Wo0,
    ushort* __restrict__ wfrag) {
  int gid = blockIdx.x*256 + threadIdx.x;
  if (gid >= NL*NTILES*64) return;
  int lane = gid & 63;
  int tile = gid >> 6;
  int l = tile / NTILES;
  int tt = tile - l*NTILES;
  int part = (tt >= 68) ? 1 : 0;
  int t = part ? (tt - 68) : tt;
  int kt, nt, K = H;
  const float* src = nullptr;
  int wvg = 0;
  if (t < 24)      { kt = t>>2;           nt = t&3; src = We1 + (size_t)l*DIN*H; K = DIN; }
  else if (t < 32) { int u=t-24; kt=u>>2; nt = u&3; src = We2 + (size_t)l*H*H; }
  else if (t < 40) { int u=t-32; kt=u>>2; nt = u&3; src = Wk  + (size_t)l*H*H; }
  else if (t < 48) { int u=t-40; kt=u>>2; nt = u&3; src = Wq  + (size_t)l*H*H; }
  else if (t < 56) { int u=t-48; kt=u>>2; nt = u&3; src = Wv0 + (size_t)l*H*H; }
  else if (t < 60) { int u=t-56; kt=u>>1; nt = u&1; wvg = 1; }
  else             { int u=t-60; kt=u>>2; nt = u&3; src = Wo0 + (size_t)l*H*H; }
  ushort out[8];
  #pragma unroll
  for (int j = 0; j < 8; ++j) {
    int k = kt*32 + (lane>>4)*8 + j;
    int col = nt*16 + (lane&15);
    float v = 0.f;
    if (k < K) {
      if (wvg) v = (col < CV) ? Wv1[(size_t)l*H*CV + k*CV + col]
                              : Wg1[(size_t)l*H*CV + k*CV + (col-CV)];
      else     v = src[(size_t)k*H + col];
    }
    ushort h, lo; split_bf(v, h, lo);
    out[j] = part ? lo : h;
  }
  *(short8v*)(wfrag + (size_t)tile*512 + lane*8) = *(const short8v*)out;
}

// ---------------------------------------------------------------- fused layer
// 128 threads = 2 waves on ONE node; wave w owns edge rows w*16..w*16+15.
// 5 barriers: B1 (broadcast staging), P3->P4 (sQ), P4->P5 (logits),
// P5->P6 (softmax), P6->P7 (sMvg/sAggP).
__global__ __launch_bounds__(128) void k_layer(
    const float* __restrict__ f0i, const float* __restrict__ f1i,
    float* __restrict__ f0o, float* __restrict__ f1o,
    const int* __restrict__ idx, const float* __restrict__ dirn,
    const ushort* __restrict__ rbf16,
    const ushort* __restrict__ wfl,
    const float* __restrict__ be1, const float* __restrict__ be2,
    const float* __restrict__ bo0)
{
  __shared__ __align__(16) ushort regionA  [32*72];   // f0src -> H1 -> fp32 Mvg[32][34]
  __shared__ __align__(16) ushort regionAlo[32*72];
  __shared__ __align__(16) ushort regionB  [32*72];   // [rbf|dotS|dotD|0] -> M
  __shared__ __align__(16) ushort regionBlo[32*72];
  __shared__ __align__(16) ushort sF0h[64], sF0l[64];
  __shared__ __align__(16) ushort sAggH[64], sAggL[64];
  __shared__ float sF1d[F1W];
  __shared__ float sDir[KK][4];
  __shared__ int   sIdx[KK];
  __shared__ float sAtt[KK*9];       // logits then softmax, in place
  __shared__ float sA[KK];
  __shared__ float sQ[64];
  __shared__ float sAggP[2][64];

  const int t    = threadIdx.x;
  const int wid  = t >> 6;
  const int lane = t & 63;
  const int node = blockIdx.x;
  const int bbase = node & ~(NN-1);
  const int r0 = lane & 15, g = lane >> 4;
  const int mrow = wid*16 + r0;
  const floatx4 fz = {0.f, 0.f, 0.f, 0.f};

  // ---- prefetch GEMM1 kt=0 B-frags (global, no deps on anything)
  short8v cbh[4], cbl[4];
  #pragma unroll
  for (int nt = 0; nt < 4; ++nt) {
    cbh[nt] = *(const short8v*)&wfl[(size_t)(nt)*512 + lane*8];
    cbl[nt] = *(const short8v*)&wfl[(size_t)(68 + nt)*512 + lane*8];
  }

  // ---- phase 0: broadcast staging
  float f0reg = 0.f;
  if (wid == 0) {
    f0reg = f0i[node*H + lane];
    ushort h, l; split_bf(f0reg, h, l); sF0h[lane] = h; sF0l[lane] = l;
  } else {
    if (lane < KK)  sIdx[lane] = idx[node*KK + lane];
    if (lane < F1W) sF1d[lane] = f1i[node*F1W + lane];
  }
  if (t < 96) sDir[t/3][t%3] = dirn[node*(KK*3) + t];
  __syncthreads();                                   // B1

  // ---- staging, own rows only (no barrier before P1)
  #pragma unroll 4
  for (int r = 0; r < 16; ++r) {
    int rr = wid*16 + r;
    float v = f0i[(bbase + sIdx[rr])*H + lane];
    ushort h, l; split_bf(v, h, l);
    regionA[rr*72 + lane] = h; regionAlo[rr*72 + lane] = l;
  }
  #pragma unroll
  for (int it = 0; it < 4; ++it) {       // rbf cols 0..15 + zero cols 48..63
    int q = it*64 + lane;
    int k = wid*16 + (q >> 4), c = q & 15;
    regionB  [k*72 + c] = rbf16[(size_t)node*(KK*NRBF) + k*NRBF + c];
    regionBlo[k*72 + c] = 0;
    regionB  [k*72 + 48 + c] = 0;
    regionBlo[k*72 + 48 + c] = 0;
  }
  #pragma unroll
  for (int it = 0; it < 4; ++it) {       // dotS cols 16..31, dotD cols 32..47
    int q = it*64 + lane;
    int k = wid*16 + (q >> 4), ch = q & 15;
    const float* fs = f1i + (size_t)(bbase + sIdx[k])*F1W + ch*3;
    float ds_ = 0.f, dd_ = 0.f;
    #pragma unroll
    for (int d = 0; d < 3; ++d) {
      float dr = sDir[k][d];
      ds_ += fs[d] * dr;
      dd_ += sF1d[ch*3 + d] * dr;
    }
    ushort h, l;
    split_bf(ds_, h, l); regionB[k*72 + 16 + ch] = h; regionBlo[k*72 + 16 + ch] = l;
    split_bf(dd_, h, l); regionB[k*72 + 32 + ch] = h; regionBlo[k*72 + 32 + ch] = l;
  }

  // ---------------- P1: H1 = relu(E @ We1 + be1), K=192, B double-buffered
  floatx4 c1[4];
  #pragma unroll
  for (int nt = 0; nt < 4; ++nt) c1[nt] = fz;
  #pragma unroll
  for (int kt = 0; kt < 6; ++kt) {
    short8v nbh[4], nbl[4];
    if (kt < 5) {
      #pragma unroll
      for (int nt = 0; nt < 4; ++nt) {
        nbh[nt] = *(const short8v*)&wfl[(size_t)((kt+1)*4 + nt)*512 + lane*8];
        nbl[nt] = *(const short8v*)&wfl[(size_t)(68 + (kt+1)*4 + nt)*512 + lane*8];
      }
    }
    short8v ah, al;
    if (kt < 2) {
      ah = *(const short8v*)&sF0h[kt*32 + g*8];
      al = *(const short8v*)&sF0l[kt*32 + g*8];
    } else if (kt < 4) {
      int off = (kt-2)*32 + g*8;
      ah = *(const short8v*)&regionA  [mrow*72 + off];
      al = *(const short8v*)&regionAlo[mrow*72 + off];
    } else {
      int off = ((kt == 4) ? 0 : 32) + g*8;
      ah = *(const short8v*)&regionB  [mrow*72 + off];
      al = *(const short8v*)&regionBlo[mrow*72 + off];
    }
    #pragma unroll
    for (int nt = 0; nt < 4; ++nt) c1[nt] = mfma3(ah, al, cbh[nt], cbl[nt], c1[nt]);
    if (kt < 5) {
      #pragma unroll
      for (int nt = 0; nt < 4; ++nt) { cbh[nt] = nbh[nt]; cbl[nt] = nbl[nt]; }
    }
  }
  // issue P2 B loads now (in flight over H1 epilogue)
  short8v b2h[8], b2l[8];
  #pragma unroll
  for (int i2 = 0; i2 < 8; ++i2) {
    b2h[i2] = *(const short8v*)&wfl[(size_t)(24 + i2)*512 + lane*8];
    b2l[i2] = *(const short8v*)&wfl[(size_t)(92 + i2)*512 + lane*8];
  }
  // H1 epilogue (own rows; no barrier)
  #pragma unroll
  for (int nt = 0; nt < 4; ++nt) {
    float be = be1[nt*16 + r0];
    #pragma unroll
    for (int i = 0; i < 4; ++i) {
      float v = fmaxf(c1[nt][i] + be, 0.f);
      ushort h, l; split_bf(v, h, l);
      regionA  [(wid*16 + g*4 + i)*72 + nt*16 + r0] = h;
      regionAlo[(wid*16 + g*4 + i)*72 + nt*16 + r0] = l;
    }
  }

  // ---------------- P2: M = H1 @ We2 + be2 (own rows; no barrier)
  floatx4 c2[4];
  #pragma unroll
  for (int nt = 0; nt < 4; ++nt) c2[nt] = fz;
  #pragma unroll
  for (int kt = 0; kt < 2; ++kt) {
    int off = kt*32 + g*8;
    short8v ah = *(const short8v*)&regionA  [mrow*72 + off];
    short8v al = *(const short8v*)&regionAlo[mrow*72 + off];
    #pragma unroll
    for (int nt = 0; nt < 4; ++nt)
      c2[nt] = mfma3(ah, al, b2h[kt*4 + nt], b2l[kt*4 + nt], c2[nt]);
  }
  #pragma unroll
  for (int nt = 0; nt < 4; ++nt) {
    float be = be2[nt*16 + r0];
    #pragma unroll
    for (int i = 0; i < 4; ++i) {
      ushort h, l; split_bf(c2[nt][i] + be, h, l);
      regionB  [(wid*16 + g*4 + i)*72 + nt*16 + r0] = h;
      regionBlo[(wid*16 + g*4 + i)*72 + nt*16 + r0] = l;
    }
  }

  // ---------------- P3: wave0 q = f0@Wq -> sQ ; wave1 ck(mt=1)
  floatx4 ck[4];
  #pragma unroll
  for (int nt = 0; nt < 4; ++nt) ck[nt] = fz;
  if (wid == 0) {
    floatx4 cq[4];
    #pragma unroll
    for (int nt = 0; nt < 4; ++nt) cq[nt] = fz;
    #pragma unroll
    for (int kt = 0; kt < 2; ++kt) {
      short8v ah = *(const short8v*)&sF0h[kt*32 + g*8];
      short8v al = *(const short8v*)&sF0l[kt*32 + g*8];
      #pragma unroll
      for (int nt = 0; nt < 4; ++nt) {
        short8v bh = *(const short8v*)&wfl[(size_t)(40 + kt*4 + nt)*512 + lane*8];
        short8v bl = *(const short8v*)&wfl[(size_t)(108 + kt*4 + nt)*512 + lane*8];
        cq[nt] = mfma3(ah, al, bh, bl, cq[nt]);
      }
    }
    if (g == 0) {
      #pragma unroll
      for (int nt = 0; nt < 4; ++nt) sQ[nt*16 + r0] = cq[nt][0];
    }
  } else {
    #pragma unroll
    for (int kt = 0; kt < 2; ++kt) {
      int off = kt*32 + g*8;
      short8v ah = *(const short8v*)&regionB  [mrow*72 + off];
      short8v al = *(const short8v*)&regionBlo[mrow*72 + off];
      #pragma unroll
      for (int nt = 0; nt < 4; ++nt) {
        short8v bh = *(const short8v*)&wfl[(size_t)(32 + kt*4 + nt)*512 + lane*8];
        short8v bl = *(const short8v*)&wfl[(size_t)(100 + kt*4 + nt)*512 + lane*8];
        ck[nt] = mfma3(ah, al, bh, bl, ck[nt]);
      }
    }
  }
  __syncthreads();                                   // B2 (sQ)

  // ---------------- P4: wave0 ck(mt=0) | wave1 V0(mt=1); both write logits
  floatx4 cv[4];
  #pragma unroll
  for (int nt = 0; nt < 4; ++nt) cv[nt] = fz;
  if (wid == 0) {
    #pragma unroll
    for (int kt = 0; kt < 2; ++kt) {
      int off = kt*32 + g*8;
      short8v ah = *(const short8v*)&regionB  [mrow*72 + off];
      short8v al = *(const short8v*)&regionBlo[mrow*72 + off];
      #pragma unroll
      for (int nt = 0; nt < 4; ++nt) {
        short8v bh = *(const short8v*)&wfl[(size_t)(32 + kt*4 + nt)*512 + lane*8];
        short8v bl = *(const short8v*)&wfl[(size_t)(100 + kt*4 + nt)*512 + lane*8];
        ck[nt] = mfma3(ah, al, bh, bl, ck[nt]);
      }
    }
  } else {
    #pragma unroll
    for (int kt = 0; kt < 2; ++kt) {
      int off = kt*32 + g*8;
      short8v ah = *(const short8v*)&regionB  [mrow*72 + off];
      short8v al = *(const short8v*)&regionBlo[mrow*72 + off];
      #pragma unroll
      for (int nt = 0; nt < 4; ++nt) {
        short8v bh = *(const short8v*)&wfl[(size_t)(48 + kt*4 + nt)*512 + lane*8];
        short8v bl = *(const short8v*)&wfl[(size_t)(116 + kt*4 + nt)*512 + lane*8];
        cv[nt] = mfma3(ah, al, bh, bl, cv[nt]);
      }
    }
  }
  {
    float qv[4];
    #pragma unroll
    for (int nt = 0; nt < 4; ++nt) qv[nt] = sQ[nt*16 + r0];
    #pragma unroll
    for (int nt = 0; nt < 4; ++nt)
      #pragma unroll
      for (int i = 0; i < 4; ++i) {
        float v = ck[nt][i] * qv[nt];
        v += __shfl_xor(v, 1, 64);
        v += __shfl_xor(v, 2, 64);
        v += __shfl_xor(v, 4, 64);
        if ((lane & 7) == 0)
          sAtt[(wid*16 + g*4 + i)*9 + nt*2 + (r0 >> 3)] = v * 0.35355339059327373f;
      }
  }
  __syncthreads();                                   // B3 (logits)

  // ---------------- P5: wave1 softmax (in place) | wave0 V0(mt0)+Mvg(mt0)
  floatx4 cvg[2];
  cvg[0] = fz; cvg[1] = fz;
  if (wid == 1) {
    int h = lane & 7, seg = lane >> 3;
    float l0[4];
    float mx = -3.0e38f;
    #pragma unroll
    for (int i = 0; i < 4; ++i) { l0[i] = sAtt[(seg*4 + i)*9 + h]; mx = fmaxf(mx, l0[i]); }
    #pragma unroll
    for (int off = 8; off <= 32; off <<= 1) mx = fmaxf(mx, __shfl_xor(mx, off, 64));
    float e0[4], sum = 0.f;
    #pragma unroll
    for (int i = 0; i < 4; ++i) { e0[i] = expf(l0[i] - mx); sum += e0[i]; }
    #pragma unroll
    for (int off = 8; off <= 32; off <<= 1) sum += __shfl_xor(sum, off, 64);
    float inv = 1.0f / sum;
    #pragma unroll
    for (int i = 0; i < 4; ++i) {
      float a = e0[i] * inv;
      sAtt[(seg*4 + i)*9 + h] = a;
      float tt = a;
      tt += __shfl_xor(tt, 1, 64);
      tt += __shfl_xor(tt, 2, 64);
      tt += __shfl_xor(tt, 4, 64);
      if (h == 0) sA[seg*4 + i] = tt * 0.125f;
    }
  } else {
    #pragma unroll
    for (int kt = 0; kt < 2; ++kt) {
      int off = kt*32 + g*8;
      short8v ah = *(const short8v*)&regionB  [mrow*72 + off];
      short8v al = *(const short8v*)&regionBlo[mrow*72 + off];
      #pragma unroll
      for (int nt = 0; nt < 4; ++nt) {
        short8v bh = *(const short8v*)&wfl[(size_t)(48 + kt*4 + nt)*512 + lane*8];
        short8v bl = *(const short8v*)&wfl[(size_t)(116 + kt*4 + nt)*512 + lane*8];
        cv[nt] = mfma3(ah, al, bh, bl, cv[nt]);
      }
      #pragma unroll
      for (int nt = 0; nt < 2; ++nt) {
        short8v bh = *(const short8v*)&wfl[(size_t)(56 + kt*2 + nt)*512 + lane*8];
        short8v bl = *(const short8v*)&wfl[(size_t)(124 + kt*2 + nt)*512 + lane*8];
        cvg[nt] = mfma3(ah, al, bh, bl, cvg[nt]);
      }
    }
    float* sMvg = (float*)regionA;     // rows 0..15 (bytes disjoint from wave1 use)
    #pragma unroll
    for (int nt = 0; nt < 2; ++nt)
      #pragma unroll
      for (int i = 0; i < 4; ++i)
        sMvg[(g*4 + i)*34 + nt*16 + r0] = cvg[nt][i];
  }
  __syncthreads();                                   // B4 (softmax)

  // ---------------- P6: both agg-partial; wave1 Mvg(mt1); wave0 prefetch Wo0
  short8v b7h[8], b7l[8];
  if (wid == 0) {
    #pragma unroll
    for (int i2 = 0; i2 < 8; ++i2) {
      b7h[i2] = *(const short8v*)&wfl[(size_t)(60 + i2)*512 + lane*8];
      b7l[i2] = *(const short8v*)&wfl[(size_t)(128 + i2)*512 + lane*8];
    }
  }
  {
    int hsub = r0 >> 3;
    #pragma unroll
    for (int nt = 0; nt < 4; ++nt) {
      float p = 0.f;
      #pragma unroll
      for (int i = 0; i < 4; ++i)
        p += sAtt[(wid*16 + g*4 + i)*9 + nt*2 + hsub] * cv[nt][i];
      p += __shfl_xor(p, 16, 64);
      p += __shfl_xor(p, 32, 64);
      if (g == 0) sAggP[wid][nt*16 + r0] = p;
    }
  }
  if (wid == 1) {
    cvg[0] = fz; cvg[1] = fz;
    #pragma unroll
    for (int kt = 0; kt < 2; ++kt) {
      int off = kt*32 + g*8;
      short8v ah = *(const short8v*)&regionB  [mrow*72 + off];
      short8v al = *(const short8v*)&regionBlo[mrow*72 + off];
      #pragma unroll
      for (int nt = 0; nt < 2; ++nt) {
        short8v bh = *(const short8v*)&wfl[(size_t)(56 + kt*2 + nt)*512 + lane*8];
        short8v bl = *(const short8v*)&wfl[(size_t)(124 + kt*2 + nt)*512 + lane*8];
        cvg[nt] = mfma3(ah, al, bh, bl, cvg[nt]);
      }
    }
    float* sMvg = (float*)regionA;
    #pragma unroll
    for (int nt = 0; nt < 2; ++nt)
      #pragma unroll
      for (int i = 0; i < 4; ++i)
        sMvg[(16 + g*4 + i)*34 + nt*16 + r0] = cvg[nt][i];
  }
  __syncthreads();                                   // B5 (sMvg/sAggP)

  // ---------------- P7: wave0 f0 out | wave1 f1 out
  if (wid == 0) {
    {
      float p = sAggP[0][lane] + sAggP[1][lane];
      ushort h, l; split_bf(p, h, l);
      sAggH[lane] = h; sAggL[lane] = l;
    }
    floatx4 co[4];
    #pragma unroll
    for (int nt = 0; nt < 4; ++nt) co[nt] = fz;
    #pragma unroll
    for (int kt = 0; kt < 2; ++kt) {
      short8v ah = *(const short8v*)&sAggH[kt*32 + g*8];
      short8v al = *(const short8v*)&sAggL[kt*32 + g*8];
      #pragma unroll
      for (int nt = 0; nt < 4; ++nt)
        co[nt] = mfma3(ah, al, b7h[kt*4 + nt], b7l[kt*4 + nt], co[nt]);
    }
    float v = (g == 0) ? co[0][0] : (g == 1) ? co[1][0] : (g == 2) ? co[2][0] : co[3][0];
    f0o[node*H + lane] = f0reg + v + bo0[lane];
  } else if (lane < F1W) {
    const float* sMvg = (const float*)regionA;
    int ch = lane / 3, d = lane - ch*3;
    float acc = sF1d[lane];
    #pragma unroll 8
    for (int k = 0; k < KK; ++k) {
      float f1s = f1i[(size_t)(bbase + sIdx[k])*F1W + lane];
      float a   = sA[k];
      float mv1 = sMvg[k*34 + ch];
      float mg1 = sMvg[k*34 + 16 + ch];
      acc += a * (sDir[k][d]*mv1 + mg1*f1s);
    }
    f1o[node*F1W + lane] = acc;
  }
}

// ---------------------------------------------------------------- output
__global__ __launch_bounds__(256) void k_out(const float* __restrict__ f1,
                                             const float* __restrict__ Wout1,
                                             float* __restrict__ out) {
  int gidx = blockIdx.x*256 + threadIdx.x;
  if (gidx >= NB*NN*3) return;
  int node = gidx / 3, d = gidx - node*3;
  float acc = 0.f;
  for (int c = 0; c < CV; ++c) acc = fmaf(f1[node*F1W + c*3 + d], Wout1[c], acc);
  out[gidx] = acc;
}

// ---------------------------------------------------------------- launch
extern "C" void kernel_launch(void* const* d_in, const int* in_sizes, int n_in,
                              void* d_out, int out_size, void* d_ws, size_t ws_size,
                              hipStream_t stream) {
  const int*   seq   = (const int*)  d_in[0];
  const float* coord = (const float*)d_in[1];
  const int*   tptr  = (const int*)  d_in[2];
  const float* atab  = (const float*)d_in[3];
  const float* ttab  = (const float*)d_in[4];
  const float* Wp0   = (const float*)d_in[5];
  const float* bp0   = (const float*)d_in[6];
  const float* Wp1   = (const float*)d_in[7];
  const float* We1   = (const float*)d_in[8];
  const float* be1   = (const float*)d_in[9];
  const float* We2   = (const float*)d_in[10];
  const float* be2   = (const float*)d_in[11];
  const float* Wq    = (const float*)d_in[12];
  const float* Wk    = (const float*)d_in[13];
  const float* Wv0   = (const float*)d_in[14];
  const float* Wv1   = (const float*)d_in[15];
  const float* Wg1   = (const float*)d_in[16];
  const float* Wo0   = (const float*)d_in[17];
  const float* bo0   = (const float*)d_in[18];
  const float* Wout1 = (const float*)d_in[19];
  float* out = (float*)d_out;

  float* ws = (float*)d_ws;
  float*  coordC = ws;
  int*    idxb   = (int*)(ws + 12288);
  float*  dirn   = ws + 12288 + 131072;
  float*  f0A    = dirn + (size_t)NB*NN*KK*3;
  float*  f0B    = f0A + (size_t)NB*NN*H;
  float*  f1A    = f0B + (size_t)NB*NN*H;
  float*  f1B    = f1A + (size_t)NB*NN*F1W;
  ushort* rbf16  = (ushort*)(f1B + (size_t)NB*NN*F1W);
  ushort* wfrag  = rbf16 + (size_t)NB*NN*KK*NRBF;

  k_center<<<NB, 256, 0, stream>>>(coord, coordC);
  k_knn<<<NB*NN, 64, 0, stream>>>(coordC, idxb, dirn, rbf16);
  k_f0init<<<NB*NN*H/256, 256, 0, stream>>>(seq, tptr, atab, ttab, Wp0, bp0, f0A);
  k_f1init<<<(NB*NN*F1W + 255)/256, 256, 0, stream>>>(coordC, Wp1, f1A);
  k_prep<<<(NL*NTILES*64 + 255)/256, 256, 0, stream>>>(We1, We2, Wq, Wk, Wv0, Wv1, Wg1, Wo0, wfrag);

  const float* f0in = f0A; float* f0out = f0B;
  const float* f1in = f1A; float* f1out = f1B;
  for (int l = 0; l < NL; ++l) {
    k_layer<<<NB*NN, 128, 0, stream>>>(
        f0in, f1in, f0out, f1out, idxb, dirn, rbf16,
        wfrag + (size_t)l*NTILES*512,
        be1 + (size_t)l*H, be2 + (size_t)l*H, bo0 + (size_t)l*H);
    const float* tf0 = f0in; f0in = f0out; f0out = (float*)tf0;
    const float* tf1 = f1in; f1in = f1out; f1out = (float*)tf1;
  }
  k_out<<<(NB*NN*3 + 255)/256, 256, 0, stream>>>(f1in, Wout1, out);
}

// Round 9
// 328.067 us; speedup vs baseline: 6.1957x; 1.1246x over previous
//
#include <hip/hip_runtime.h>
#include <hip/hip_bf16.h>
#include <math.h>

#define NL    4
#define H     64
#define CV    16
#define NRBF  16
#define HEADS 8
#define KK    32
#define DIN   176
#define NB    2
#define NN    2048
#define F1W   (CV*3)   // 48
#define NTILES 136     // 68 hi + 68 lo per layer

typedef __attribute__((ext_vector_type(8))) short short8v;
typedef __attribute__((ext_vector_type(4))) float floatx4;

__device__ __forceinline__ ushort f2bf(float f) {
  union { float f; unsigned u; } v; v.f = f;
  unsigned r = v.u + 0x7FFFu + ((v.u >> 16) & 1u);
  return (ushort)(r >> 16);
}
__device__ __forceinline__ float bf2f(ushort s) {
  union { unsigned u; float f; } v; v.u = ((unsigned)s) << 16;
  return v.f;
}
__device__ __forceinline__ void split_bf(float v, ushort& h, ushort& l) {
  h = f2bf(v);
  l = f2bf(v - bf2f(h));
}
__device__ __forceinline__ floatx4 mfma3(short8v ah, short8v al,
                                         short8v bh, short8v bl, floatx4 acc) {
  acc = __builtin_amdgcn_mfma_f32_16x16x32_bf16(ah, bh, acc, 0, 0, 0);
  acc = __builtin_amdgcn_mfma_f32_16x16x32_bf16(ah, bl, acc, 0, 0, 0);
  acc = __builtin_amdgcn_mfma_f32_16x16x32_bf16(al, bh, acc, 0, 0, 0);
  return acc;
}

// ---------------------------------------------------------------- center
__global__ __launch_bounds__(256) void k_center(const float* __restrict__ coord,
                                                float* __restrict__ coordC) {
  __shared__ float rx[256], ry[256], rz[256];
  int b = blockIdx.x;
  const float* cb = coord + b*NN*3;
  float sx = 0.f, sy = 0.f, sz = 0.f;
  for (int i = threadIdx.x; i < NN; i += 256) {
    sx += cb[i*3+0]; sy += cb[i*3+1]; sz += cb[i*3+2];
  }
  rx[threadIdx.x] = sx; ry[threadIdx.x] = sy; rz[threadIdx.x] = sz;
  __syncthreads();
  for (int s = 128; s > 0; s >>= 1) {
    if (threadIdx.x < s) {
      rx[threadIdx.x] += rx[threadIdx.x+s];
      ry[threadIdx.x] += ry[threadIdx.x+s];
      rz[threadIdx.x] += rz[threadIdx.x+s];
    }
    __syncthreads();
  }
  float mx = rx[0]*(1.0f/NN), my = ry[0]*(1.0f/NN), mz = rz[0]*(1.0f/NN);
  float* ob = coordC + b*NN*3;
  for (int i = threadIdx.x; i < NN; i += 256) {
    ob[i*3+0] = cb[i*3+0] - mx;
    ob[i*3+1] = cb[i*3+1] - my;
    ob[i*3+2] = cb[i*3+2] - mz;
  }
}

// ---------------------------------------------------------------- knn (bitonic, unchanged from r8)
__global__ __launch_bounds__(64) void k_knn(const float* __restrict__ coordC,
                                            int* __restrict__ idx,
                                            float* __restrict__ dirn,
                                            ushort* __restrict__ rbf16) {
  __shared__ unsigned long long heap[64*33];
  const int node = blockIdx.x;
  const int b = node >> 11;
  const int i = node & (NN-1);
  const int l = threadIdx.x;
  const float* cb = coordC + b*NN*3;
  const float xi = cb[i*3+0], yi = cb[i*3+1], zi = cb[i*3+2];
  const float sqi = xi*xi + yi*yi + zi*zi;
  unsigned long long key[32];
  #pragma unroll
  for (int it = 0; it < 32; ++it) {
    int j = it*64 + l;
    float xj = cb[j*3+0], yj = cb[j*3+1], zj = cb[j*3+2];
    float sqj = xj*xj + yj*yj + zj*zj;
    float dot = xi*xj + yi*yj + zi*zj;
    float v = sqi + sqj - 2.0f*dot;
    if (j == i) v += 1.0e9f;
    unsigned u = __float_as_uint(v);
    u ^= (u >> 31) ? 0xFFFFFFFFu : 0x80000000u;
    key[it] = (((unsigned long long)u) << 16) | (unsigned)j;
  }
  #pragma unroll
  for (int k2 = 2; k2 <= 32; k2 <<= 1) {
    #pragma unroll
    for (int jj = k2 >> 1; jj > 0; jj >>= 1) {
      #pragma unroll
      for (int ii = 0; ii < 32; ++ii) {
        int ixj = ii ^ jj;
        if (ixj > ii) {
          bool up = ((ii & k2) == 0);
          unsigned long long a = key[ii], c = key[ixj];
          bool sw = (a > c) == up;
          unsigned long long lo = sw ? c : a;
          unsigned long long hi = sw ? a : c;
          key[ii] = lo; key[ixj] = hi;
        }
      }
    }
  }
  unsigned long long* row = heap + l*33;
  #pragma unroll
  for (int it = 0; it < 32; ++it) row[it] = key[it];
  row[32] = 0xFFFFFFFFFFFFFFFFULL;
  int ptr = 0;
  unsigned long long head = key[0];
  int myselidx = 0;
  for (int s = 0; s < KK; ++s) {
    unsigned long long w = head;
    #pragma unroll
    for (int off = 1; off <= 32; off <<= 1) {
      unsigned long long o = __shfl_xor(w, off, 64);
      w = (o < w) ? o : w;
    }
    int wj = (int)(w & 0xFFFFull);
    if (l == s) myselidx = wj;
    if ((wj & 63) == l) { ++ptr; head = row[ptr]; }
  }
  if (l < KK) {
    int j = myselidx;
    idx[node*KK + l] = j;
    float rxv = cb[j*3+0] - xi, ryv = cb[j*3+1] - yi, rzv = cb[j*3+2] - zi;
    float dd = sqrtf(rxv*rxv + ryv*ryv + rzv*rzv + 1e-8f);
    float inv = 1.0f/dd;
    float* dn = dirn + (node*KK + l)*3;
    dn[0] = rxv*inv; dn[1] = ryv*inv; dn[2] = rzv*inv;
    ushort* rb = rbf16 + (size_t)(node*KK + l)*NRBF;
    const float inv2s2 = 1.0f/(2.0f*0.625f*0.625f);
    #pragma unroll
    for (int r = 0; r < NRBF; ++r) {
      float mu = (10.0f/15.0f)*(float)r;
      float dm = dd - mu;
      rb[r] = f2bf(expf(-(dm*dm)*inv2s2));
    }
  }
}

// ---------------------------------------------------------------- f0 init
__global__ __launch_bounds__(256) void k_f0init(const int* __restrict__ seq,
                                                const int* __restrict__ tptr,
                                                const float* __restrict__ atab,
                                                const float* __restrict__ ttab,
                                                const float* __restrict__ Wp0,
                                                const float* __restrict__ bp0,
                                                float* __restrict__ f0) {
  int gidx = blockIdx.x*256 + threadIdx.x;
  int node = gidx >> 6, o = gidx & (H-1);
  int s = seq[node];
  int tv = tptr[0];
  const float* ar = atab + s*32;
  const float* tr = ttab + tv*32;
  float acc = bp0[o];
  for (int i2 = 0; i2 < 32; ++i2) acc = fmaf(ar[i2], Wp0[i2*H + o], acc);
  for (int i2 = 0; i2 < 32; ++i2) acc = fmaf(tr[i2], Wp0[(32+i2)*H + o], acc);
  f0[gidx] = acc;
}

// ---------------------------------------------------------------- f1 init
__global__ __launch_bounds__(256) void k_f1init(const float* __restrict__ coordC,
                                                const float* __restrict__ Wp1,
                                                float* __restrict__ f1) {
  int gidx = blockIdx.x*256 + threadIdx.x;
  if (gidx >= NB*NN*F1W) return;
  int node = gidx / F1W;
  int r = gidx - node*F1W;
  int c = r / 3, d = r - c*3;
  f1[gidx] = coordC[node*3 + d] * Wp1[c];
}

// ---------------------------------------------------------------- weight fragment prep
__global__ __launch_bounds__(256) void k_prep(
    const float* __restrict__ We1, const float* __restrict__ We2,
    const float* __restrict__ Wq,  const float* __restrict__ Wk,
    const float* __restrict__ Wv0, const float* __restrict__ Wv1,
    const float* __restrict__ Wg1, const float* __restrict__ Wo0,
    ushort* __restrict__ wfrag) {
  int gid = blockIdx.x*256 + threadIdx.x;
  if (gid >= NL*NTILES*64) return;
  int lane = gid & 63;
  int tile = gid >> 6;
  int l = tile / NTILES;
  int tt = tile - l*NTILES;
  int part = (tt >= 68) ? 1 : 0;
  int t = part ? (tt - 68) : tt;
  int kt, nt, K = H;
  const float* src = nullptr;
  int wvg = 0;
  if (t < 24)      { kt = t>>2;           nt = t&3; src = We1 + (size_t)l*DIN*H; K = DIN; }
  else if (t < 32) { int u=t-24; kt=u>>2; nt = u&3; src = We2 + (size_t)l*H*H; }
  else if (t < 40) { int u=t-32; kt=u>>2; nt = u&3; src = Wk  + (size_t)l*H*H; }
  else if (t < 48) { int u=t-40; kt=u>>2; nt = u&3; src = Wq  + (size_t)l*H*H; }
  else if (t < 56) { int u=t-48; kt=u>>2; nt = u&3; src = Wv0 + (size_t)l*H*H; }
  else if (t < 60) { int u=t-56; kt=u>>1; nt = u&1; wvg = 1; }
  else             { int u=t-60; kt=u>>2; nt = u&3; src = Wo0 + (size_t)l*H*H; }
  ushort out[8];
  #pragma unroll
  for (int j = 0; j < 8; ++j) {
    int k = kt*32 + (lane>>4)*8 + j;
    int col = nt*16 + (lane&15);
    float v = 0.f;
    if (k < K) {
      if (wvg) v = (col < CV) ? Wv1[(size_t)l*H*CV + k*CV + col]
                              : Wg1[(size_t)l*H*CV + k*CV + (col-CV)];
      else     v = src[(size_t)k*H + col];
    }
    ushort h, lo; split_bf(v, h, lo);
    out[j] = part ? lo : h;
  }
  *(short8v*)(wfrag + (size_t)tile*512 + lane*8) = *(const short8v*)out;
}

// ---------------------------------------------------------------- fused layer
// 256 threads = 4 waves on ONE node. Wave wid: mt = wid>>1 (rows mt*16..+15),
// nh = wid&1 (col half, nt tiles {2nh, 2nh+1}).
__global__ __launch_bounds__(256, 6) void k_layer(
    const float* __restrict__ f0i, const float* __restrict__ f1i,
    float* __restrict__ f0o, float* __restrict__ f1o,
    const int* __restrict__ idx, const float* __restrict__ dirn,
    const ushort* __restrict__ rbf16,
    const ushort* __restrict__ wfl,
    const float* __restrict__ be1, const float* __restrict__ be2,
    const float* __restrict__ bo0)
{
  __shared__ __align__(16) ushort regionA  [32*72];   // f0src -> H1 -> fp32 sMvg[32][34]
  __shared__ __align__(16) ushort regionAlo[32*72];
  __shared__ __align__(16) ushort regionB  [32*72];   // [rbf|dotS|dotD|0] -> M
  __shared__ __align__(16) ushort regionBlo[32*72];
  __shared__ __align__(16) ushort sF0h[64], sF0l[64];
  __shared__ __align__(16) ushort sAggH[64], sAggL[64];
  __shared__ float sF1d[F1W];
  __shared__ float sDir[KK][4];
  __shared__ int   sIdx[KK];
  __shared__ float sAtt[KK*9];       // logits then softmax, in place
  __shared__ float sA[KK];
  __shared__ float sQ[64];
  __shared__ float sAggP[2][64];
  __shared__ float sAPart[4][32];

  const int t    = threadIdx.x;
  const int wid  = t >> 6;
  const int lane = t & 63;
  const int mt   = wid >> 1;
  const int nh   = wid & 1;
  const int node = blockIdx.x;
  const int bbase = node & ~(NN-1);
  const int r0 = lane & 15, g = lane >> 4;
  const int mrow = mt*16 + r0;
  const floatx4 fz = {0.f, 0.f, 0.f, 0.f};

  // ---------------- S0: broadcast staging
  float f0reg = 0.f;
  if (wid == 0) {
    f0reg = f0i[node*H + lane];
    ushort h, l; split_bf(f0reg, h, l); sF0h[lane] = h; sF0l[lane] = l;
  } else if (wid == 1) {
    if (lane < KK) sIdx[lane] = idx[node*KK + lane];
  } else if (wid == 2) {
    if (lane < F1W) sF1d[lane] = f1i[node*F1W + lane];
  } else {
    sDir[lane/3][lane%3] = dirn[node*(KK*3) + lane];
    if (lane < 32) {
      int e = 64 + lane;
      sDir[e/3][e%3] = dirn[node*(KK*3) + e];
    }
  }
  __syncthreads();                                   // B0

  // ---------------- S1: staging split over 4 waves
  #pragma unroll
  for (int r = 0; r < 8; ++r) {
    int rr = wid*8 + r;
    float v = f0i[(bbase + sIdx[rr])*H + lane];
    ushort h, l; split_bf(v, h, l);
    regionA[rr*72 + lane] = h; regionAlo[rr*72 + lane] = l;
  }
  #pragma unroll
  for (int it = 0; it < 2; ++it) {       // rbf cols 0..15 + zero cols 48..63
    int p = it*256 + t;
    int k = p >> 4, c = p & 15;
    regionB  [k*72 + c] = rbf16[(size_t)node*(KK*NRBF) + p];
    regionBlo[k*72 + c] = 0;
    regionB  [k*72 + 48 + c] = 0;
    regionBlo[k*72 + 48 + c] = 0;
  }
  #pragma unroll
  for (int it = 0; it < 2; ++it) {       // dotS cols 16..31, dotD cols 32..47
    int p = it*256 + t;
    int k = p >> 4, ch = p & 15;
    const float* fs = f1i + (size_t)(bbase + sIdx[k])*F1W + ch*3;
    float ds_ = 0.f, dd_ = 0.f;
    #pragma unroll
    for (int d = 0; d < 3; ++d) {
      float dr = sDir[k][d];
      ds_ += fs[d] * dr;
      dd_ += sF1d[ch*3 + d] * dr;
    }
    ushort h, l;
    split_bf(ds_, h, l); regionB[k*72 + 16 + ch] = h; regionBlo[k*72 + 16 + ch] = l;
    split_bf(dd_, h, l); regionB[k*72 + 32 + ch] = h; regionBlo[k*72 + 32 + ch] = l;
  }
  __syncthreads();                                   // B1

  // ---------------- P1: H1 = relu(E @ We1 + be1); quarter (rows mt, nt pair nh)
  floatx4 c1[2]; c1[0] = fz; c1[1] = fz;
  #pragma unroll
  for (int kt = 0; kt < 6; ++kt) {
    short8v ah, al;
    if (kt < 2) {
      ah = *(const short8v*)&sF0h[kt*32 + g*8];
      al = *(const short8v*)&sF0l[kt*32 + g*8];
    } else if (kt < 4) {
      int off = (kt-2)*32 + g*8;
      ah = *(const short8v*)&regionA  [mrow*72 + off];
      al = *(const short8v*)&regionAlo[mrow*72 + off];
    } else {
      int off = ((kt == 4) ? 0 : 32) + g*8;
      ah = *(const short8v*)&regionB  [mrow*72 + off];
      al = *(const short8v*)&regionBlo[mrow*72 + off];
    }
    #pragma unroll
    for (int j = 0; j < 2; ++j) {
      int ntg = nh*2 + j;
      short8v bh = *(const short8v*)&wfl[(size_t)(kt*4 + ntg)*512 + lane*8];
      short8v bl = *(const short8v*)&wfl[(size_t)(68 + kt*4 + ntg)*512 + lane*8];
      c1[j] = mfma3(ah, al, bh, bl, c1[j]);
    }
  }
  #pragma unroll
  for (int j = 0; j < 2; ++j) {
    int ntg = nh*2 + j;
    float be = be1[ntg*16 + r0];
    #pragma unroll
    for (int i = 0; i < 4; ++i) {
      float v = fmaxf(c1[j][i] + be, 0.f);
      ushort h, l; split_bf(v, h, l);
      regionA  [(mt*16 + g*4 + i)*72 + ntg*16 + r0] = h;
      regionAlo[(mt*16 + g*4 + i)*72 + ntg*16 + r0] = l;
    }
  }
  __syncthreads();                                   // B2

  // ---------------- P2: M = H1 @ We2 + be2; quarter
  floatx4 c2[2]; c2[0] = fz; c2[1] = fz;
  #pragma unroll
  for (int kt = 0; kt < 2; ++kt) {
    int off = kt*32 + g*8;
    short8v ah = *(const short8v*)&regionA  [mrow*72 + off];
    short8v al = *(const short8v*)&regionAlo[mrow*72 + off];
    #pragma unroll
    for (int j = 0; j < 2; ++j) {
      int ntg = nh*2 + j;
      short8v bh = *(const short8v*)&wfl[(size_t)(24 + kt*4 + ntg)*512 + lane*8];
      short8v bl = *(const short8v*)&wfl[(size_t)(92 + kt*4 + ntg)*512 + lane*8];
      c2[j] = mfma3(ah, al, bh, bl, c2[j]);
    }
  }
  __syncthreads();                                   // B3a (all H1 reads done before M overwrites regionB? M goes to regionB, H1 is in regionA - no hazard; barrier needed only for M-completeness later)
  #pragma unroll
  for (int j = 0; j < 2; ++j) {
    int ntg = nh*2 + j;
    float be = be2[ntg*16 + r0];
    #pragma unroll
    for (int i = 0; i < 4; ++i) {
      ushort h, l; split_bf(c2[j][i] + be, h, l);
      regionB  [(mt*16 + g*4 + i)*72 + ntg*16 + r0] = h;
      regionBlo[(mt*16 + g*4 + i)*72 + ntg*16 + r0] = l;
    }
  }
  __syncthreads();                                   // B3 (M complete)

  // ---------------- P3: all: ck quarter; mt0: q; mt1: V0 quarter
  floatx4 ck[2]; ck[0] = fz; ck[1] = fz;
  floatx4 cv[2]; cv[0] = fz; cv[1] = fz;
  #pragma unroll
  for (int kt = 0; kt < 2; ++kt) {
    int off = kt*32 + g*8;
    short8v ah = *(const short8v*)&regionB  [mrow*72 + off];
    short8v al = *(const short8v*)&regionBlo[mrow*72 + off];
    #pragma unroll
    for (int j = 0; j < 2; ++j) {
      int ntg = nh*2 + j;
      short8v bh = *(const short8v*)&wfl[(size_t)(32 + kt*4 + ntg)*512 + lane*8];
      short8v bl = *(const short8v*)&wfl[(size_t)(100 + kt*4 + ntg)*512 + lane*8];
      ck[j] = mfma3(ah, al, bh, bl, ck[j]);
    }
  }
  if (mt == 0) {
    floatx4 cq[2]; cq[0] = fz; cq[1] = fz;
    #pragma unroll
    for (int kt = 0; kt < 2; ++kt) {
      short8v ah = *(const short8v*)&sF0h[kt*32 + g*8];
      short8v al = *(const short8v*)&sF0l[kt*32 + g*8];
      #pragma unroll
      for (int j = 0; j < 2; ++j) {
        int ntg = nh*2 + j;
        short8v bh = *(const short8v*)&wfl[(size_t)(40 + kt*4 + ntg)*512 + lane*8];
        short8v bl = *(const short8v*)&wfl[(size_t)(108 + kt*4 + ntg)*512 + lane*8];
        cq[j] = mfma3(ah, al, bh, bl, cq[j]);
      }
    }
    if (g == 0) {
      sQ[(nh*2 + 0)*16 + r0] = cq[0][0];
      sQ[(nh*2 + 1)*16 + r0] = cq[1][0];
    }
  } else {
    #pragma unroll
    for (int kt = 0; kt < 2; ++kt) {
      int off = kt*32 + g*8;
      short8v ah = *(const short8v*)&regionB  [mrow*72 + off];
      short8v al = *(const short8v*)&regionBlo[mrow*72 + off];
      #pragma unroll
      for (int j = 0; j < 2; ++j) {
        int ntg = nh*2 + j;
        short8v bh = *(const short8v*)&wfl[(size_t)(48 + kt*4 + ntg)*512 + lane*8];
        short8v bl = *(const short8v*)&wfl[(size_t)(116 + kt*4 + ntg)*512 + lane*8];
        cv[j] = mfma3(ah, al, bh, bl, cv[j]);
      }
    }
  }
  __syncthreads();                                   // B4 (sQ ready)

  // ---------------- P4: logits (all); mt0: V0 quarter; mt1: Mvg (both row halves, tile nh)
  #pragma unroll
  for (int j = 0; j < 2; ++j) {
    int ntg = nh*2 + j;
    float qv = sQ[ntg*16 + r0];
    #pragma unroll
    for (int i = 0; i < 4; ++i) {
      float v = ck[j][i] * qv;
      v += __shfl_xor(v, 1, 64);
      v += __shfl_xor(v, 2, 64);
      v += __shfl_xor(v, 4, 64);
      if ((lane & 7) == 0)
        sAtt[(mt*16 + g*4 + i)*9 + ntg*2 + (r0 >> 3)] = v * 0.35355339059327373f;
    }
  }
  if (mt == 0) {
    #pragma unroll
    for (int kt = 0; kt < 2; ++kt) {
      int off = kt*32 + g*8;
      short8v ah = *(const short8v*)&regionB  [mrow*72 + off];
      short8v al = *(const short8v*)&regionBlo[mrow*72 + off];
      #pragma unroll
      for (int j = 0; j < 2; ++j) {
        int ntg = nh*2 + j;
        short8v bh = *(const short8v*)&wfl[(size_t)(48 + kt*4 + ntg)*512 + lane*8];
        short8v bl = *(const short8v*)&wfl[(size_t)(116 + kt*4 + ntg)*512 + lane*8];
        cv[j] = mfma3(ah, al, bh, bl, cv[j]);
      }
    }
  } else {
    float* sMvg = (float*)regionA;   // regionA dead (f0src/H1 consumed)
    #pragma unroll
    for (int msub = 0; msub < 2; ++msub) {
      floatx4 cvg = fz;
      #pragma unroll
      for (int kt = 0; kt < 2; ++kt) {
        int off = kt*32 + g*8;
        short8v ah = *(const short8v*)&regionB  [(msub*16 + r0)*72 + off];
        short8v al = *(const short8v*)&regionBlo[(msub*16 + r0)*72 + off];
        short8v bh = *(const short8v*)&wfl[(size_t)(56 + kt*2 + nh)*512 + lane*8];
        short8v bl = *(const short8v*)&wfl[(size_t)(124 + kt*2 + nh)*512 + lane*8];
        cvg = mfma3(ah, al, bh, bl, cvg);
      }
      #pragma unroll
      for (int i = 0; i < 4; ++i)
        sMvg[(msub*16 + g*4 + i)*34 + nh*16 + r0] = cvg[i];
    }
  }
  __syncthreads();                                   // B5 (logits + Mvg)

  // ---------------- P5: softmax — 2 heads per wave, 1 (head,k) per lane
  {
    int head = wid*2 + (lane >> 5);
    int k = lane & 31;
    float lg = sAtt[k*9 + head];
    float mx = lg;
    #pragma unroll
    for (int off = 1; off <= 16; off <<= 1) mx = fmaxf(mx, __shfl_xor(mx, off, 64));
    float e = expf(lg - mx);
    float sum = e;
    #pragma unroll
    for (int off = 1; off <= 16; off <<= 1) sum += __shfl_xor(sum, off, 64);
    float a = e / sum;
    sAtt[k*9 + head] = a;
    float pr = a + __shfl_xor(a, 32, 64);
    if (lane < 32) sAPart[wid][k] = pr;
  }
  __syncthreads();                                   // B6 (softmax + sAPart)

  // ---------------- P6: agg partials from cv; wid3: sA
  {
    #pragma unroll
    for (int j = 0; j < 2; ++j) {
      int ntg = nh*2 + j;
      int head = ntg*2 + (r0 >> 3);
      float p = 0.f;
      #pragma unroll
      for (int i = 0; i < 4; ++i)
        p += sAtt[(mt*16 + g*4 + i)*9 + head] * cv[j][i];
      p += __shfl_xor(p, 16, 64);
      p += __shfl_xor(p, 32, 64);
      if (g == 0) sAggP[mt][ntg*16 + r0] = p;
    }
  }
  if (wid == 3 && lane < 32)
    sA[lane] = 0.125f*(sAPart[0][lane] + sAPart[1][lane] + sAPart[2][lane] + sAPart[3][lane]);
  __syncthreads();                                   // B7

  // ---------------- P7: wid0: f0 out; wid1: f1 out
  if (wid == 0) {
    {
      float p = sAggP[0][lane] + sAggP[1][lane];
      ushort h, l; split_bf(p, h, l);
      sAggH[lane] = h; sAggL[lane] = l;
    }
    floatx4 co[4];
    #pragma unroll
    for (int nt = 0; nt < 4; ++nt) co[nt] = fz;
    #pragma unroll
    for (int kt = 0; kt < 2; ++kt) {
      short8v ah = *(const short8v*)&sAggH[kt*32 + g*8];
      short8v al = *(const short8v*)&sAggL[kt*32 + g*8];
      #pragma unroll
      for (int nt = 0; nt < 4; ++nt) {
        short8v bh = *(const short8v*)&wfl[(size_t)(60 + kt*4 + nt)*512 + lane*8];
        short8v bl = *(const short8v*)&wfl[(size_t)(128 + kt*4 + nt)*512 + lane*8];
        co[nt] = mfma3(ah, al, bh, bl, co[nt]);
      }
    }
    float v = (g == 0) ? co[0][0] : (g == 1) ? co[1][0] : (g == 2) ? co[2][0] : co[3][0];
    f0o[node*H + lane] = f0reg + v + bo0[lane];
  } else if (wid == 1 && lane < F1W) {
    const float* sMvg = (const float*)regionA;
    int ch = lane / 3, d = lane - ch*3;
    float acc = sF1d[lane];
    #pragma unroll 8
    for (int k = 0; k < KK; ++k) {
      float f1s = f1i[(size_t)(bbase + sIdx[k])*F1W + lane];
      float a   = sA[k];
      float mv1 = sMvg[k*34 + ch];
      float mg1 = sMvg[k*34 + 16 + ch];
      acc += a * (sDir[k][d]*mv1 + mg1*f1s);
    }
    f1o[node*F1W + lane] = acc;
  }
}

// ---------------------------------------------------------------- output
__global__ __launch_bounds__(256) void k_out(const float* __restrict__ f1,
                                             const float* __restrict__ Wout1,
                                             float* __restrict__ out) {
  int gidx = blockIdx.x*256 + threadIdx.x;
  if (gidx >= NB*NN*3) return;
  int node = gidx / 3, d = gidx - node*3;
  float acc = 0.f;
  for (int c = 0; c < CV; ++c) acc = fmaf(f1[node*F1W + c*3 + d], Wout1[c], acc);
  out[gidx] = acc;
}

// ---------------------------------------------------------------- launch
extern "C" void kernel_launch(void* const* d_in, const int* in_sizes, int n_in,
                              void* d_out, int out_size, void* d_ws, size_t ws_size,
                              hipStream_t stream) {
  const int*   seq   = (const int*)  d_in[0];
  const float* coord = (const float*)d_in[1];
  const int*   tptr  = (const int*)  d_in[2];
  const float* atab  = (const float*)d_in[3];
  const float* ttab  = (const float*)d_in[4];
  const float* Wp0   = (const float*)d_in[5];
  const float* bp0   = (const float*)d_in[6];
  const float* Wp1   = (const float*)d_in[7];
  const float* We1   = (const float*)d_in[8];
  const float* be1   = (const float*)d_in[9];
  const float* We2   = (const float*)d_in[10];
  const float* be2   = (const float*)d_in[11];
  const float* Wq    = (const float*)d_in[12];
  const float* Wk    = (const float*)d_in[13];
  const float* Wv0   = (const float*)d_in[14];
  const float* Wv1   = (const float*)d_in[15];
  const float* Wg1   = (const float*)d_in[16];
  const float* Wo0   = (const float*)d_in[17];
  const float* bo0   = (const float*)d_in[18];
  const float* Wout1 = (const float*)d_in[19];
  float* out = (float*)d_out;

  float* ws = (float*)d_ws;
  float*  coordC = ws;
  int*    idxb   = (int*)(ws + 12288);
  float*  dirn   = ws + 12288 + 131072;
  float*  f0A    = dirn + (size_t)NB*NN*KK*3;
  float*  f0B    = f0A + (size_t)NB*NN*H;
  float*  f1A    = f0B + (size_t)NB*NN*H;
  float*  f1B    = f1A + (size_t)NB*NN*F1W;
  ushort* rbf16  = (ushort*)(f1B + (size_t)NB*NN*F1W);
  ushort* wfrag  = rbf16 + (size_t)NB*NN*KK*NRBF;

  k_center<<<NB, 256, 0, stream>>>(coord, coordC);
  k_knn<<<NB*NN, 64, 0, stream>>>(coordC, idxb, dirn, rbf16);
  k_f0init<<<NB*NN*H/256, 256, 0, stream>>>(seq, tptr, atab, ttab, Wp0, bp0, f0A);
  k_f1init<<<(NB*NN*F1W + 255)/256, 256, 0, stream>>>(coordC, Wp1, f1A);
  k_prep<<<(NL*NTILES*64 + 255)/256, 256, 0, stream>>>(We1, We2, Wq, Wk, Wv0, Wv1, Wg1, Wo0, wfrag);

  const float* f0in = f0A; float* f0out = f0B;
  const float* f1in = f1A; float* f1out = f1B;
  for (int l = 0; l < NL; ++l) {
    k_layer<<<NB*NN, 256, 0, stream>>>(
        f0in, f1in, f0out, f1out, idxb, dirn, rbf16,
        wfrag + (size_t)l*NTILES*512,
        be1 + (size_t)l*H, be2 + (size_t)l*H, bo0 + (size_t)l*H);
    const float* tf0 = f0in; f0in = f0out; f0out = (float*)tf0;
    const float* tf1 = f1in; f1in = f1out; f1out = (float*)tf1;
  }
  k_out<<<(NB*NN*3 + 255)/256, 256, 0, stream>>>(f1in, Wout1, out);
}

// Round 11
// 324.107 us; speedup vs baseline: 6.2714x; 1.0122x over previous
//
#include <hip/hip_runtime.h>
#include <hip/hip_bf16.h>
#include <math.h>

#define NL    4
#define H     64
#define CV    16
#define NRBF  16
#define HEADS 8
#define KK    32
#define DIN   176
#define NB    2
#define NN    2048
#define F1W   (CV*3)   // 48
#define NTILES 136     // 68 hi + 68 lo per layer
#define HEAPN 17       // 16 keys + sentinel per lane

typedef __attribute__((ext_vector_type(8))) short short8v;
typedef __attribute__((ext_vector_type(4))) float floatx4;

__device__ __forceinline__ ushort f2bf(float f) {
  union { float f; unsigned u; } v; v.f = f;
  unsigned r = v.u + 0x7FFFu + ((v.u >> 16) & 1u);
  return (ushort)(r >> 16);
}
__device__ __forceinline__ float bf2f(ushort s) {
  union { unsigned u; float f; } v; v.u = ((unsigned)s) << 16;
  return v.f;
}
__device__ __forceinline__ void split_bf(float v, ushort& h, ushort& l) {
  h = f2bf(v);
  l = f2bf(v - bf2f(h));
}
__device__ __forceinline__ floatx4 mfma3(short8v ah, short8v al,
                                         short8v bh, short8v bl, floatx4 acc) {
  acc = __builtin_amdgcn_mfma_f32_16x16x32_bf16(ah, bh, acc, 0, 0, 0);
  acc = __builtin_amdgcn_mfma_f32_16x16x32_bf16(ah, bl, acc, 0, 0, 0);
  acc = __builtin_amdgcn_mfma_f32_16x16x32_bf16(al, bh, acc, 0, 0, 0);
  return acc;
}

// ---------------------------------------------------------------- center (+ f1 init fused)
__global__ __launch_bounds__(256) void k_center(const float* __restrict__ coord,
                                                const float* __restrict__ Wp1,
                                                float* __restrict__ coordC,
                                                float* __restrict__ f1) {
  __shared__ float rx[256], ry[256], rz[256];
  int b = blockIdx.x;
  const float* cb = coord + b*NN*3;
  float sx = 0.f, sy = 0.f, sz = 0.f;
  for (int i = threadIdx.x; i < NN; i += 256) {
    sx += cb[i*3+0]; sy += cb[i*3+1]; sz += cb[i*3+2];
  }
  rx[threadIdx.x] = sx; ry[threadIdx.x] = sy; rz[threadIdx.x] = sz;
  __syncthreads();
  for (int s = 128; s > 0; s >>= 1) {
    if (threadIdx.x < s) {
      rx[threadIdx.x] += rx[threadIdx.x+s];
      ry[threadIdx.x] += ry[threadIdx.x+s];
      rz[threadIdx.x] += rz[threadIdx.x+s];
    }
    __syncthreads();
  }
  float mx = rx[0]*(1.0f/NN), my = ry[0]*(1.0f/NN), mz = rz[0]*(1.0f/NN);
  float wp1[CV];
  #pragma unroll
  for (int c = 0; c < CV; ++c) wp1[c] = Wp1[c];
  float* ob = coordC + b*NN*3;
  float* fb = f1 + (size_t)b*NN*F1W;
  for (int i = threadIdx.x; i < NN; i += 256) {
    float cx = cb[i*3+0] - mx, cy = cb[i*3+1] - my, cz = cb[i*3+2] - mz;
    ob[i*3+0] = cx; ob[i*3+1] = cy; ob[i*3+2] = cz;
    #pragma unroll
    for (int c = 0; c < CV; ++c) {
      fb[(size_t)i*F1W + c*3 + 0] = cx * wp1[c];
      fb[(size_t)i*F1W + c*3 + 1] = cy * wp1[c];
      fb[(size_t)i*F1W + c*3 + 2] = cz * wp1[c];
    }
  }
}

// ---------------------------------------------------------------- knn
// Per-lane bitonic sort of 32 keys; only the 16 smallest (+ sentinel) spill
// to LDS (P(lane needs >16 of global top-32) ~ 6e-20); 32 tournament rounds.
__global__ __launch_bounds__(64) void k_knn(const float* __restrict__ coordC,
                                            int* __restrict__ idx,
                                            float* __restrict__ dirn,
                                            ushort* __restrict__ rbf16) {
  __shared__ unsigned long long heap[64*HEAPN];
  const int node = blockIdx.x;
  const int b = node >> 11;
  const int i = node & (NN-1);
  const int l = threadIdx.x;
  const float* cb = coordC + b*NN*3;
  const float xi = cb[i*3+0], yi = cb[i*3+1], zi = cb[i*3+2];
  const float sqi = xi*xi + yi*yi + zi*zi;
  unsigned long long key[32];
  #pragma unroll
  for (int it = 0; it < 32; ++it) {
    int j = it*64 + l;
    float xj = cb[j*3+0], yj = cb[j*3+1], zj = cb[j*3+2];
    float sqj = xj*xj + yj*yj + zj*zj;
    float dot = xi*xj + yi*yj + zi*zj;
    float v = sqi + sqj - 2.0f*dot;            // gram-trick, matches reference
    if (j == i) v += 1.0e9f;
    unsigned u = __float_as_uint(v);
    u ^= (u >> 31) ? 0xFFFFFFFFu : 0x80000000u;  // total order = float order
    key[it] = (((unsigned long long)u) << 16) | (unsigned)j;
  }
  #pragma unroll
  for (int k2 = 2; k2 <= 32; k2 <<= 1) {
    #pragma unroll
    for (int jj = k2 >> 1; jj > 0; jj >>= 1) {
      #pragma unroll
      for (int ii = 0; ii < 32; ++ii) {
        int ixj = ii ^ jj;
        if (ixj > ii) {
          bool up = ((ii & k2) == 0);
          unsigned long long a = key[ii], c = key[ixj];
          bool sw = (a > c) == up;
          unsigned long long lo = sw ? c : a;
          unsigned long long hi = sw ? a : c;
          key[ii] = lo; key[ixj] = hi;
        }
      }
    }
  }
  unsigned long long* row = heap + l*HEAPN;
  #pragma unroll
  for (int it = 0; it < HEAPN-1; ++it) row[it] = key[it];
  row[HEAPN-1] = 0xFFFFFFFFFFFFFFFFULL;
  int ptr = 0;
  unsigned long long head = key[0];
  int myselidx = 0;
  for (int s = 0; s < KK; ++s) {
    unsigned long long w = head;
    #pragma unroll
    for (int off = 1; off <= 32; off <<= 1) {
      unsigned long long o = __shfl_xor(w, off, 64);
      w = (o < w) ? o : w;
    }
    int wj = (int)(w & 0xFFFFull);
    if (l == s) myselidx = wj;
    if ((wj & 63) == l) { ptr = (ptr < HEAPN-1) ? ptr+1 : ptr; head = row[ptr]; }
  }
  if (l < KK) {
    int j = myselidx;
    idx[node*KK + l] = j;
    float rxv = cb[j*3+0] - xi, ryv = cb[j*3+1] - yi, rzv = cb[j*3+2] - zi;
    float dd = sqrtf(rxv*rxv + ryv*ryv + rzv*rzv + 1e-8f);
    float inv = 1.0f/dd;
    float* dn = dirn + (node*KK + l)*3;
    dn[0] = rxv*inv; dn[1] = ryv*inv; dn[2] = rzv*inv;
    ushort* rb = rbf16 + (size_t)(node*KK + l)*NRBF;
    const float inv2s2 = 1.0f/(2.0f*0.625f*0.625f);
    #pragma unroll
    for (int r = 0; r < NRBF; ++r) {
      float mu = (10.0f/15.0f)*(float)r;
      float dm = dd - mu;
      rb[r] = f2bf(expf(-(dm*dm)*inv2s2));
    }
  }
}

// ---------------------------------------------------------------- f0 init
__global__ __launch_bounds__(256) void k_f0init(const int* __restrict__ seq,
                                                const int* __restrict__ tptr,
                                                const float* __restrict__ atab,
                                                const float* __restrict__ ttab,
                                                const float* __restrict__ Wp0,
                                                const float* __restrict__ bp0,
                                                float* __restrict__ f0) {
  int gidx = blockIdx.x*256 + threadIdx.x;
  int node = gidx >> 6, o = gidx & (H-1);
  int s = seq[node];
  int tv = tptr[0];
  const float* ar = atab + s*32;
  const float* tr = ttab + tv*32;
  float acc = bp0[o];
  for (int i2 = 0; i2 < 32; ++i2) acc = fmaf(ar[i2], Wp0[i2*H + o], acc);
  for (int i2 = 0; i2 < 32; ++i2) acc = fmaf(tr[i2], Wp0[(32+i2)*H + o], acc);
  f0[gidx] = acc;
}

// ---------------------------------------------------------------- weight fragment prep
__global__ __launch_bounds__(256) void k_prep(
    const float* __restrict__ We1, const float* __restrict__ We2,
    const float* __restrict__ Wq,  const float* __restrict__ Wk,
    const float* __restrict__ Wv0, const float* __restrict__ Wv1,
    const float* __restrict__ Wg1, const float* __restrict__ Wo0,
    ushort* __restrict__ wfrag) {
  int gid = blockIdx.x*256 + threadIdx.x;
  if (gid >= NL*NTILES*64) return;
  int lane = gid & 63;
  int tile = gid >> 6;
  int l = tile / NTILES;
  int tt = tile - l*NTILES;
  int part = (tt >= 68) ? 1 : 0;
  int t = part ? (tt - 68) : tt;
  int kt, nt, K = H;
  const float* src = nullptr;
  int wvg = 0;
  if (t < 24)      { kt = t>>2;           nt = t&3; src = We1 + (size_t)l*DIN*H; K = DIN; }
  else if (t < 32) { int u=t-24; kt=u>>2; nt = u&3; src = We2 + (size_t)l*H*H; }
  else if (t < 40) { int u=t-32; kt=u>>2; nt = u&3; src = Wk  + (size_t)l*H*H; }
  else if (t < 48) { int u=t-40; kt=u>>2; nt = u&3; src = Wq  + (size_t)l*H*H; }
  else if (t < 56) { int u=t-48; kt=u>>2; nt = u&3; src = Wv0 + (size_t)l*H*H; }
  else if (t < 60) { int u=t-56; kt=u>>1; nt = u&1; wvg = 1; }
  else             { int u=t-60; kt=u>>2; nt = u&3; src = Wo0 + (size_t)l*H*H; }
  ushort out[8];
  #pragma unroll
  for (int j = 0; j < 8; ++j) {
    int k = kt*32 + (lane>>4)*8 + j;
    int col = nt*16 + (lane&15);
    float v = 0.f;
    if (k < K) {
      if (wvg) v = (col < CV) ? Wv1[(size_t)l*H*CV + k*CV + col]
                              : Wg1[(size_t)l*H*CV + k*CV + (col-CV)];
      else     v = src[(size_t)k*H + col];
    }
    ushort h, lo; split_bf(v, h, lo);
    out[j] = part ? lo : h;
  }
  *(short8v*)(wfrag + (size_t)tile*512 + lane*8) = *(const short8v*)out;
}

// ---------------------------------------------------------------- fused layer
// 256 threads = 4 waves on ONE node. Wave wid: mt = wid>>1 (rows mt*16..+15),
// nh = wid&1 (col half, nt tiles {2nh, 2nh+1}).
__global__ __launch_bounds__(256, 6) void k_layer(
    const float* __restrict__ f0i, const float* __restrict__ f1i,
    float* __restrict__ f0o, float* __restrict__ f1o,
    const int* __restrict__ idx, const float* __restrict__ dirn,
    const ushort* __restrict__ rbf16,
    const ushort* __restrict__ wfl,
    const float* __restrict__ be1, const float* __restrict__ be2,
    const float* __restrict__ bo0)
{
  __shared__ __align__(16) ushort regionA  [32*72];   // f0src -> H1 -> fp32 sMvg[32][34]
  __shared__ __align__(16) ushort regionAlo[32*72];
  __shared__ __align__(16) ushort regionB  [32*72];   // [rbf|dotS|dotD|0] -> M
  __shared__ __align__(16) ushort regionBlo[32*72];
  __shared__ __align__(16) ushort sF0h[64], sF0l[64];
  __shared__ __align__(16) ushort sAggH[64], sAggL[64];
  __shared__ float sF1d[F1W];
  __shared__ float sDir[KK][4];
  __shared__ int   sIdx[KK];
  __shared__ float sAtt[KK*9];       // logits then softmax, in place
  __shared__ float sA[KK];
  __shared__ float sQ[64];
  __shared__ float sAggP[2][64];
  __shared__ float sAPart[4][32];

  const int t    = threadIdx.x;
  const int wid  = t >> 6;
  const int lane = t & 63;
  const int mt   = wid >> 1;
  const int nh   = wid & 1;
  const int node = blockIdx.x;
  const int bbase = node & ~(NN-1);
  const int r0 = lane & 15, g = lane >> 4;
  const int mrow = mt*16 + r0;
  const floatx4 fz = {0.f, 0.f, 0.f, 0.f};

  // ---------------- S0: broadcast staging
  float f0reg = 0.f;
  if (wid == 0) {
    f0reg = f0i[node*H + lane];
    ushort h, l; split_bf(f0reg, h, l); sF0h[lane] = h; sF0l[lane] = l;
  } else if (wid == 1) {
    if (lane < KK) sIdx[lane] = idx[node*KK + lane];
  } else if (wid == 2) {
    if (lane < F1W) sF1d[lane] = f1i[node*F1W + lane];
  } else {
    sDir[lane/3][lane%3] = dirn[node*(KK*3) + lane];
    if (lane < 32) {
      int e = 64 + lane;
      sDir[e/3][e%3] = dirn[node*(KK*3) + e];
    }
  }
  __syncthreads();                                   // B0

  // ---------------- S1: staging split over 4 waves
  #pragma unroll
  for (int r = 0; r < 8; ++r) {
    int rr = wid*8 + r;
    float v = f0i[(bbase + sIdx[rr])*H + lane];
    ushort h, l; split_bf(v, h, l);
    regionA[rr*72 + lane] = h; regionAlo[rr*72 + lane] = l;
  }
  #pragma unroll
  for (int it = 0; it < 2; ++it) {       // rbf cols 0..15 + zero cols 48..63
    int p = it*256 + t;
    int k = p >> 4, c = p & 15;
    regionB  [k*72 + c] = rbf16[(size_t)node*(KK*NRBF) + p];
    regionBlo[k*72 + c] = 0;
    regionB  [k*72 + 48 + c] = 0;
    regionBlo[k*72 + 48 + c] = 0;
  }
  #pragma unroll
  for (int it = 0; it < 2; ++it) {       // dotS cols 16..31, dotD cols 32..47
    int p = it*256 + t;
    int k = p >> 4, ch = p & 15;
    const float* fs = f1i + (size_t)(bbase + sIdx[k])*F1W + ch*3;
    float ds_ = 0.f, dd_ = 0.f;
    #pragma unroll
    for (int d = 0; d < 3; ++d) {
      float dr = sDir[k][d];
      ds_ += fs[d] * dr;
      dd_ += sF1d[ch*3 + d] * dr;
    }
    ushort h, l;
    split_bf(ds_, h, l); regionB[k*72 + 16 + ch] = h; regionBlo[k*72 + 16 + ch] = l;
    split_bf(dd_, h, l); regionB[k*72 + 32 + ch] = h; regionBlo[k*72 + 32 + ch] = l;
  }
  __syncthreads();                                   // B1

  // ---------------- P1: H1 = relu(E @ We1 + be1); quarter (rows mt, nt pair nh)
  floatx4 c1[2]; c1[0] = fz; c1[1] = fz;
  #pragma unroll
  for (int kt = 0; kt < 6; ++kt) {
    short8v ah, al;
    if (kt < 2) {
      ah = *(const short8v*)&sF0h[kt*32 + g*8];
      al = *(const short8v*)&sF0l[kt*32 + g*8];
    } else if (kt < 4) {
      int off = (kt-2)*32 + g*8;
      ah = *(const short8v*)&regionA  [mrow*72 + off];
      al = *(const short8v*)&regionAlo[mrow*72 + off];
    } else {
      int off = ((kt == 4) ? 0 : 32) + g*8;
      ah = *(const short8v*)&regionB  [mrow*72 + off];
      al = *(const short8v*)&regionBlo[mrow*72 + off];
    }
    #pragma unroll
    for (int j = 0; j < 2; ++j) {
      int ntg = nh*2 + j;
      short8v bh = *(const short8v*)&wfl[(size_t)(kt*4 + ntg)*512 + lane*8];
      short8v bl = *(const short8v*)&wfl[(size_t)(68 + kt*4 + ntg)*512 + lane*8];
      c1[j] = mfma3(ah, al, bh, bl, c1[j]);
    }
  }
  #pragma unroll
  for (int j = 0; j < 2; ++j) {
    int ntg = nh*2 + j;
    float be = be1[ntg*16 + r0];
    #pragma unroll
    for (int i = 0; i < 4; ++i) {
      float v = fmaxf(c1[j][i] + be, 0.f);
      ushort h, l; split_bf(v, h, l);
      regionA  [(mt*16 + g*4 + i)*72 + ntg*16 + r0] = h;
      regionAlo[(mt*16 + g*4 + i)*72 + ntg*16 + r0] = l;
    }
  }
  __syncthreads();                                   // B2

  // ---------------- P2: M = H1 @ We2 + be2; quarter
  floatx4 c2[2]; c2[0] = fz; c2[1] = fz;
  #pragma unroll
  for (int kt = 0; kt < 2; ++kt) {
    int off = kt*32 + g*8;
    short8v ah = *(const short8v*)&regionA  [mrow*72 + off];
    short8v al = *(const short8v*)&regionAlo[mrow*72 + off];
    #pragma unroll
    for (int j = 0; j < 2; ++j) {
      int ntg = nh*2 + j;
      short8v bh = *(const short8v*)&wfl[(size_t)(24 + kt*4 + ntg)*512 + lane*8];
      short8v bl = *(const short8v*)&wfl[(size_t)(92 + kt*4 + ntg)*512 + lane*8];
      c2[j] = mfma3(ah, al, bh, bl, c2[j]);
    }
  }
  __syncthreads();                                   // B3a
  #pragma unroll
  for (int j = 0; j < 2; ++j) {
    int ntg = nh*2 + j;
    float be = be2[ntg*16 + r0];
    #pragma unroll
    for (int i = 0; i < 4; ++i) {
      ushort h, l; split_bf(c2[j][i] + be, h, l);
      regionB  [(mt*16 + g*4 + i)*72 + ntg*16 + r0] = h;
      regionBlo[(mt*16 + g*4 + i)*72 + ntg*16 + r0] = l;
    }
  }
  __syncthreads();                                   // B3 (M complete)

  // ---------------- P3: all: ck quarter; mt0: q; mt1: V0 quarter
  floatx4 ck[2]; ck[0] = fz; ck[1] = fz;
  floatx4 cv[2]; cv[0] = fz; cv[1] = fz;
  #pragma unroll
  for (int kt = 0; kt < 2; ++kt) {
    int off = kt*32 + g*8;
    short8v ah = *(const short8v*)&regionB  [mrow*72 + off];
    short8v al = *(const short8v*)&regionBlo[mrow*72 + off];
    #pragma unroll
    for (int j = 0; j < 2; ++j) {
      int ntg = nh*2 + j;
      short8v bh = *(const short8v*)&wfl[(size_t)(32 + kt*4 + ntg)*512 + lane*8];
      short8v bl = *(const short8v*)&wfl[(size_t)(100 + kt*4 + ntg)*512 + lane*8];
      ck[j] = mfma3(ah, al, bh, bl, ck[j]);
    }
  }
  if (mt == 0) {
    floatx4 cq[2]; cq[0] = fz; cq[1] = fz;
    #pragma unroll
    for (int kt = 0; kt < 2; ++kt) {
      short8v ah = *(const short8v*)&sF0h[kt*32 + g*8];
      short8v al = *(const short8v*)&sF0l[kt*32 + g*8];
      #pragma unroll
      for (int j = 0; j < 2; ++j) {
        int ntg = nh*2 + j;
        short8v bh = *(const short8v*)&wfl[(size_t)(40 + kt*4 + ntg)*512 + lane*8];
        short8v bl = *(const short8v*)&wfl[(size_t)(108 + kt*4 + ntg)*512 + lane*8];
        cq[j] = mfma3(ah, al, bh, bl, cq[j]);
      }
    }
    if (g == 0) {
      sQ[(nh*2 + 0)*16 + r0] = cq[0][0];
      sQ[(nh*2 + 1)*16 + r0] = cq[1][0];
    }
  } else {
    #pragma unroll
    for (int kt = 0; kt < 2; ++kt) {
      int off = kt*32 + g*8;
      short8v ah = *(const short8v*)&regionB  [mrow*72 + off];
      short8v al = *(const short8v*)&regionBlo[mrow*72 + off];
      #pragma unroll
      for (int j = 0; j < 2; ++j) {
        int ntg = nh*2 + j;
        short8v bh = *(const short8v*)&wfl[(size_t)(48 + kt*4 + ntg)*512 + lane*8];
        short8v bl = *(const short8v*)&wfl[(size_t)(116 + kt*4 + ntg)*512 + lane*8];
        cv[j] = mfma3(ah, al, bh, bl, cv[j]);
      }
    }
  }
  __syncthreads();                                   // B4 (sQ ready)

  // ---------------- P4: logits (all); mt0: V0 quarter; mt1: Mvg
  #pragma unroll
  for (int j = 0; j < 2; ++j) {
    int ntg = nh*2 + j;
    float qv = sQ[ntg*16 + r0];
    #pragma unroll
    for (int i = 0; i < 4; ++i) {
      float v = ck[j][i] * qv;
      v += __shfl_xor(v, 1, 64);
      v += __shfl_xor(v, 2, 64);
      v += __shfl_xor(v, 4, 64);
      if ((lane & 7) == 0)
        sAtt[(mt*16 + g*4 + i)*9 + ntg*2 + (r0 >> 3)] = v * 0.35355339059327373f;
    }
  }
  if (mt == 0) {
    #pragma unroll
    for (int kt = 0; kt < 2; ++kt) {
      int off = kt*32 + g*8;
      short8v ah = *(const short8v*)&regionB  [mrow*72 + off];
      short8v al = *(const short8v*)&regionBlo[mrow*72 + off];
      #pragma unroll
      for (int j = 0; j < 2; ++j) {
        int ntg = nh*2 + j;
        short8v bh = *(const short8v*)&wfl[(size_t)(48 + kt*4 + ntg)*512 + lane*8];
        short8v bl = *(const short8v*)&wfl[(size_t)(116 + kt*4 + ntg)*512 + lane*8];
        cv[j] = mfma3(ah, al, bh, bl, cv[j]);
      }
    }
  } else {
    float* sMvg = (float*)regionA;   // regionA dead (f0src/H1 consumed)
    #pragma unroll
    for (int msub = 0; msub < 2; ++msub) {
      floatx4 cvg = fz;
      #pragma unroll
      for (int kt = 0; kt < 2; ++kt) {
        int off = kt*32 + g*8;
        short8v ah = *(const short8v*)&regionB  [(msub*16 + r0)*72 + off];
        short8v al = *(const short8v*)&regionBlo[(msub*16 + r0)*72 + off];
        short8v bh = *(const short8v*)&wfl[(size_t)(56 + kt*2 + nh)*512 + lane*8];
        short8v bl = *(const short8v*)&wfl[(size_t)(124 + kt*2 + nh)*512 + lane*8];
        cvg = mfma3(ah, al, bh, bl, cvg);
      }
      #pragma unroll
      for (int i = 0; i < 4; ++i)
        sMvg[(msub*16 + g*4 + i)*34 + nh*16 + r0] = cvg[i];
    }
  }
  __syncthreads();                                   // B5 (logits + Mvg)

  // ---------------- P5: softmax — 2 heads per wave, 1 (head,k) per lane
  {
    int head = wid*2 + (lane >> 5);
    int k = lane & 31;
    float lg = sAtt[k*9 + head];
    float mx = lg;
    #pragma unroll
    for (int off = 1; off <= 16; off <<= 1) mx = fmaxf(mx, __shfl_xor(mx, off, 64));
    float e = expf(lg - mx);
    float sum = e;
    #pragma unroll
    for (int off = 1; off <= 16; off <<= 1) sum += __shfl_xor(sum, off, 64);
    float a = e / sum;
    sAtt[k*9 + head] = a;
    float pr = a + __shfl_xor(a, 32, 64);
    if (lane < 32) sAPart[wid][k] = pr;
  }
  __syncthreads();                                   // B6 (softmax + sAPart)

  // ---------------- P6: agg partials from cv; wid3: sA
  {
    #pragma unroll
    for (int j = 0; j < 2; ++j) {
      int ntg = nh*2 + j;
      int head = ntg*2 + (r0 >> 3);
      float p = 0.f;
      #pragma unroll
      for (int i = 0; i < 4; ++i)
        p += sAtt[(mt*16 + g*4 + i)*9 + head] * cv[j][i];
      p += __shfl_xor(p, 16, 64);
      p += __shfl_xor(p, 32, 64);
      if (g == 0) sAggP[mt][ntg*16 + r0] = p;
    }
  }
  if (wid == 3 && lane < 32)
    sA[lane] = 0.125f*(sAPart[0][lane] + sAPart[1][lane] + sAPart[2][lane] + sAPart[3][lane]);
  __syncthreads();                                   // B7

  // ---------------- P7: wid0: f0 out; wid1: f1 out
  if (wid == 0) {
    {
      float p = sAggP[0][lane] + sAggP[1][lane];
      ushort h, l; split_bf(p, h, l);
      sAggH[lane] = h; sAggL[lane] = l;
    }
    floatx4 co[4];
    #pragma unroll
    for (int nt = 0; nt < 4; ++nt) co[nt] = fz;
    #pragma unroll
    for (int kt = 0; kt < 2; ++kt) {
      short8v ah = *(const short8v*)&sAggH[kt*32 + g*8];
      short8v al = *(const short8v*)&sAggL[kt*32 + g*8];
      #pragma unroll
      for (int nt = 0; nt < 4; ++nt) {
        short8v bh = *(const short8v*)&wfl[(size_t)(60 + kt*4 + nt)*512 + lane*8];
        short8v bl = *(const short8v*)&wfl[(size_t)(128 + kt*4 + nt)*512 + lane*8];
        co[nt] = mfma3(ah, al, bh, bl, co[nt]);
      }
    }
    float v = (g == 0) ? co[0][0] : (g == 1) ? co[1][0] : (g == 2) ? co[2][0] : co[3][0];
    f0o[node*H + lane] = f0reg + v + bo0[lane];
  } else if (wid == 1 && lane < F1W) {
    const float* sMvg = (const float*)regionA;
    int ch = lane / 3, d = lane - ch*3;
    float acc = sF1d[lane];
    #pragma unroll 8
    for (int k = 0; k < KK; ++k) {
      float f1s = f1i[(size_t)(bbase + sIdx[k])*F1W + lane];
      float a   = sA[k];
      float mv1 = sMvg[k*34 + ch];
      float mg1 = sMvg[k*34 + 16 + ch];
      acc += a * (sDir[k][d]*mv1 + mg1*f1s);
    }
    f1o[node*F1W + lane] = acc;
  }
}

// ---------------------------------------------------------------- output
__global__ __launch_bounds__(256) void k_out(const float* __restrict__ f1,
                                             const float* __restrict__ Wout1,
                                             float* __restrict__ out) {
  int gidx = blockIdx.x*256 + threadIdx.x;
  if (gidx >= NB*NN*3) return;
  int node = gidx / 3, d = gidx - node*3;
  float acc = 0.f;
  for (int c = 0; c < CV; ++c) acc = fmaf(f1[node*F1W + c*3 + d], Wout1[c], acc);
  out[gidx] = acc;
}

// ---------------------------------------------------------------- launch
extern "C" void kernel_launch(void* const* d_in, const int* in_sizes, int n_in,
                              void* d_out, int out_size, void* d_ws, size_t ws_size,
                              hipStream_t stream) {
  const int*   seq   = (const int*)  d_in[0];
  const float* coord = (const float*)d_in[1];
  const int*   tptr  = (const int*)  d_in[2];
  const float* atab  = (const float*)d_in[3];
  const float* ttab  = (const float*)d_in[4];
  const float* Wp0   = (const float*)d_in[5];
  const float* bp0   = (const float*)d_in[6];
  const float* Wp1   = (const float*)d_in[7];
  const float* We1   = (const float*)d_in[8];
  const float* be1   = (const float*)d_in[9];
  const float* We2   = (const float*)d_in[10];
  const float* be2   = (const float*)d_in[11];
  const float* Wq    = (const float*)d_in[12];
  const float* Wk    = (const float*)d_in[13];
  const float* Wv0   = (const float*)d_in[14];
  const float* Wv1   = (const float*)d_in[15];
  const float* Wg1   = (const float*)d_in[16];
  const float* Wo0   = (const float*)d_in[17];
  const float* bo0   = (const float*)d_in[18];
  const float* Wout1 = (const float*)d_in[19];
  float* out = (float*)d_out;

  float* ws = (float*)d_ws;
  float*  coordC = ws;
  int*    idxb   = (int*)(ws + 12288);
  float*  dirn   = ws + 12288 + 131072;
  float*  f0A    = dirn + (size_t)NB*NN*KK*3;
  float*  f0B    = f0A + (size_t)NB*NN*H;
  float*  f1A    = f0B + (size_t)NB*NN*H;
  float*  f1B    = f1A + (size_t)NB*NN*F1W;
  ushort* rbf16  = (ushort*)(f1B + (size_t)NB*NN*F1W);
  ushort* wfrag  = rbf16 + (size_t)NB*NN*KK*NRBF;

  k_center<<<NB, 256, 0, stream>>>(coord, Wp1, coordC, f1A);
  k_knn<<<NB*NN, 64, 0, stream>>>(coordC, idxb, dirn, rbf16);
  k_f0init<<<NB*NN*H/256, 256, 0, stream>>>(seq, tptr, atab, ttab, Wp0, bp0, f0A);
  k_prep<<<(NL*NTILES*64 + 255)/256, 256, 0, stream>>>(We1, We2, Wq, Wk, Wv0, Wv1, Wg1, Wo0, wfrag);

  const float* f0in = f0A; float* f0out = f0B;
  const float* f1in = f1A; float* f1out = f1B;
  for (int l = 0; l < NL; ++l) {
    k_layer<<<NB*NN, 256, 0, stream>>>(
        f0in, f1in, f0out, f1out, idxb, dirn, rbf16,
        wfrag + (size_t)l*NTILES*512,
        be1 + (size_t)l*H, be2 + (size_t)l*H, bo0 + (size_t)l*H);
    const float* tf0 = f0in; f0in = f0out; f0out = (float*)tf0;
    const float* tf1 = f1in; f1in = f1out; f1out = (float*)tf1;
  }
  k_out<<<(NB*NN*3 + 255)/256, 256, 0, stream>>>(f1in, Wout1, out);
}